// Round 4
// baseline (3013.542 us; speedup 1.0000x reference)
//
#include <hip/hip_runtime.h>
#include <stdint.h>
#include <math.h>

#define USER_N 100000
#define NODE_N 150000
#define DD 64
#define NNZE 2400000
#define BB 4096
#define NLV 3
#define LF 32
#define HALF_SZ 196608u  /* (3*4096*32)/2 */
#define NTILE 586        /* ceil(150000/256) */

// ---------------- threefry2x32 (JAX original mode) ----------------
__host__ __device__ inline void tf_block(uint32_t k0, uint32_t k1, uint32_t& x0, uint32_t& x1) {
  uint32_t ks[3] = {k0, k1, k0 ^ k1 ^ 0x1BD11BDAu};
  x0 += ks[0]; x1 += ks[1];
  const int R0[4] = {13, 15, 26, 6};
  const int R1[4] = {17, 29, 16, 24};
#pragma unroll
  for (int i = 0; i < 5; ++i) {
    const int* R = (i & 1) ? R1 : R0;
#pragma unroll
    for (int j = 0; j < 4; ++j) {
      x0 += x1;
      x1 = (x1 << R[j]) | (x1 >> (32 - R[j]));
      x1 ^= x0;
    }
    x0 += ks[(i + 1) % 3];
    x1 += ks[(i + 2) % 3] + (uint32_t)(i + 1);
  }
}

__device__ inline float tf_uniform(uint32_t ka, uint32_t kb, uint32_t m) {
  uint32_t x0, x1;
  bool first = m < HALF_SZ;
  if (first) { x0 = m; x1 = m + HALF_SZ; } else { x0 = m - HALF_SZ; x1 = m; }
  tf_block(ka, kb, x0, x1);
  uint32_t bits = first ? x0 : x1;
  return __uint_as_float((bits >> 9) | 0x3f800000u) - 1.0f;
}

// ---------------- kernels ----------------
__global__ __launch_bounds__(256) void k_init(const float* __restrict__ ego,
                                              float* __restrict__ E, float* __restrict__ Esum) {
  int i = blockIdx.x * 256 + threadIdx.x;  // float4 index
  float4 v = ((const float4*)ego)[i];
  ((float4*)E)[i] = v;
  ((float4*)Esum)[i] = v;
}

// per-tile histogram; counters padded to one per 64B line
__global__ __launch_bounds__(256) void k_hist_t(const int* __restrict__ rows,
                                                int* __restrict__ hist) {
  int e = blockIdx.x * 256 + threadIdx.x;
  if (e < NNZE) atomicAdd(&hist[(rows[e] >> 8) * 16], 1);
}

// single-block scan over 586 tile counts -> tile_start (exclusive bounds) + cursor init
__global__ __launch_bounds__(1024) void k_scan_t(const int* __restrict__ hist,
                                                 int* __restrict__ tile_start,
                                                 int* __restrict__ cursor) {
  __shared__ int buf[1024];
  int t = threadIdx.x;
  int v = (t < NTILE) ? hist[t * 16] : 0;
  buf[t] = v;
  __syncthreads();
  for (int off = 1; off < 1024; off <<= 1) {
    int add = (t >= off) ? buf[t - off] : 0;
    __syncthreads();
    buf[t] += add;
    __syncthreads();
  }
  if (t < NTILE) {
    tile_start[t + 1] = buf[t];
    cursor[t * 16] = buf[t] - v;  // exclusive prefix
  }
  if (t == 0) tile_start[0] = 0;
}

// bucket edges by tile; record = {row_local<<18 | col, val}. Destinations advance
// ~sequentially per tile -> write frontier (586 lines) stays L2-resident, lines
// fully populated before writeback (vs 149MB partial-line traffic in round 3).
__global__ __launch_bounds__(256) void k_scatter_t(const int* __restrict__ rows,
                                                   const int* __restrict__ cols,
                                                   const float* __restrict__ vals,
                                                   int* __restrict__ cursor,
                                                   uint2* __restrict__ sedge) {
  int e = blockIdx.x * 256 + threadIdx.x;
  if (e < NNZE) {
    int r = rows[e];
    int tile = r >> 8;
    uint32_t rl = (uint32_t)(r & 255);
    int p = atomicAdd(&cursor[tile * 16], 1);
    sedge[p] = make_uint2((uint32_t)cols[e] | (rl << 18), __float_as_uint(vals[e]));
  }
}

// Fused sort+SpMM: one block per tile, 256x64 fp32 accumulator in LDS,
// edges processed unsorted with ds_add_f32. 16-lane float4 E-row gathers,
// 2 edges in flight per wave iteration.
__global__ __launch_bounds__(256) void k_spmm_tile(const float* __restrict__ E,
                                                   const uint2* __restrict__ sedge,
                                                   const int* __restrict__ tile_start,
                                                   float* __restrict__ side) {
  __shared__ float acc[256 * 64];
  int t = threadIdx.x;
  int tile = blockIdx.x;
  int s = tile_start[tile], e = tile_start[tile + 1];
  {
    float4 z = make_float4(0.f, 0.f, 0.f, 0.f);
    for (int i = t; i < 256 * 64 / 4; i += 256) ((float4*)acc)[i] = z;
  }
  __syncthreads();
  int w = t >> 6, lane = t & 63, g = lane >> 4, q = lane & 15;
  int idx = s + w * 8 + g;
  for (; idx + 4 < e; idx += 32) {
    uint2 r0 = sedge[idx];
    uint2 r1 = sedge[idx + 4];
    const float4 a0 = *(const float4*)&E[(size_t)(r0.x & 0x3FFFFu) * DD + q * 4];
    const float4 a1 = *(const float4*)&E[(size_t)(r1.x & 0x3FFFFu) * DD + q * 4];
    float v0 = __uint_as_float(r0.y);
    float v1 = __uint_as_float(r1.y);
    float* d0 = &acc[(r0.x >> 18) * 64 + q * 4];
    float* d1 = &acc[(r1.x >> 18) * 64 + q * 4];
    atomicAdd(d0 + 0, v0 * a0.x);
    atomicAdd(d0 + 1, v0 * a0.y);
    atomicAdd(d0 + 2, v0 * a0.z);
    atomicAdd(d0 + 3, v0 * a0.w);
    atomicAdd(d1 + 0, v1 * a1.x);
    atomicAdd(d1 + 1, v1 * a1.y);
    atomicAdd(d1 + 2, v1 * a1.z);
    atomicAdd(d1 + 3, v1 * a1.w);
  }
  if (idx < e) {
    uint2 r0 = sedge[idx];
    const float4 a0 = *(const float4*)&E[(size_t)(r0.x & 0x3FFFFu) * DD + q * 4];
    float v0 = __uint_as_float(r0.y);
    float* d0 = &acc[(r0.x >> 18) * 64 + q * 4];
    atomicAdd(d0 + 0, v0 * a0.x);
    atomicAdd(d0 + 1, v0 * a0.y);
    atomicAdd(d0 + 2, v0 * a0.z);
    atomicAdd(d0 + 3, v0 * a0.w);
  }
  __syncthreads();
  int nrow = NODE_N - tile * 256;
  if (nrow > 256) nrow = 256;
  int nf4 = nrow * 16;  // float4s
  float4* dst = (float4*)&side[(size_t)tile * 256 * 64];
  for (int i = t; i < nf4; i += 256) dst[i] = ((const float4*)acc)[i];
}

// Transform: weights held in VGPR columns, row vectors broadcast from LDS via b128.
#define TR_ROWS 16
#define TR_GRID 1875   /* 9375 chunks / 5 per block */
__global__ __launch_bounds__(256) void k_transform(const float* __restrict__ gw,
                                                   const float* __restrict__ gb,
                                                   const float* __restrict__ bw,
                                                   const float* __restrict__ bb,
                                                   float* __restrict__ E, float* __restrict__ Esum,
                                                   const float* __restrict__ side) {
  __shared__ float ss[TR_ROWS][64];
  __shared__ float pp[TR_ROWS][64];
  int t = threadIdx.x;
  int lane = t & 63;
  int wv = t >> 6;
  float wgr[64], wbr[64];
#pragma unroll
  for (int k = 0; k < 64; ++k) {
    wgr[k] = gw[k * 64 + lane];
    wbr[k] = bw[k * 64 + lane];
  }
  float gbl = gb[lane], bbl = bb[lane];
  const int nchunks = NODE_N / TR_ROWS;  // 9375
  for (int chunk = blockIdx.x; chunk < nchunks; chunk += TR_GRID) {
    int r0 = chunk * TR_ROWS;
    {
      int row = t >> 4;
      int col = (t & 15) * 4;
      float4 sv = *(const float4*)&side[(size_t)(r0 + row) * 64 + col];
      float4 ev = *(const float4*)&E[(size_t)(r0 + row) * 64 + col];
      *(float4*)&ss[row][col] = sv;
      pp[row][col + 0] = sv.x * ev.x;
      pp[row][col + 1] = sv.y * ev.y;
      pp[row][col + 2] = sv.z * ev.z;
      pp[row][col + 3] = sv.w * ev.w;
    }
    __syncthreads();
#pragma unroll
    for (int rr = 0; rr < 4; ++rr) {
      int row = wv + rr * 4;
      float a10 = 0.f, a11 = 0.f, a12 = 0.f, a13 = 0.f;
      float a20 = 0.f, a21 = 0.f, a22 = 0.f, a23 = 0.f;
#pragma unroll
      for (int k = 0; k < 64; k += 4) {
        float4 s4 = *(const float4*)&ss[row][k];
        float4 p4 = *(const float4*)&pp[row][k];
        a10 = fmaf(s4.x, wgr[k + 0], a10);
        a11 = fmaf(s4.y, wgr[k + 1], a11);
        a12 = fmaf(s4.z, wgr[k + 2], a12);
        a13 = fmaf(s4.w, wgr[k + 3], a13);
        a20 = fmaf(p4.x, wbr[k + 0], a20);
        a21 = fmaf(p4.y, wbr[k + 1], a21);
        a22 = fmaf(p4.z, wbr[k + 2], a22);
        a23 = fmaf(p4.w, wbr[k + 3], a23);
      }
      float a1 = gbl + ((a10 + a11) + (a12 + a13));
      float a2 = bbl + ((a20 + a21) + (a22 + a23));
      a1 = (a1 > 0.f) ? a1 : 0.01f * a1;
      a2 = (a2 > 0.f) ? a2 : 0.01f * a2;
      float v = a1 + a2;
      float sq = v * v;
#pragma unroll
      for (int off = 32; off; off >>= 1) sq += __shfl_xor(sq, off, 64);
      v = v / fmaxf(sqrtf(sq), 1e-12f);
      size_t o = (size_t)(r0 + row) * 64 + lane;
      E[o] = v;
      Esum[o] += v;
    }
    __syncthreads();
  }
}

__global__ __launch_bounds__(128) void k_gather(const float* __restrict__ Esum,
                                                const int* __restrict__ uid,
                                                const int* __restrict__ iid,
                                                float* __restrict__ ue, float* __restrict__ ie) {
  int b = blockIdx.x, t = threadIdx.x;
  if (t < 64) ue[(size_t)b * 64 + t] = Esum[(size_t)uid[b] * 64 + t];
  else {
    int d = t - 64;
    ie[(size_t)b * 64 + d] = Esum[(size_t)(USER_N + iid[b]) * 64 + d];
  }
}

__global__ __launch_bounds__(256) void k_encoder(const float* __restrict__ xin,
                                                 const float* __restrict__ hw, const float* __restrict__ hb,
                                                 const float* __restrict__ w1, const float* __restrict__ b1,
                                                 const float* __restrict__ w2, const float* __restrict__ b2,
                                                 float* __restrict__ recs) {
  __shared__ float sx[64], sreps[64], st[256];
  int b = blockIdx.x, l = blockIdx.y, t = threadIdx.x;
  if (t < 64) sx[t] = xin[(size_t)b * 64 + t];
  __syncthreads();
  if (t < 64) {
    const float* W = hw + l * 64 * 64;
    float a = hb[l * 64 + t];
#pragma unroll 8
    for (int k = 0; k < 64; ++k) a += sx[k] * W[k * 64 + t];
    sreps[t] = tanhf(a);
  }
  __syncthreads();
  {
    const float* W = w1 + l * 64 * 256;
    float a = b1[l * 256 + t];
#pragma unroll 8
    for (int k = 0; k < 64; ++k) a += sreps[k] * W[k * 256 + t];
    st[t] = tanhf(a);
  }
  __syncthreads();
  if (t < 32) {
    const float* W = w2 + l * 256 * 32;
    float a = b2[l * 32 + t];
#pragma unroll 8
    for (int k = 0; k < 256; ++k) a += st[k] * W[k * 32 + t];
    recs[((size_t)l * BB + b) * 32 + t] = a;
  }
}

__global__ __launch_bounds__(256) void k_attn(const float* __restrict__ recs,
                                              const float* __restrict__ qw, const float* __restrict__ qb,
                                              const float* __restrict__ kw, const float* __restrict__ kb,
                                              const float* __restrict__ vw, const float* __restrict__ vb,
                                              float* __restrict__ att) {
  int t = threadIdx.x;
  int b = blockIdx.x * 8 + (t >> 5);
  int d = t & 31;
  float x0 = recs[((size_t)0 * BB + b) * 32 + d];
  float x1 = recs[((size_t)1 * BB + b) * 32 + d];
  float x2 = recs[((size_t)2 * BB + b) * 32 + d];
  float q0 = qb[d], q1 = q0, q2 = q0;
  float c0 = kb[d], c1 = c0, c2 = c0;
  float v0 = vb[d], v1 = v0, v2 = v0;
#pragma unroll 4
  for (int kk = 0; kk < 32; ++kk) {
    float xa = __shfl(x0, kk, 32);
    float xb = __shfl(x1, kk, 32);
    float xc = __shfl(x2, kk, 32);
    float wq = qw[kk * 32 + d], wk = kw[kk * 32 + d], wv = vw[kk * 32 + d];
    q0 += xa * wq; q1 += xb * wq; q2 += xc * wq;
    c0 += xa * wk; c1 += xb * wk; c2 += xc * wk;
    v0 += xa * wv; v1 += xb * wv; v2 += xc * wv;
  }
  float qs[3] = {q0, q1, q2}, ks[3] = {c0, c1, c2}, vs[3] = {v0, v1, v2};
  float sc[3][3];
#pragma unroll
  for (int s = 0; s < 3; ++s)
#pragma unroll
    for (int u = 0; u < 3; ++u) {
      float p = qs[s] * ks[u];
#pragma unroll
      for (int off = 16; off; off >>= 1) p += __shfl_xor(p, off, 32);
      sc[s][u] = p * 0.17677669529663687f;  // 1/sqrt(32)
    }
#pragma unroll
  for (int s = 0; s < 3; ++s) {
    float m = fmaxf(sc[s][0], fmaxf(sc[s][1], sc[s][2]));
    float e0 = __expf(sc[s][0] - m), e1 = __expf(sc[s][1] - m), e2 = __expf(sc[s][2] - m);
    float inv = 1.f / (e0 + e1 + e2);
    att[(size_t)b * 96 + s * 32 + d] = (e0 * vs[0] + e1 * vs[1] + e2 * vs[2]) * inv;
  }
}

__global__ __launch_bounds__(256) void k_noise(const float* __restrict__ att_u,
                                               const float* __restrict__ att_i,
                                               uint32_t ku0, uint32_t ku1, uint32_t ki0, uint32_t ki1,
                                               float* __restrict__ n1, float* __restrict__ n2,
                                               float* __restrict__ posdot) {
  int t = threadIdx.x;
  int g = blockIdx.x * 8 + (t >> 5);   // [0, 24576)
  int k = t & 31;
  int side = g / (NLV * BB);
  int rem = g - side * (NLV * BB);
  int l = rem >> 12;
  int b = rem & 4095;
  const float* att = side ? att_i : att_u;
  uint32_t ka = side ? ki0 : ku0;
  uint32_t kb = side ? ki1 : ku1;
  float r = att[(size_t)b * 96 + l * 32 + k];
  float ss = r * r;
#pragma unroll
  for (int off = 16; off; off >>= 1) ss += __shfl_xor(ss, off, 32);
  float v1 = r / fmaxf(sqrtf(ss), 1e-12f);
  uint32_t m = ((uint32_t)(l * BB + b)) * 32u + (uint32_t)k;
  float u = tf_uniform(ka, kb, m);
  float us = u * u;
#pragma unroll
  for (int off = 16; off; off >>= 1) us += __shfl_xor(us, off, 32);
  float un = u / fmaxf(sqrtf(us), 1e-12f);
  float sgn = (r > 0.f) ? 1.f : ((r < 0.f) ? -1.f : 0.f);
  float rn = r + sgn * un * 0.1f;
  float s2 = rn * rn;
#pragma unroll
  for (int off = 16; off; off >>= 1) s2 += __shfl_xor(s2, off, 32);
  float v2 = rn / fmaxf(sqrtf(s2), 1e-12f);
  float pd = v1 * v2;
#pragma unroll
  for (int off = 16; off; off >>= 1) pd += __shfl_xor(pd, off, 32);
  size_t o = (size_t)g * 32 + k;
  n1[o] = v1;
  n2[o] = v2;
  if (k == 0) posdot[g] = pd;
}

// ttl: per-slice [4096 x 4096] exp(dot/tau) row-sums.
// 2 i-rows per thread share each staged j-chunk read.
__global__ __launch_bounds__(256) void k_ttl(const float* __restrict__ n1,
                                             const float* __restrict__ n2,
                                             float* __restrict__ ttl) {
  __shared__ float4 sj[128][8];
  int sl = blockIdx.z;
  int t = threadIdx.x;
  int ia = blockIdx.x * 512 + t;
  int ib = ia + 256;
  const float* n1b = n1 + (size_t)sl * BB * 32;
  const float* n2b = n2 + (size_t)sl * BB * 32;
  float4 ra[8], rb[8];
#pragma unroll
  for (int k = 0; k < 8; ++k) {
    ra[k] = *(const float4*)&n1b[(size_t)ia * 32 + k * 4];
    rb[k] = *(const float4*)&n1b[(size_t)ib * 32 + k * 4];
  }
  float acca = 0.f, accb = 0.f;
  for (int jc = 0; jc < 2; ++jc) {
    int j0 = blockIdx.y * 256 + jc * 128;
    __syncthreads();
    for (int idx = t; idx < 128 * 8; idx += 256) {
      int jj = idx >> 3, kk = idx & 7;
      sj[jj][kk] = *(const float4*)&n2b[(size_t)(j0 + jj) * 32 + kk * 4];
    }
    __syncthreads();
    for (int j = 0; j < 128; ++j) {
      float a0 = 0.f, a1 = 0.f, a2 = 0.f, a3 = 0.f;
      float b0 = 0.f, b1 = 0.f, b2 = 0.f, b3 = 0.f;
#pragma unroll
      for (int k = 0; k < 8; ++k) {
        float4 sv = sj[j][k];
        a0 = fmaf(ra[k].x, sv.x, a0);
        a1 = fmaf(ra[k].y, sv.y, a1);
        a2 = fmaf(ra[k].z, sv.z, a2);
        a3 = fmaf(ra[k].w, sv.w, a3);
        b0 = fmaf(rb[k].x, sv.x, b0);
        b1 = fmaf(rb[k].y, sv.y, b1);
        b2 = fmaf(rb[k].z, sv.z, b2);
        b3 = fmaf(rb[k].w, sv.w, b3);
      }
      acca += __expf(((a0 + a1) + (a2 + a3)) * 5.0f);  // 1/TAU = 5
      accb += __expf(((b0 + b1) + (b2 + b3)) * 5.0f);
    }
  }
  atomicAdd(&ttl[sl * BB + ia], acca);
  atomicAdd(&ttl[sl * BB + ib], accb);
}

__global__ __launch_bounds__(1024) void k_clred(const float* __restrict__ ttl,
                                                const float* __restrict__ posdot,
                                                float* __restrict__ outp) {
  __shared__ float red[1024];
  int t = threadIdx.x;
  float a = 0.f;
  for (int idx = t; idx < 6 * BB; idx += 1024)
    a += logf(ttl[idx]) - posdot[idx] * 5.0f;
  red[t] = a;
  __syncthreads();
  for (int off = 512; off; off >>= 1) {
    if (t < off) red[t] += red[t + off];
    __syncthreads();
  }
  if (t == 0) outp[2 * BB] = red[0] * (1.f / 12288.f);  // (cl_u + cl_i)
}

__global__ __launch_bounds__(256) void k_head(const float* __restrict__ att_u,
                                              const float* __restrict__ att_i,
                                              const float* __restrict__ skills,
                                              const float* __restrict__ w1, const float* __restrict__ b1,
                                              const float* __restrict__ w2, const float* __restrict__ b2,
                                              const float* __restrict__ pw, const float* __restrict__ pb,
                                              float* __restrict__ outp) {
  __shared__ float diag[4][96], t1[4][64];
  int t = threadIdx.x;
  int w = t >> 6, lane = t & 63;
  int b = blockIdx.x * 4 + w;
  for (int j = lane; j < 96; j += 64) {
    float su = 1.f / (1.f + __expf(-att_u[(size_t)b * 96 + j]));
    float si = 1.f / (1.f + __expf(-att_i[(size_t)b * 96 + j]));
    diag[w][j] = (su - si) * skills[(size_t)b * 96 + j];
  }
  __syncthreads();
  float a = b1[lane];
#pragma unroll 8
  for (int j = 0; j < 96; ++j) a += diag[w][j] * w1[j * 64 + lane];
  t1[w][lane] = tanhf(a);
  __syncthreads();
  float h = b2[lane];
#pragma unroll 8
  for (int kk = 0; kk < 64; ++kk) h += t1[w][kk] * w2[kk * 64 + lane];
  float p0 = h * pw[lane * 2 + 0];
  float p1 = h * pw[lane * 2 + 1];
#pragma unroll
  for (int off = 32; off; off >>= 1) {
    p0 += __shfl_xor(p0, off, 64);
    p1 += __shfl_xor(p1, off, 64);
  }
  if (lane == 0) {
    float l0 = p0 + pb[0], l1 = p1 + pb[1];
    float m = fmaxf(l0, l1);
    float e0 = __expf(l0 - m), e1 = __expf(l1 - m);
    float inv = 1.f / (e0 + e1);
    outp[(size_t)b * 2 + 0] = e0 * inv;
    outp[(size_t)b * 2 + 1] = e1 * inv;
  }
}

// ---------------- launcher ----------------
extern "C" void kernel_launch(void* const* d_in, const int* in_sizes, int n_in,
                              void* d_out, int out_size, void* d_ws, size_t ws_size,
                              hipStream_t stream) {
  const float* ego    = (const float*)d_in[0];
  const float* gc_w   = (const float*)d_in[1];
  const float* gc_b   = (const float*)d_in[2];
  const float* bi_w   = (const float*)d_in[3];
  const float* bi_b   = (const float*)d_in[4];
  const float* uh_w   = (const float*)d_in[5];
  const float* uh_b   = (const float*)d_in[6];
  const float* ih_w   = (const float*)d_in[7];
  const float* ih_b   = (const float*)d_in[8];
  const float* ud_w1  = (const float*)d_in[9];
  const float* ud_b1  = (const float*)d_in[10];
  const float* ud_w2  = (const float*)d_in[11];
  const float* ud_b2  = (const float*)d_in[12];
  const float* id_w1  = (const float*)d_in[13];
  const float* id_b1  = (const float*)d_in[14];
  const float* id_w2  = (const float*)d_in[15];
  const float* id_b2  = (const float*)d_in[16];
  const float* q_w    = (const float*)d_in[17];
  const float* q_b    = (const float*)d_in[18];
  const float* k_w    = (const float*)d_in[19];
  const float* k_b    = (const float*)d_in[20];
  const float* v_w    = (const float*)d_in[21];
  const float* v_b    = (const float*)d_in[22];
  const float* dg_w1  = (const float*)d_in[23];
  const float* dg_b1  = (const float*)d_in[24];
  const float* dg_w2  = (const float*)d_in[25];
  const float* dg_b2  = (const float*)d_in[26];
  const float* pr_w   = (const float*)d_in[27];
  const float* pr_b   = (const float*)d_in[28];
  const float* adj_vals = (const float*)d_in[29];
  const float* skills = (const float*)d_in[30];
  const int* user_id  = (const int*)d_in[31];
  const int* item_id  = (const int*)d_in[32];
  const int* adj_rows = (const int*)d_in[33];
  const int* adj_cols = (const int*)d_in[34];
  float* outp = (float*)d_out;

  char* w = (char*)d_ws;
  auto alloc = [&](size_t bytes) -> char* {
    char* p = w;
    w += (bytes + 255) & ~(size_t)255;
    return p;
  };
  float* E      = (float*)alloc((size_t)NODE_N * DD * 4);
  float* Esum   = (float*)alloc((size_t)NODE_N * DD * 4);
  float* side   = (float*)alloc((size_t)NTILE * 256 * DD * 4);  // padded to tile grid
  uint2* sedge  = (uint2*)alloc((size_t)NNZE * 8);
  int*   hist   = (int*)  alloc((size_t)NTILE * 16 * 4);
  int*   tile_start = (int*)alloc((size_t)(NTILE + 1) * 4);
  int*   cursor = (int*)  alloc((size_t)NTILE * 16 * 4);
  float* ue     = (float*)alloc((size_t)BB * 64 * 4);
  float* ie     = (float*)alloc((size_t)BB * 64 * 4);
  float* recs_u = (float*)alloc((size_t)NLV * BB * 32 * 4);
  float* recs_i = (float*)alloc((size_t)NLV * BB * 32 * 4);
  float* att_u  = (float*)alloc((size_t)BB * 96 * 4);
  float* att_i  = (float*)alloc((size_t)BB * 96 * 4);
  float* n1     = (float*)alloc((size_t)6 * BB * 32 * 4);
  float* n2     = (float*)alloc((size_t)6 * BB * 32 * 4);
  float* posdot = (float*)alloc((size_t)6 * BB * 4);
  float* ttl    = (float*)alloc((size_t)6 * BB * 4);

  // host-side: kc = jax.random.split(jax.random.key(42), 2)
  uint32_t a0 = 0, a1 = 2, b0 = 1, b1 = 3;
  tf_block(0u, 42u, a0, a1);
  tf_block(0u, 42u, b0, b1);
  uint32_t ku0 = a0, ku1 = b0;   // kc[0] -> u side
  uint32_t ki0 = a1, ki1 = b1;   // kc[1] -> i side

  hipMemsetAsync(hist, 0, (size_t)NTILE * 16 * 4, stream);
  hipMemsetAsync(ttl, 0, (size_t)6 * BB * 4, stream);

  k_init<<<9375, 256, 0, stream>>>(ego, E, Esum);
  k_hist_t<<<9375, 256, 0, stream>>>(adj_rows, hist);
  k_scan_t<<<1, 1024, 0, stream>>>(hist, tile_start, cursor);
  k_scatter_t<<<9375, 256, 0, stream>>>(adj_rows, adj_cols, adj_vals, cursor, sedge);

  for (int l = 0; l < 2; ++l) {
    k_spmm_tile<<<NTILE, 256, 0, stream>>>(E, sedge, tile_start, side);
    k_transform<<<TR_GRID, 256, 0, stream>>>(gc_w + l * 4096, gc_b + l * 64,
                                             bi_w + l * 4096, bi_b + l * 64,
                                             E, Esum, side);
  }

  k_gather<<<4096, 128, 0, stream>>>(Esum, user_id, item_id, ue, ie);

  dim3 ge(4096, 3);
  k_encoder<<<ge, 256, 0, stream>>>(ue, uh_w, uh_b, ud_w1, ud_b1, ud_w2, ud_b2, recs_u);
  k_encoder<<<ge, 256, 0, stream>>>(ie, ih_w, ih_b, id_w1, id_b1, id_w2, id_b2, recs_i);

  k_attn<<<512, 256, 0, stream>>>(recs_u, q_w, q_b, k_w, k_b, v_w, v_b, att_u);
  k_attn<<<512, 256, 0, stream>>>(recs_i, q_w, q_b, k_w, k_b, v_w, v_b, att_i);

  k_noise<<<3072, 256, 0, stream>>>(att_u, att_i, ku0, ku1, ki0, ki1, n1, n2, posdot);

  dim3 gt(8, 16, 6);
  k_ttl<<<gt, 256, 0, stream>>>(n1, n2, ttl);
  k_clred<<<1, 1024, 0, stream>>>(ttl, posdot, outp);

  k_head<<<1024, 256, 0, stream>>>(att_u, att_i, skills, dg_w1, dg_b1, dg_w2, dg_b2,
                                   pr_w, pr_b, outp);
}

// Round 5
// 1200.584 us; speedup vs baseline: 2.5101x; 2.5101x over previous
//
#include <hip/hip_runtime.h>
#include <stdint.h>
#include <math.h>

#define USER_N 100000
#define NODE_N 150000
#define DD 64
#define NNZE 2400000
#define BB 4096
#define NLV 3
#define LF 32
#define HALF_SZ 196608u  /* (3*4096*32)/2 */
#define NTILE 586        /* ceil(150000/256) */

// ---------------- threefry2x32 (JAX original mode) ----------------
__host__ __device__ inline void tf_block(uint32_t k0, uint32_t k1, uint32_t& x0, uint32_t& x1) {
  uint32_t ks[3] = {k0, k1, k0 ^ k1 ^ 0x1BD11BDAu};
  x0 += ks[0]; x1 += ks[1];
  const int R0[4] = {13, 15, 26, 6};
  const int R1[4] = {17, 29, 16, 24};
#pragma unroll
  for (int i = 0; i < 5; ++i) {
    const int* R = (i & 1) ? R1 : R0;
#pragma unroll
    for (int j = 0; j < 4; ++j) {
      x0 += x1;
      x1 = (x1 << R[j]) | (x1 >> (32 - R[j]));
      x1 ^= x0;
    }
    x0 += ks[(i + 1) % 3];
    x1 += ks[(i + 2) % 3] + (uint32_t)(i + 1);
  }
}

__device__ inline float tf_uniform(uint32_t ka, uint32_t kb, uint32_t m) {
  uint32_t x0, x1;
  bool first = m < HALF_SZ;
  if (first) { x0 = m; x1 = m + HALF_SZ; } else { x0 = m - HALF_SZ; x1 = m; }
  tf_block(ka, kb, x0, x1);
  uint32_t bits = first ? x0 : x1;
  return __uint_as_float((bits >> 9) | 0x3f800000u) - 1.0f;
}

// ---------------- kernels ----------------
__global__ __launch_bounds__(256) void k_init(const float* __restrict__ ego,
                                              float* __restrict__ E, float* __restrict__ Esum) {
  int i = blockIdx.x * 256 + threadIdx.x;  // float4 index
  float4 v = ((const float4*)ego)[i];
  ((float4*)E)[i] = v;
  ((float4*)Esum)[i] = v;
}

// per-tile histogram; counters padded to one per 64B line
__global__ __launch_bounds__(256) void k_hist_t(const int* __restrict__ rows,
                                                int* __restrict__ hist) {
  int e = blockIdx.x * 256 + threadIdx.x;
  if (e < NNZE) atomicAdd(&hist[(rows[e] >> 8) * 16], 1);
}

// scan over 586 tile counts -> tile_start bounds + tile cursor init; also caps row_start
__global__ __launch_bounds__(1024) void k_scan_t(const int* __restrict__ hist,
                                                 int* __restrict__ tile_start,
                                                 int* __restrict__ cursor,
                                                 int* __restrict__ row_start) {
  __shared__ int buf[1024];
  int t = threadIdx.x;
  int v = (t < NTILE) ? hist[t * 16] : 0;
  buf[t] = v;
  __syncthreads();
  for (int off = 1; off < 1024; off <<= 1) {
    int add = (t >= off) ? buf[t - off] : 0;
    __syncthreads();
    buf[t] += add;
    __syncthreads();
  }
  if (t < NTILE) {
    tile_start[t + 1] = buf[t];
    cursor[t * 16] = buf[t] - v;  // exclusive prefix
  }
  if (t == 0) { tile_start[0] = 0; row_start[NODE_N] = NNZE; }
}

// bucket edges by 256-row tile; record = {row_local<<18 | col, val}. Destinations
// advance ~sequentially per tile -> write frontier (586 lines) stays L2-resident.
__global__ __launch_bounds__(256) void k_scatter_t(const int* __restrict__ rows,
                                                   const int* __restrict__ cols,
                                                   const float* __restrict__ vals,
                                                   int* __restrict__ cursor,
                                                   uint2* __restrict__ sedge) {
  int e = blockIdx.x * 256 + threadIdx.x;
  if (e < NNZE) {
    int r = rows[e];
    int tile = r >> 8;
    uint32_t rl = (uint32_t)(r & 255);
    int p = atomicAdd(&cursor[tile * 16], 1);
    sedge[p] = make_uint2((uint32_t)cols[e] | (rl << 18), __float_as_uint(vals[e]));
  }
}

// per-tile 256-bin counting sort: bucketed records -> row-sorted CSR (+ row_start).
// All scattered writes land inside this tile's ~32KB window -> L2-resident.
__global__ __launch_bounds__(256) void k_sort_t(const uint2* __restrict__ sedge_in,
                                                const int* __restrict__ tile_start,
                                                uint2* __restrict__ sedge_out,
                                                int* __restrict__ row_start) {
  __shared__ int hist[256], buf[256], curs[256];
  int t = threadIdx.x;
  int tile = blockIdx.x;
  int s = tile_start[tile], e = tile_start[tile + 1];
  hist[t] = 0;
  __syncthreads();
  for (int i = s + t; i < e; i += 256)
    atomicAdd(&hist[sedge_in[i].x >> 18], 1);
  __syncthreads();
  int v = hist[t];
  buf[t] = v;
  __syncthreads();
  for (int off = 1; off < 256; off <<= 1) {
    int add = (t >= off) ? buf[t - off] : 0;
    __syncthreads();
    buf[t] += add;
    __syncthreads();
  }
  int excl = buf[t] - v;
  curs[t] = excl;
  int row = tile * 256 + t;
  if (row < NODE_N) row_start[row] = s + excl;
  __syncthreads();
  for (int i = s + t; i < e; i += 256) {
    uint2 rec = sedge_in[i];
    int rl = rec.x >> 18;
    int p = atomicAdd(&curs[rl], 1);
    sedge_out[s + p] = make_uint2(rec.x & 0x3FFFFu, rec.y);
  }
}

// wave-per-row SpMM over sorted CSR: 16-lane float4 row gathers,
// up to 4 gathers in flight per thread (16 edges / wave iteration).
__global__ __launch_bounds__(256) void k_spmm(const float* __restrict__ E,
                                              const uint2* __restrict__ sedge,
                                              const int* __restrict__ row_start,
                                              float* __restrict__ side) {
  int r = blockIdx.x * 4 + (threadIdx.x >> 6);
  int lane = threadIdx.x & 63;
  int g = lane >> 4;
  int q = lane & 15;
  int rs = row_start[r], re = row_start[r + 1];
  float4 acc = make_float4(0.f, 0.f, 0.f, 0.f);
  int e = rs;
  for (; e + 16 <= re; e += 16) {
    uint2 e0 = sedge[e + g];
    uint2 e1 = sedge[e + 4 + g];
    uint2 e2 = sedge[e + 8 + g];
    uint2 e3 = sedge[e + 12 + g];
    float4 a0 = *(const float4*)&E[(size_t)e0.x * DD + q * 4];
    float4 a1 = *(const float4*)&E[(size_t)e1.x * DD + q * 4];
    float4 a2 = *(const float4*)&E[(size_t)e2.x * DD + q * 4];
    float4 a3 = *(const float4*)&E[(size_t)e3.x * DD + q * 4];
    float v0 = __uint_as_float(e0.y), v1 = __uint_as_float(e1.y);
    float v2 = __uint_as_float(e2.y), v3 = __uint_as_float(e3.y);
    acc.x = fmaf(v0, a0.x, acc.x); acc.y = fmaf(v0, a0.y, acc.y);
    acc.z = fmaf(v0, a0.z, acc.z); acc.w = fmaf(v0, a0.w, acc.w);
    acc.x = fmaf(v1, a1.x, acc.x); acc.y = fmaf(v1, a1.y, acc.y);
    acc.z = fmaf(v1, a1.z, acc.z); acc.w = fmaf(v1, a1.w, acc.w);
    acc.x = fmaf(v2, a2.x, acc.x); acc.y = fmaf(v2, a2.y, acc.y);
    acc.z = fmaf(v2, a2.z, acc.z); acc.w = fmaf(v2, a2.w, acc.w);
    acc.x = fmaf(v3, a3.x, acc.x); acc.y = fmaf(v3, a3.y, acc.y);
    acc.z = fmaf(v3, a3.z, acc.z); acc.w = fmaf(v3, a3.w, acc.w);
  }
  for (; e + 8 <= re; e += 8) {
    uint2 e0 = sedge[e + g];
    uint2 e1 = sedge[e + 4 + g];
    float4 a0 = *(const float4*)&E[(size_t)e0.x * DD + q * 4];
    float4 a1 = *(const float4*)&E[(size_t)e1.x * DD + q * 4];
    float v0 = __uint_as_float(e0.y), v1 = __uint_as_float(e1.y);
    acc.x = fmaf(v0, a0.x, acc.x); acc.y = fmaf(v0, a0.y, acc.y);
    acc.z = fmaf(v0, a0.z, acc.z); acc.w = fmaf(v0, a0.w, acc.w);
    acc.x = fmaf(v1, a1.x, acc.x); acc.y = fmaf(v1, a1.y, acc.y);
    acc.z = fmaf(v1, a1.z, acc.z); acc.w = fmaf(v1, a1.w, acc.w);
  }
  for (; e + 4 <= re; e += 4) {
    uint2 e0 = sedge[e + g];
    float4 a0 = *(const float4*)&E[(size_t)e0.x * DD + q * 4];
    float v0 = __uint_as_float(e0.y);
    acc.x = fmaf(v0, a0.x, acc.x); acc.y = fmaf(v0, a0.y, acc.y);
    acc.z = fmaf(v0, a0.z, acc.z); acc.w = fmaf(v0, a0.w, acc.w);
  }
  for (; e < re; ++e) {
    if (g == (e & 3)) {
      uint2 e0 = sedge[e];
      float4 a0 = *(const float4*)&E[(size_t)e0.x * DD + q * 4];
      float v0 = __uint_as_float(e0.y);
      acc.x = fmaf(v0, a0.x, acc.x); acc.y = fmaf(v0, a0.y, acc.y);
      acc.z = fmaf(v0, a0.z, acc.z); acc.w = fmaf(v0, a0.w, acc.w);
    }
  }
#pragma unroll
  for (int off = 16; off <= 32; off <<= 1) {
    acc.x += __shfl_xor(acc.x, off, 64);
    acc.y += __shfl_xor(acc.y, off, 64);
    acc.z += __shfl_xor(acc.z, off, 64);
    acc.w += __shfl_xor(acc.w, off, 64);
  }
  if (g == 0) *(float4*)&side[(size_t)r * DD + q * 4] = acc;
}

// Transform: weights held in VGPR columns, row vectors broadcast from LDS via b128.
#define TR_ROWS 16
#define TR_GRID 1875   /* 9375 chunks / 5 per block */
__global__ __launch_bounds__(256) void k_transform(const float* __restrict__ gw,
                                                   const float* __restrict__ gb,
                                                   const float* __restrict__ bw,
                                                   const float* __restrict__ bb,
                                                   float* __restrict__ E, float* __restrict__ Esum,
                                                   const float* __restrict__ side) {
  __shared__ float ss[TR_ROWS][64];
  __shared__ float pp[TR_ROWS][64];
  int t = threadIdx.x;
  int lane = t & 63;
  int wv = t >> 6;
  float wgr[64], wbr[64];
#pragma unroll
  for (int k = 0; k < 64; ++k) {
    wgr[k] = gw[k * 64 + lane];
    wbr[k] = bw[k * 64 + lane];
  }
  float gbl = gb[lane], bbl = bb[lane];
  const int nchunks = NODE_N / TR_ROWS;  // 9375
  for (int chunk = blockIdx.x; chunk < nchunks; chunk += TR_GRID) {
    int r0 = chunk * TR_ROWS;
    {
      int row = t >> 4;
      int col = (t & 15) * 4;
      float4 sv = *(const float4*)&side[(size_t)(r0 + row) * 64 + col];
      float4 ev = *(const float4*)&E[(size_t)(r0 + row) * 64 + col];
      *(float4*)&ss[row][col] = sv;
      pp[row][col + 0] = sv.x * ev.x;
      pp[row][col + 1] = sv.y * ev.y;
      pp[row][col + 2] = sv.z * ev.z;
      pp[row][col + 3] = sv.w * ev.w;
    }
    __syncthreads();
#pragma unroll
    for (int rr = 0; rr < 4; ++rr) {
      int row = wv + rr * 4;
      float a10 = 0.f, a11 = 0.f, a12 = 0.f, a13 = 0.f;
      float a20 = 0.f, a21 = 0.f, a22 = 0.f, a23 = 0.f;
#pragma unroll
      for (int k = 0; k < 64; k += 4) {
        float4 s4 = *(const float4*)&ss[row][k];
        float4 p4 = *(const float4*)&pp[row][k];
        a10 = fmaf(s4.x, wgr[k + 0], a10);
        a11 = fmaf(s4.y, wgr[k + 1], a11);
        a12 = fmaf(s4.z, wgr[k + 2], a12);
        a13 = fmaf(s4.w, wgr[k + 3], a13);
        a20 = fmaf(p4.x, wbr[k + 0], a20);
        a21 = fmaf(p4.y, wbr[k + 1], a21);
        a22 = fmaf(p4.z, wbr[k + 2], a22);
        a23 = fmaf(p4.w, wbr[k + 3], a23);
      }
      float a1 = gbl + ((a10 + a11) + (a12 + a13));
      float a2 = bbl + ((a20 + a21) + (a22 + a23));
      a1 = (a1 > 0.f) ? a1 : 0.01f * a1;
      a2 = (a2 > 0.f) ? a2 : 0.01f * a2;
      float v = a1 + a2;
      float sq = v * v;
#pragma unroll
      for (int off = 32; off; off >>= 1) sq += __shfl_xor(sq, off, 64);
      v = v / fmaxf(sqrtf(sq), 1e-12f);
      size_t o = (size_t)(r0 + row) * 64 + lane;
      E[o] = v;
      Esum[o] += v;
    }
    __syncthreads();
  }
}

__global__ __launch_bounds__(128) void k_gather(const float* __restrict__ Esum,
                                                const int* __restrict__ uid,
                                                const int* __restrict__ iid,
                                                float* __restrict__ ue, float* __restrict__ ie) {
  int b = blockIdx.x, t = threadIdx.x;
  if (t < 64) ue[(size_t)b * 64 + t] = Esum[(size_t)uid[b] * 64 + t];
  else {
    int d = t - 64;
    ie[(size_t)b * 64 + d] = Esum[(size_t)(USER_N + iid[b]) * 64 + d];
  }
}

__global__ __launch_bounds__(256) void k_encoder(const float* __restrict__ xin,
                                                 const float* __restrict__ hw, const float* __restrict__ hb,
                                                 const float* __restrict__ w1, const float* __restrict__ b1,
                                                 const float* __restrict__ w2, const float* __restrict__ b2,
                                                 float* __restrict__ recs) {
  __shared__ float sx[64], sreps[64], st[256];
  int b = blockIdx.x, l = blockIdx.y, t = threadIdx.x;
  if (t < 64) sx[t] = xin[(size_t)b * 64 + t];
  __syncthreads();
  if (t < 64) {
    const float* W = hw + l * 64 * 64;
    float a = hb[l * 64 + t];
#pragma unroll 8
    for (int k = 0; k < 64; ++k) a += sx[k] * W[k * 64 + t];
    sreps[t] = tanhf(a);
  }
  __syncthreads();
  {
    const float* W = w1 + l * 64 * 256;
    float a = b1[l * 256 + t];
#pragma unroll 8
    for (int k = 0; k < 64; ++k) a += sreps[k] * W[k * 256 + t];
    st[t] = tanhf(a);
  }
  __syncthreads();
  if (t < 32) {
    const float* W = w2 + l * 256 * 32;
    float a = b2[l * 32 + t];
#pragma unroll 8
    for (int k = 0; k < 256; ++k) a += st[k] * W[k * 32 + t];
    recs[((size_t)l * BB + b) * 32 + t] = a;
  }
}

__global__ __launch_bounds__(256) void k_attn(const float* __restrict__ recs,
                                              const float* __restrict__ qw, const float* __restrict__ qb,
                                              const float* __restrict__ kw, const float* __restrict__ kb,
                                              const float* __restrict__ vw, const float* __restrict__ vb,
                                              float* __restrict__ att) {
  int t = threadIdx.x;
  int b = blockIdx.x * 8 + (t >> 5);
  int d = t & 31;
  float x0 = recs[((size_t)0 * BB + b) * 32 + d];
  float x1 = recs[((size_t)1 * BB + b) * 32 + d];
  float x2 = recs[((size_t)2 * BB + b) * 32 + d];
  float q0 = qb[d], q1 = q0, q2 = q0;
  float c0 = kb[d], c1 = c0, c2 = c0;
  float v0 = vb[d], v1 = v0, v2 = v0;
#pragma unroll 4
  for (int kk = 0; kk < 32; ++kk) {
    float xa = __shfl(x0, kk, 32);
    float xb = __shfl(x1, kk, 32);
    float xc = __shfl(x2, kk, 32);
    float wq = qw[kk * 32 + d], wk = kw[kk * 32 + d], wv = vw[kk * 32 + d];
    q0 += xa * wq; q1 += xb * wq; q2 += xc * wq;
    c0 += xa * wk; c1 += xb * wk; c2 += xc * wk;
    v0 += xa * wv; v1 += xb * wv; v2 += xc * wv;
  }
  float qs[3] = {q0, q1, q2}, ks[3] = {c0, c1, c2}, vs[3] = {v0, v1, v2};
  float sc[3][3];
#pragma unroll
  for (int s = 0; s < 3; ++s)
#pragma unroll
    for (int u = 0; u < 3; ++u) {
      float p = qs[s] * ks[u];
#pragma unroll
      for (int off = 16; off; off >>= 1) p += __shfl_xor(p, off, 32);
      sc[s][u] = p * 0.17677669529663687f;  // 1/sqrt(32)
    }
#pragma unroll
  for (int s = 0; s < 3; ++s) {
    float m = fmaxf(sc[s][0], fmaxf(sc[s][1], sc[s][2]));
    float e0 = __expf(sc[s][0] - m), e1 = __expf(sc[s][1] - m), e2 = __expf(sc[s][2] - m);
    float inv = 1.f / (e0 + e1 + e2);
    att[(size_t)b * 96 + s * 32 + d] = (e0 * vs[0] + e1 * vs[1] + e2 * vs[2]) * inv;
  }
}

__global__ __launch_bounds__(256) void k_noise(const float* __restrict__ att_u,
                                               const float* __restrict__ att_i,
                                               uint32_t ku0, uint32_t ku1, uint32_t ki0, uint32_t ki1,
                                               float* __restrict__ n1, float* __restrict__ n2,
                                               float* __restrict__ posdot) {
  int t = threadIdx.x;
  int g = blockIdx.x * 8 + (t >> 5);   // [0, 24576)
  int k = t & 31;
  int side = g / (NLV * BB);
  int rem = g - side * (NLV * BB);
  int l = rem >> 12;
  int b = rem & 4095;
  const float* att = side ? att_i : att_u;
  uint32_t ka = side ? ki0 : ku0;
  uint32_t kb = side ? ki1 : ku1;
  float r = att[(size_t)b * 96 + l * 32 + k];
  float ss = r * r;
#pragma unroll
  for (int off = 16; off; off >>= 1) ss += __shfl_xor(ss, off, 32);
  float v1 = r / fmaxf(sqrtf(ss), 1e-12f);
  uint32_t m = ((uint32_t)(l * BB + b)) * 32u + (uint32_t)k;
  float u = tf_uniform(ka, kb, m);
  float us = u * u;
#pragma unroll
  for (int off = 16; off; off >>= 1) us += __shfl_xor(us, off, 32);
  float un = u / fmaxf(sqrtf(us), 1e-12f);
  float sgn = (r > 0.f) ? 1.f : ((r < 0.f) ? -1.f : 0.f);
  float rn = r + sgn * un * 0.1f;
  float s2 = rn * rn;
#pragma unroll
  for (int off = 16; off; off >>= 1) s2 += __shfl_xor(s2, off, 32);
  float v2 = rn / fmaxf(sqrtf(s2), 1e-12f);
  float pd = v1 * v2;
#pragma unroll
  for (int off = 16; off; off >>= 1) pd += __shfl_xor(pd, off, 32);
  size_t o = (size_t)g * 32 + k;
  n1[o] = v1;
  n2[o] = v2;
  if (k == 0) posdot[g] = pd;
}

// ttl: per-slice [4096 x 4096] exp(dot/tau) row-sums.
// 2 i-rows per thread share each staged j-chunk read.
__global__ __launch_bounds__(256) void k_ttl(const float* __restrict__ n1,
                                             const float* __restrict__ n2,
                                             float* __restrict__ ttl) {
  __shared__ float4 sj[128][8];
  int sl = blockIdx.z;
  int t = threadIdx.x;
  int ia = blockIdx.x * 512 + t;
  int ib = ia + 256;
  const float* n1b = n1 + (size_t)sl * BB * 32;
  const float* n2b = n2 + (size_t)sl * BB * 32;
  float4 ra[8], rb[8];
#pragma unroll
  for (int k = 0; k < 8; ++k) {
    ra[k] = *(const float4*)&n1b[(size_t)ia * 32 + k * 4];
    rb[k] = *(const float4*)&n1b[(size_t)ib * 32 + k * 4];
  }
  float acca = 0.f, accb = 0.f;
  for (int jc = 0; jc < 2; ++jc) {
    int j0 = blockIdx.y * 256 + jc * 128;
    __syncthreads();
    for (int idx = t; idx < 128 * 8; idx += 256) {
      int jj = idx >> 3, kk = idx & 7;
      sj[jj][kk] = *(const float4*)&n2b[(size_t)(j0 + jj) * 32 + kk * 4];
    }
    __syncthreads();
    for (int j = 0; j < 128; ++j) {
      float a0 = 0.f, a1 = 0.f, a2 = 0.f, a3 = 0.f;
      float b0 = 0.f, b1 = 0.f, b2 = 0.f, b3 = 0.f;
#pragma unroll
      for (int k = 0; k < 8; ++k) {
        float4 sv = sj[j][k];
        a0 = fmaf(ra[k].x, sv.x, a0);
        a1 = fmaf(ra[k].y, sv.y, a1);
        a2 = fmaf(ra[k].z, sv.z, a2);
        a3 = fmaf(ra[k].w, sv.w, a3);
        b0 = fmaf(rb[k].x, sv.x, b0);
        b1 = fmaf(rb[k].y, sv.y, b1);
        b2 = fmaf(rb[k].z, sv.z, b2);
        b3 = fmaf(rb[k].w, sv.w, b3);
      }
      acca += __expf(((a0 + a1) + (a2 + a3)) * 5.0f);  // 1/TAU = 5
      accb += __expf(((b0 + b1) + (b2 + b3)) * 5.0f);
    }
  }
  atomicAdd(&ttl[sl * BB + ia], acca);
  atomicAdd(&ttl[sl * BB + ib], accb);
}

__global__ __launch_bounds__(1024) void k_clred(const float* __restrict__ ttl,
                                                const float* __restrict__ posdot,
                                                float* __restrict__ outp) {
  __shared__ float red[1024];
  int t = threadIdx.x;
  float a = 0.f;
  for (int idx = t; idx < 6 * BB; idx += 1024)
    a += logf(ttl[idx]) - posdot[idx] * 5.0f;
  red[t] = a;
  __syncthreads();
  for (int off = 512; off; off >>= 1) {
    if (t < off) red[t] += red[t + off];
    __syncthreads();
  }
  if (t == 0) outp[2 * BB] = red[0] * (1.f / 12288.f);  // (cl_u + cl_i)
}

__global__ __launch_bounds__(256) void k_head(const float* __restrict__ att_u,
                                              const float* __restrict__ att_i,
                                              const float* __restrict__ skills,
                                              const float* __restrict__ w1, const float* __restrict__ b1,
                                              const float* __restrict__ w2, const float* __restrict__ b2,
                                              const float* __restrict__ pw, const float* __restrict__ pb,
                                              float* __restrict__ outp) {
  __shared__ float diag[4][96], t1[4][64];
  int t = threadIdx.x;
  int w = t >> 6, lane = t & 63;
  int b = blockIdx.x * 4 + w;
  for (int j = lane; j < 96; j += 64) {
    float su = 1.f / (1.f + __expf(-att_u[(size_t)b * 96 + j]));
    float si = 1.f / (1.f + __expf(-att_i[(size_t)b * 96 + j]));
    diag[w][j] = (su - si) * skills[(size_t)b * 96 + j];
  }
  __syncthreads();
  float a = b1[lane];
#pragma unroll 8
  for (int j = 0; j < 96; ++j) a += diag[w][j] * w1[j * 64 + lane];
  t1[w][lane] = tanhf(a);
  __syncthreads();
  float h = b2[lane];
#pragma unroll 8
  for (int kk = 0; kk < 64; ++kk) h += t1[w][kk] * w2[kk * 64 + lane];
  float p0 = h * pw[lane * 2 + 0];
  float p1 = h * pw[lane * 2 + 1];
#pragma unroll
  for (int off = 32; off; off >>= 1) {
    p0 += __shfl_xor(p0, off, 64);
    p1 += __shfl_xor(p1, off, 64);
  }
  if (lane == 0) {
    float l0 = p0 + pb[0], l1 = p1 + pb[1];
    float m = fmaxf(l0, l1);
    float e0 = __expf(l0 - m), e1 = __expf(l1 - m);
    float inv = 1.f / (e0 + e1);
    outp[(size_t)b * 2 + 0] = e0 * inv;
    outp[(size_t)b * 2 + 1] = e1 * inv;
  }
}

// ---------------- launcher ----------------
extern "C" void kernel_launch(void* const* d_in, const int* in_sizes, int n_in,
                              void* d_out, int out_size, void* d_ws, size_t ws_size,
                              hipStream_t stream) {
  const float* ego    = (const float*)d_in[0];
  const float* gc_w   = (const float*)d_in[1];
  const float* gc_b   = (const float*)d_in[2];
  const float* bi_w   = (const float*)d_in[3];
  const float* bi_b   = (const float*)d_in[4];
  const float* uh_w   = (const float*)d_in[5];
  const float* uh_b   = (const float*)d_in[6];
  const float* ih_w   = (const float*)d_in[7];
  const float* ih_b   = (const float*)d_in[8];
  const float* ud_w1  = (const float*)d_in[9];
  const float* ud_b1  = (const float*)d_in[10];
  const float* ud_w2  = (const float*)d_in[11];
  const float* ud_b2  = (const float*)d_in[12];
  const float* id_w1  = (const float*)d_in[13];
  const float* id_b1  = (const float*)d_in[14];
  const float* id_w2  = (const float*)d_in[15];
  const float* id_b2  = (const float*)d_in[16];
  const float* q_w    = (const float*)d_in[17];
  const float* q_b    = (const float*)d_in[18];
  const float* k_w    = (const float*)d_in[19];
  const float* k_b    = (const float*)d_in[20];
  const float* v_w    = (const float*)d_in[21];
  const float* v_b    = (const float*)d_in[22];
  const float* dg_w1  = (const float*)d_in[23];
  const float* dg_b1  = (const float*)d_in[24];
  const float* dg_w2  = (const float*)d_in[25];
  const float* dg_b2  = (const float*)d_in[26];
  const float* pr_w   = (const float*)d_in[27];
  const float* pr_b   = (const float*)d_in[28];
  const float* adj_vals = (const float*)d_in[29];
  const float* skills = (const float*)d_in[30];
  const int* user_id  = (const int*)d_in[31];
  const int* item_id  = (const int*)d_in[32];
  const int* adj_rows = (const int*)d_in[33];
  const int* adj_cols = (const int*)d_in[34];
  float* outp = (float*)d_out;

  char* w = (char*)d_ws;
  auto alloc = [&](size_t bytes) -> char* {
    char* p = w;
    w += (bytes + 255) & ~(size_t)255;
    return p;
  };
  float* E      = (float*)alloc((size_t)NODE_N * DD * 4);
  float* Esum   = (float*)alloc((size_t)NODE_N * DD * 4);
  float* side   = (float*)alloc((size_t)NODE_N * DD * 4);
  uint2* sedge_r= (uint2*)alloc((size_t)NNZE * 8);   // tile-bucketed
  uint2* sedge  = (uint2*)alloc((size_t)NNZE * 8);   // row-sorted CSR
  int*   hist   = (int*)  alloc((size_t)NTILE * 16 * 4);
  int*   tile_start = (int*)alloc((size_t)(NTILE + 1) * 4);
  int*   cursor = (int*)  alloc((size_t)NTILE * 16 * 4);
  int*   row_start = (int*)alloc((size_t)(NODE_N + 1) * 4);
  float* ue     = (float*)alloc((size_t)BB * 64 * 4);
  float* ie     = (float*)alloc((size_t)BB * 64 * 4);
  float* recs_u = (float*)alloc((size_t)NLV * BB * 32 * 4);
  float* recs_i = (float*)alloc((size_t)NLV * BB * 32 * 4);
  float* att_u  = (float*)alloc((size_t)BB * 96 * 4);
  float* att_i  = (float*)alloc((size_t)BB * 96 * 4);
  float* n1     = (float*)alloc((size_t)6 * BB * 32 * 4);
  float* n2     = (float*)alloc((size_t)6 * BB * 32 * 4);
  float* posdot = (float*)alloc((size_t)6 * BB * 4);
  float* ttl    = (float*)alloc((size_t)6 * BB * 4);

  // host-side: kc = jax.random.split(jax.random.key(42), 2)
  uint32_t a0 = 0, a1 = 2, b0 = 1, b1 = 3;
  tf_block(0u, 42u, a0, a1);
  tf_block(0u, 42u, b0, b1);
  uint32_t ku0 = a0, ku1 = b0;   // kc[0] -> u side
  uint32_t ki0 = a1, ki1 = b1;   // kc[1] -> i side

  hipMemsetAsync(hist, 0, (size_t)NTILE * 16 * 4, stream);
  hipMemsetAsync(ttl, 0, (size_t)6 * BB * 4, stream);

  k_init<<<9375, 256, 0, stream>>>(ego, E, Esum);
  k_hist_t<<<9375, 256, 0, stream>>>(adj_rows, hist);
  k_scan_t<<<1, 1024, 0, stream>>>(hist, tile_start, cursor, row_start);
  k_scatter_t<<<9375, 256, 0, stream>>>(adj_rows, adj_cols, adj_vals, cursor, sedge_r);
  k_sort_t<<<NTILE, 256, 0, stream>>>(sedge_r, tile_start, sedge, row_start);

  for (int l = 0; l < 2; ++l) {
    k_spmm<<<37500, 256, 0, stream>>>(E, sedge, row_start, side);
    k_transform<<<TR_GRID, 256, 0, stream>>>(gc_w + l * 4096, gc_b + l * 64,
                                             bi_w + l * 4096, bi_b + l * 64,
                                             E, Esum, side);
  }

  k_gather<<<4096, 128, 0, stream>>>(Esum, user_id, item_id, ue, ie);

  dim3 ge(4096, 3);
  k_encoder<<<ge, 256, 0, stream>>>(ue, uh_w, uh_b, ud_w1, ud_b1, ud_w2, ud_b2, recs_u);
  k_encoder<<<ge, 256, 0, stream>>>(ie, ih_w, ih_b, id_w1, id_b1, id_w2, id_b2, recs_i);

  k_attn<<<512, 256, 0, stream>>>(recs_u, q_w, q_b, k_w, k_b, v_w, v_b, att_u);
  k_attn<<<512, 256, 0, stream>>>(recs_i, q_w, q_b, k_w, k_b, v_w, v_b, att_i);

  k_noise<<<3072, 256, 0, stream>>>(att_u, att_i, ku0, ku1, ki0, ki1, n1, n2, posdot);

  dim3 gt(8, 16, 6);
  k_ttl<<<gt, 256, 0, stream>>>(n1, n2, ttl);
  k_clred<<<1, 1024, 0, stream>>>(ttl, posdot, outp);

  k_head<<<1024, 256, 0, stream>>>(att_u, att_i, skills, dg_w1, dg_b1, dg_w2, dg_b2,
                                   pr_w, pr_b, outp);
}

// Round 6
// 1059.176 us; speedup vs baseline: 2.8452x; 1.1335x over previous
//
#include <hip/hip_runtime.h>
#include <stdint.h>
#include <math.h>

#define USER_N 100000
#define NODE_N 150000
#define DD 64
#define NNZE 2400000
#define BB 4096
#define NLV 3
#define LF 32
#define HALF_SZ 196608u  /* (3*4096*32)/2 */
#define NTILE 586        /* ceil(150000/256) */
#define NVX 8            /* virtual-XCD sub-buckets per tile */
#define NENT (NTILE * NVX)

// ---------------- threefry2x32 (JAX original mode) ----------------
__host__ __device__ inline void tf_block(uint32_t k0, uint32_t k1, uint32_t& x0, uint32_t& x1) {
  uint32_t ks[3] = {k0, k1, k0 ^ k1 ^ 0x1BD11BDAu};
  x0 += ks[0]; x1 += ks[1];
  const int R0[4] = {13, 15, 26, 6};
  const int R1[4] = {17, 29, 16, 24};
#pragma unroll
  for (int i = 0; i < 5; ++i) {
    const int* R = (i & 1) ? R1 : R0;
#pragma unroll
    for (int j = 0; j < 4; ++j) {
      x0 += x1;
      x1 = (x1 << R[j]) | (x1 >> (32 - R[j]));
      x1 ^= x0;
    }
    x0 += ks[(i + 1) % 3];
    x1 += ks[(i + 2) % 3] + (uint32_t)(i + 1);
  }
}

__device__ inline float tf_uniform(uint32_t ka, uint32_t kb, uint32_t m) {
  uint32_t x0, x1;
  bool first = m < HALF_SZ;
  if (first) { x0 = m; x1 = m + HALF_SZ; } else { x0 = m - HALF_SZ; x1 = m; }
  tf_block(ka, kb, x0, x1);
  uint32_t bits = first ? x0 : x1;
  return __uint_as_float((bits >> 9) | 0x3f800000u) - 1.0f;
}

// bf16 round-to-nearest-even
__device__ inline unsigned short f2bf(float x) {
  uint32_t b = __float_as_uint(x);
  return (unsigned short)((b + 0x7FFFu + ((b >> 16) & 1u)) >> 16);
}

// ---------------- kernels ----------------
__global__ __launch_bounds__(256) void k_init(const float* __restrict__ ego,
                                              float* __restrict__ E, float* __restrict__ Esum,
                                              unsigned short* __restrict__ E16) {
  int i = blockIdx.x * 256 + threadIdx.x;  // float4 index
  float4 v = ((const float4*)ego)[i];
  ((float4*)E)[i] = v;
  ((float4*)Esum)[i] = v;
  ushort4 h;
  h.x = f2bf(v.x); h.y = f2bf(v.y); h.z = f2bf(v.z); h.w = f2bf(v.w);
  ((ushort4*)E16)[i] = h;
}

// per-(tile, virtual-XCD) histogram; counters padded to one per 64B line
__global__ __launch_bounds__(256) void k_hist_t(const int* __restrict__ rows,
                                                int* __restrict__ hist) {
  int e = blockIdx.x * 256 + threadIdx.x;
  int vx = blockIdx.x & (NVX - 1);
  if (e < NNZE) atomicAdd(&hist[((rows[e] >> 8) * NVX + vx) * 16], 1);
}

// single-block scan over 4688 (tile,vx) counts -> tile_start + per-entry cursors
__global__ __launch_bounds__(1024) void k_scan_t(const int* __restrict__ hist,
                                                 int* __restrict__ tile_start,
                                                 int* __restrict__ cursor,
                                                 int* __restrict__ row_start) {
  __shared__ int buf[1024];
  int t = threadIdx.x;
  int base = t * 5;
  int loc[5];
  int sum = 0;
#pragma unroll
  for (int j = 0; j < 5; ++j) {
    int idx = base + j;
    int v = (idx < NENT) ? hist[idx * 16] : 0;
    loc[j] = sum;
    sum += v;
  }
  buf[t] = sum;
  __syncthreads();
  for (int off = 1; off < 1024; off <<= 1) {
    int add = (t >= off) ? buf[t - off] : 0;
    __syncthreads();
    buf[t] += add;
    __syncthreads();
  }
  int tbase = (t > 0) ? buf[t - 1] : 0;
#pragma unroll
  for (int j = 0; j < 5; ++j) {
    int idx = base + j;
    if (idx < NENT) {
      int excl = tbase + loc[j];
      cursor[idx * 16] = excl;
      if ((idx & (NVX - 1)) == 0) tile_start[idx / NVX] = excl;
    }
  }
  if (t == 0) { tile_start[NTILE] = NNZE; row_start[NODE_N] = NNZE; }
}

// bucket edges by (256-row tile, virtual XCD). With round-robin block->XCD
// dispatch, each sub-segment's write frontier is touched by ONE XCD's L2 ->
// lines fully populated before a single writeback (fixes r5's 132MB partial-
// line writeback traffic; per-XCD L2s are not coherent).
__global__ __launch_bounds__(256) void k_scatter_t(const int* __restrict__ rows,
                                                   const int* __restrict__ cols,
                                                   const float* __restrict__ vals,
                                                   int* __restrict__ cursor,
                                                   uint2* __restrict__ sedge) {
  int e = blockIdx.x * 256 + threadIdx.x;
  int vx = blockIdx.x & (NVX - 1);
  if (e < NNZE) {
    int r = rows[e];
    uint32_t rl = (uint32_t)(r & 255);
    int p = atomicAdd(&cursor[((r >> 8) * NVX + vx) * 16], 1);
    sedge[p] = make_uint2((uint32_t)cols[e] | (rl << 18), __float_as_uint(vals[e]));
  }
}

// per-tile 256-bin counting sort: bucketed records -> row-sorted CSR (+ row_start).
__global__ __launch_bounds__(256) void k_sort_t(const uint2* __restrict__ sedge_in,
                                                const int* __restrict__ tile_start,
                                                uint2* __restrict__ sedge_out,
                                                int* __restrict__ row_start) {
  __shared__ int hist[256], buf[256], curs[256];
  int t = threadIdx.x;
  int tile = blockIdx.x;
  int s = tile_start[tile], e = tile_start[tile + 1];
  hist[t] = 0;
  __syncthreads();
  for (int i = s + t; i < e; i += 256)
    atomicAdd(&hist[sedge_in[i].x >> 18], 1);
  __syncthreads();
  int v = hist[t];
  buf[t] = v;
  __syncthreads();
  for (int off = 1; off < 256; off <<= 1) {
    int add = (t >= off) ? buf[t - off] : 0;
    __syncthreads();
    buf[t] += add;
    __syncthreads();
  }
  int excl = buf[t] - v;
  curs[t] = excl;
  int row = tile * 256 + t;
  if (row < NODE_N) row_start[row] = s + excl;
  __syncthreads();
  for (int i = s + t; i < e; i += 256) {
    uint2 rec = sedge_in[i];
    int rl = rec.x >> 18;
    int p = atomicAdd(&curs[rl], 1);
    sedge_out[s + p] = make_uint2(rec.x & 0x3FFFFu, rec.y);
  }
}

// wave-per-row SpMM over sorted CSR, bf16 E rows (128B/row, half of fp32).
// 16-lane uint2 gathers; subgroup g = lane>>4 picks the edge, q = lane&15
// covers elements 4q..4q+3. Accumulation fp32.
__global__ __launch_bounds__(256) void k_spmm(const unsigned short* __restrict__ E16,
                                              const uint2* __restrict__ sedge,
                                              const int* __restrict__ row_start,
                                              float* __restrict__ side) {
  const uint2* E2 = (const uint2*)E16;  // 16 uint2 per row
  int r = blockIdx.x * 4 + (threadIdx.x >> 6);
  int lane = threadIdx.x & 63;
  int g = lane >> 4;
  int q = lane & 15;
  int rs = row_start[r], re = row_start[r + 1];
  float4 acc = make_float4(0.f, 0.f, 0.f, 0.f);
  int e = rs;
#define BF_FMA(rec, a)                                                        \
  {                                                                           \
    float vv = __uint_as_float(rec.y);                                        \
    acc.x = fmaf(vv, __uint_as_float(a.x << 16), acc.x);                      \
    acc.y = fmaf(vv, __uint_as_float(a.x & 0xFFFF0000u), acc.y);              \
    acc.z = fmaf(vv, __uint_as_float(a.y << 16), acc.z);                      \
    acc.w = fmaf(vv, __uint_as_float(a.y & 0xFFFF0000u), acc.w);              \
  }
  for (; e + 16 <= re; e += 16) {
    uint2 e0 = sedge[e + g];
    uint2 e1 = sedge[e + 4 + g];
    uint2 e2 = sedge[e + 8 + g];
    uint2 e3 = sedge[e + 12 + g];
    uint2 a0 = E2[(size_t)e0.x * 16 + q];
    uint2 a1 = E2[(size_t)e1.x * 16 + q];
    uint2 a2 = E2[(size_t)e2.x * 16 + q];
    uint2 a3 = E2[(size_t)e3.x * 16 + q];
    BF_FMA(e0, a0) BF_FMA(e1, a1) BF_FMA(e2, a2) BF_FMA(e3, a3)
  }
  for (; e + 8 <= re; e += 8) {
    uint2 e0 = sedge[e + g];
    uint2 e1 = sedge[e + 4 + g];
    uint2 a0 = E2[(size_t)e0.x * 16 + q];
    uint2 a1 = E2[(size_t)e1.x * 16 + q];
    BF_FMA(e0, a0) BF_FMA(e1, a1)
  }
  for (; e + 4 <= re; e += 4) {
    uint2 e0 = sedge[e + g];
    uint2 a0 = E2[(size_t)e0.x * 16 + q];
    BF_FMA(e0, a0)
  }
  for (; e < re; ++e) {
    if (g == (e & 3)) {
      uint2 e0 = sedge[e];
      uint2 a0 = E2[(size_t)e0.x * 16 + q];
      BF_FMA(e0, a0)
    }
  }
#undef BF_FMA
#pragma unroll
  for (int off = 16; off <= 32; off <<= 1) {
    acc.x += __shfl_xor(acc.x, off, 64);
    acc.y += __shfl_xor(acc.y, off, 64);
    acc.z += __shfl_xor(acc.z, off, 64);
    acc.w += __shfl_xor(acc.w, off, 64);
  }
  if (g == 0) *(float4*)&side[(size_t)r * DD + q * 4] = acc;
}

// Transform: weights held in VGPR columns, row vectors broadcast from LDS via b128.
#define TR_ROWS 16
#define TR_GRID 1875   /* 9375 chunks / 5 per block */
__global__ __launch_bounds__(256) void k_transform(const float* __restrict__ gw,
                                                   const float* __restrict__ gb,
                                                   const float* __restrict__ bw,
                                                   const float* __restrict__ bb,
                                                   float* __restrict__ E, float* __restrict__ Esum,
                                                   unsigned short* __restrict__ E16,
                                                   const float* __restrict__ side) {
  __shared__ float ss[TR_ROWS][64];
  __shared__ float pp[TR_ROWS][64];
  int t = threadIdx.x;
  int lane = t & 63;
  int wv = t >> 6;
  float wgr[64], wbr[64];
#pragma unroll
  for (int k = 0; k < 64; ++k) {
    wgr[k] = gw[k * 64 + lane];
    wbr[k] = bw[k * 64 + lane];
  }
  float gbl = gb[lane], bbl = bb[lane];
  const int nchunks = NODE_N / TR_ROWS;  // 9375
  for (int chunk = blockIdx.x; chunk < nchunks; chunk += TR_GRID) {
    int r0 = chunk * TR_ROWS;
    {
      int row = t >> 4;
      int col = (t & 15) * 4;
      float4 sv = *(const float4*)&side[(size_t)(r0 + row) * 64 + col];
      float4 ev = *(const float4*)&E[(size_t)(r0 + row) * 64 + col];
      *(float4*)&ss[row][col] = sv;
      pp[row][col + 0] = sv.x * ev.x;
      pp[row][col + 1] = sv.y * ev.y;
      pp[row][col + 2] = sv.z * ev.z;
      pp[row][col + 3] = sv.w * ev.w;
    }
    __syncthreads();
#pragma unroll
    for (int rr = 0; rr < 4; ++rr) {
      int row = wv + rr * 4;
      float a10 = 0.f, a11 = 0.f, a12 = 0.f, a13 = 0.f;
      float a20 = 0.f, a21 = 0.f, a22 = 0.f, a23 = 0.f;
#pragma unroll
      for (int k = 0; k < 64; k += 4) {
        float4 s4 = *(const float4*)&ss[row][k];
        float4 p4 = *(const float4*)&pp[row][k];
        a10 = fmaf(s4.x, wgr[k + 0], a10);
        a11 = fmaf(s4.y, wgr[k + 1], a11);
        a12 = fmaf(s4.z, wgr[k + 2], a12);
        a13 = fmaf(s4.w, wgr[k + 3], a13);
        a20 = fmaf(p4.x, wbr[k + 0], a20);
        a21 = fmaf(p4.y, wbr[k + 1], a21);
        a22 = fmaf(p4.z, wbr[k + 2], a22);
        a23 = fmaf(p4.w, wbr[k + 3], a23);
      }
      float a1 = gbl + ((a10 + a11) + (a12 + a13));
      float a2 = bbl + ((a20 + a21) + (a22 + a23));
      a1 = (a1 > 0.f) ? a1 : 0.01f * a1;
      a2 = (a2 > 0.f) ? a2 : 0.01f * a2;
      float v = a1 + a2;
      float sq = v * v;
#pragma unroll
      for (int off = 32; off; off >>= 1) sq += __shfl_xor(sq, off, 64);
      v = v / fmaxf(sqrtf(sq), 1e-12f);
      size_t o = (size_t)(r0 + row) * 64 + lane;
      E[o] = v;
      E16[o] = f2bf(v);
      Esum[o] += v;
    }
    __syncthreads();
  }
}

__global__ __launch_bounds__(128) void k_gather(const float* __restrict__ Esum,
                                                const int* __restrict__ uid,
                                                const int* __restrict__ iid,
                                                float* __restrict__ ue, float* __restrict__ ie) {
  int b = blockIdx.x, t = threadIdx.x;
  if (t < 64) ue[(size_t)b * 64 + t] = Esum[(size_t)uid[b] * 64 + t];
  else {
    int d = t - 64;
    ie[(size_t)b * 64 + d] = Esum[(size_t)(USER_N + iid[b]) * 64 + d];
  }
}

__global__ __launch_bounds__(256) void k_encoder(const float* __restrict__ xin,
                                                 const float* __restrict__ hw, const float* __restrict__ hb,
                                                 const float* __restrict__ w1, const float* __restrict__ b1,
                                                 const float* __restrict__ w2, const float* __restrict__ b2,
                                                 float* __restrict__ recs) {
  __shared__ float sx[64], sreps[64], st[256];
  int b = blockIdx.x, l = blockIdx.y, t = threadIdx.x;
  if (t < 64) sx[t] = xin[(size_t)b * 64 + t];
  __syncthreads();
  if (t < 64) {
    const float* W = hw + l * 64 * 64;
    float a = hb[l * 64 + t];
#pragma unroll 8
    for (int k = 0; k < 64; ++k) a += sx[k] * W[k * 64 + t];
    sreps[t] = tanhf(a);
  }
  __syncthreads();
  {
    const float* W = w1 + l * 64 * 256;
    float a = b1[l * 256 + t];
#pragma unroll 8
    for (int k = 0; k < 64; ++k) a += sreps[k] * W[k * 256 + t];
    st[t] = tanhf(a);
  }
  __syncthreads();
  if (t < 32) {
    const float* W = w2 + l * 256 * 32;
    float a = b2[l * 32 + t];
#pragma unroll 8
    for (int k = 0; k < 256; ++k) a += st[k] * W[k * 32 + t];
    recs[((size_t)l * BB + b) * 32 + t] = a;
  }
}

__global__ __launch_bounds__(256) void k_attn(const float* __restrict__ recs,
                                              const float* __restrict__ qw, const float* __restrict__ qb,
                                              const float* __restrict__ kw, const float* __restrict__ kb,
                                              const float* __restrict__ vw, const float* __restrict__ vb,
                                              float* __restrict__ att) {
  int t = threadIdx.x;
  int b = blockIdx.x * 8 + (t >> 5);
  int d = t & 31;
  float x0 = recs[((size_t)0 * BB + b) * 32 + d];
  float x1 = recs[((size_t)1 * BB + b) * 32 + d];
  float x2 = recs[((size_t)2 * BB + b) * 32 + d];
  float q0 = qb[d], q1 = q0, q2 = q0;
  float c0 = kb[d], c1 = c0, c2 = c0;
  float v0 = vb[d], v1 = v0, v2 = v0;
#pragma unroll 4
  for (int kk = 0; kk < 32; ++kk) {
    float xa = __shfl(x0, kk, 32);
    float xb = __shfl(x1, kk, 32);
    float xc = __shfl(x2, kk, 32);
    float wq = qw[kk * 32 + d], wk = kw[kk * 32 + d], wv = vw[kk * 32 + d];
    q0 += xa * wq; q1 += xb * wq; q2 += xc * wq;
    c0 += xa * wk; c1 += xb * wk; c2 += xc * wk;
    v0 += xa * wv; v1 += xb * wv; v2 += xc * wv;
  }
  float qs[3] = {q0, q1, q2}, ks[3] = {c0, c1, c2}, vs[3] = {v0, v1, v2};
  float sc[3][3];
#pragma unroll
  for (int s = 0; s < 3; ++s)
#pragma unroll
    for (int u = 0; u < 3; ++u) {
      float p = qs[s] * ks[u];
#pragma unroll
      for (int off = 16; off; off >>= 1) p += __shfl_xor(p, off, 32);
      sc[s][u] = p * 0.17677669529663687f;  // 1/sqrt(32)
    }
#pragma unroll
  for (int s = 0; s < 3; ++s) {
    float m = fmaxf(sc[s][0], fmaxf(sc[s][1], sc[s][2]));
    float e0 = __expf(sc[s][0] - m), e1 = __expf(sc[s][1] - m), e2 = __expf(sc[s][2] - m);
    float inv = 1.f / (e0 + e1 + e2);
    att[(size_t)b * 96 + s * 32 + d] = (e0 * vs[0] + e1 * vs[1] + e2 * vs[2]) * inv;
  }
}

__global__ __launch_bounds__(256) void k_noise(const float* __restrict__ att_u,
                                               const float* __restrict__ att_i,
                                               uint32_t ku0, uint32_t ku1, uint32_t ki0, uint32_t ki1,
                                               float* __restrict__ n1, float* __restrict__ n2,
                                               float* __restrict__ posdot) {
  int t = threadIdx.x;
  int g = blockIdx.x * 8 + (t >> 5);   // [0, 24576)
  int k = t & 31;
  int side = g / (NLV * BB);
  int rem = g - side * (NLV * BB);
  int l = rem >> 12;
  int b = rem & 4095;
  const float* att = side ? att_i : att_u;
  uint32_t ka = side ? ki0 : ku0;
  uint32_t kb = side ? ki1 : ku1;
  float r = att[(size_t)b * 96 + l * 32 + k];
  float ss = r * r;
#pragma unroll
  for (int off = 16; off; off >>= 1) ss += __shfl_xor(ss, off, 32);
  float v1 = r / fmaxf(sqrtf(ss), 1e-12f);
  uint32_t m = ((uint32_t)(l * BB + b)) * 32u + (uint32_t)k;
  float u = tf_uniform(ka, kb, m);
  float us = u * u;
#pragma unroll
  for (int off = 16; off; off >>= 1) us += __shfl_xor(us, off, 32);
  float un = u / fmaxf(sqrtf(us), 1e-12f);
  float sgn = (r > 0.f) ? 1.f : ((r < 0.f) ? -1.f : 0.f);
  float rn = r + sgn * un * 0.1f;
  float s2 = rn * rn;
#pragma unroll
  for (int off = 16; off; off >>= 1) s2 += __shfl_xor(s2, off, 32);
  float v2 = rn / fmaxf(sqrtf(s2), 1e-12f);
  float pd = v1 * v2;
#pragma unroll
  for (int off = 16; off; off >>= 1) pd += __shfl_xor(pd, off, 32);
  size_t o = (size_t)g * 32 + k;
  n1[o] = v1;
  n2[o] = v2;
  if (k == 0) posdot[g] = pd;
}

// ttl: per-slice [4096 x 4096] exp(dot/tau) row-sums.
// 2 i-rows per thread share each staged j-chunk read.
__global__ __launch_bounds__(256) void k_ttl(const float* __restrict__ n1,
                                             const float* __restrict__ n2,
                                             float* __restrict__ ttl) {
  __shared__ float4 sj[128][8];
  int sl = blockIdx.z;
  int t = threadIdx.x;
  int ia = blockIdx.x * 512 + t;
  int ib = ia + 256;
  const float* n1b = n1 + (size_t)sl * BB * 32;
  const float* n2b = n2 + (size_t)sl * BB * 32;
  float4 ra[8], rb[8];
#pragma unroll
  for (int k = 0; k < 8; ++k) {
    ra[k] = *(const float4*)&n1b[(size_t)ia * 32 + k * 4];
    rb[k] = *(const float4*)&n1b[(size_t)ib * 32 + k * 4];
  }
  float acca = 0.f, accb = 0.f;
  for (int jc = 0; jc < 2; ++jc) {
    int j0 = blockIdx.y * 256 + jc * 128;
    __syncthreads();
    for (int idx = t; idx < 128 * 8; idx += 256) {
      int jj = idx >> 3, kk = idx & 7;
      sj[jj][kk] = *(const float4*)&n2b[(size_t)(j0 + jj) * 32 + kk * 4];
    }
    __syncthreads();
    for (int j = 0; j < 128; ++j) {
      float a0 = 0.f, a1 = 0.f, a2 = 0.f, a3 = 0.f;
      float b0 = 0.f, b1 = 0.f, b2 = 0.f, b3 = 0.f;
#pragma unroll
      for (int k = 0; k < 8; ++k) {
        float4 sv = sj[j][k];
        a0 = fmaf(ra[k].x, sv.x, a0);
        a1 = fmaf(ra[k].y, sv.y, a1);
        a2 = fmaf(ra[k].z, sv.z, a2);
        a3 = fmaf(ra[k].w, sv.w, a3);
        b0 = fmaf(rb[k].x, sv.x, b0);
        b1 = fmaf(rb[k].y, sv.y, b1);
        b2 = fmaf(rb[k].z, sv.z, b2);
        b3 = fmaf(rb[k].w, sv.w, b3);
      }
      acca += __expf(((a0 + a1) + (a2 + a3)) * 5.0f);  // 1/TAU = 5
      accb += __expf(((b0 + b1) + (b2 + b3)) * 5.0f);
    }
  }
  atomicAdd(&ttl[sl * BB + ia], acca);
  atomicAdd(&ttl[sl * BB + ib], accb);
}

__global__ __launch_bounds__(1024) void k_clred(const float* __restrict__ ttl,
                                                const float* __restrict__ posdot,
                                                float* __restrict__ outp) {
  __shared__ float red[1024];
  int t = threadIdx.x;
  float a = 0.f;
  for (int idx = t; idx < 6 * BB; idx += 1024)
    a += logf(ttl[idx]) - posdot[idx] * 5.0f;
  red[t] = a;
  __syncthreads();
  for (int off = 512; off; off >>= 1) {
    if (t < off) red[t] += red[t + off];
    __syncthreads();
  }
  if (t == 0) outp[2 * BB] = red[0] * (1.f / 12288.f);  // (cl_u + cl_i)
}

__global__ __launch_bounds__(256) void k_head(const float* __restrict__ att_u,
                                              const float* __restrict__ att_i,
                                              const float* __restrict__ skills,
                                              const float* __restrict__ w1, const float* __restrict__ b1,
                                              const float* __restrict__ w2, const float* __restrict__ b2,
                                              const float* __restrict__ pw, const float* __restrict__ pb,
                                              float* __restrict__ outp) {
  __shared__ float diag[4][96], t1[4][64];
  int t = threadIdx.x;
  int w = t >> 6, lane = t & 63;
  int b = blockIdx.x * 4 + w;
  for (int j = lane; j < 96; j += 64) {
    float su = 1.f / (1.f + __expf(-att_u[(size_t)b * 96 + j]));
    float si = 1.f / (1.f + __expf(-att_i[(size_t)b * 96 + j]));
    diag[w][j] = (su - si) * skills[(size_t)b * 96 + j];
  }
  __syncthreads();
  float a = b1[lane];
#pragma unroll 8
  for (int j = 0; j < 96; ++j) a += diag[w][j] * w1[j * 64 + lane];
  t1[w][lane] = tanhf(a);
  __syncthreads();
  float h = b2[lane];
#pragma unroll 8
  for (int kk = 0; kk < 64; ++kk) h += t1[w][kk] * w2[kk * 64 + lane];
  float p0 = h * pw[lane * 2 + 0];
  float p1 = h * pw[lane * 2 + 1];
#pragma unroll
  for (int off = 32; off; off >>= 1) {
    p0 += __shfl_xor(p0, off, 64);
    p1 += __shfl_xor(p1, off, 64);
  }
  if (lane == 0) {
    float l0 = p0 + pb[0], l1 = p1 + pb[1];
    float m = fmaxf(l0, l1);
    float e0 = __expf(l0 - m), e1 = __expf(l1 - m);
    float inv = 1.f / (e0 + e1);
    outp[(size_t)b * 2 + 0] = e0 * inv;
    outp[(size_t)b * 2 + 1] = e1 * inv;
  }
}

// ---------------- launcher ----------------
extern "C" void kernel_launch(void* const* d_in, const int* in_sizes, int n_in,
                              void* d_out, int out_size, void* d_ws, size_t ws_size,
                              hipStream_t stream) {
  const float* ego    = (const float*)d_in[0];
  const float* gc_w   = (const float*)d_in[1];
  const float* gc_b   = (const float*)d_in[2];
  const float* bi_w   = (const float*)d_in[3];
  const float* bi_b   = (const float*)d_in[4];
  const float* uh_w   = (const float*)d_in[5];
  const float* uh_b   = (const float*)d_in[6];
  const float* ih_w   = (const float*)d_in[7];
  const float* ih_b   = (const float*)d_in[8];
  const float* ud_w1  = (const float*)d_in[9];
  const float* ud_b1  = (const float*)d_in[10];
  const float* ud_w2  = (const float*)d_in[11];
  const float* ud_b2  = (const float*)d_in[12];
  const float* id_w1  = (const float*)d_in[13];
  const float* id_b1  = (const float*)d_in[14];
  const float* id_w2  = (const float*)d_in[15];
  const float* id_b2  = (const float*)d_in[16];
  const float* q_w    = (const float*)d_in[17];
  const float* q_b    = (const float*)d_in[18];
  const float* k_w    = (const float*)d_in[19];
  const float* k_b    = (const float*)d_in[20];
  const float* v_w    = (const float*)d_in[21];
  const float* v_b    = (const float*)d_in[22];
  const float* dg_w1  = (const float*)d_in[23];
  const float* dg_b1  = (const float*)d_in[24];
  const float* dg_w2  = (const float*)d_in[25];
  const float* dg_b2  = (const float*)d_in[26];
  const float* pr_w   = (const float*)d_in[27];
  const float* pr_b   = (const float*)d_in[28];
  const float* adj_vals = (const float*)d_in[29];
  const float* skills = (const float*)d_in[30];
  const int* user_id  = (const int*)d_in[31];
  const int* item_id  = (const int*)d_in[32];
  const int* adj_rows = (const int*)d_in[33];
  const int* adj_cols = (const int*)d_in[34];
  float* outp = (float*)d_out;

  char* w = (char*)d_ws;
  auto alloc = [&](size_t bytes) -> char* {
    char* p = w;
    w += (bytes + 255) & ~(size_t)255;
    return p;
  };
  float* E      = (float*)alloc((size_t)NODE_N * DD * 4);
  float* Esum   = (float*)alloc((size_t)NODE_N * DD * 4);
  float* side   = (float*)alloc((size_t)NODE_N * DD * 4);
  unsigned short* E16 = (unsigned short*)alloc((size_t)NODE_N * DD * 2);
  uint2* sedge_r= (uint2*)alloc((size_t)NNZE * 8);   // tile-bucketed (dead after sort)
  uint2* sedge  = (uint2*)alloc((size_t)NNZE * 8);   // row-sorted CSR
  int*   hist   = (int*)  alloc((size_t)NENT * 16 * 4);
  int*   tile_start = (int*)alloc((size_t)(NTILE + 1) * 4);
  int*   cursor = (int*)  alloc((size_t)NENT * 16 * 4);
  int*   row_start = (int*)alloc((size_t)(NODE_N + 1) * 4);
  float* posdot = (float*)alloc((size_t)6 * BB * 4);
  float* ttl    = (float*)alloc((size_t)6 * BB * 4);

  // late-phase buffers aliased onto sedge_r (dead after k_sort_t); 14.7MB <= 19.2MB
  char* ap = (char*)sedge_r;
  auto alias = [&](size_t bytes) -> char* {
    char* p = ap;
    ap += (bytes + 255) & ~(size_t)255;
    return p;
  };
  float* ue     = (float*)alias((size_t)BB * 64 * 4);
  float* ie     = (float*)alias((size_t)BB * 64 * 4);
  float* recs_u = (float*)alias((size_t)NLV * BB * 32 * 4);
  float* recs_i = (float*)alias((size_t)NLV * BB * 32 * 4);
  float* att_u  = (float*)alias((size_t)BB * 96 * 4);
  float* att_i  = (float*)alias((size_t)BB * 96 * 4);
  float* n1     = (float*)alias((size_t)6 * BB * 32 * 4);
  float* n2     = (float*)alias((size_t)6 * BB * 32 * 4);

  // host-side: kc = jax.random.split(jax.random.key(42), 2)
  uint32_t a0 = 0, a1 = 2, b0 = 1, b1 = 3;
  tf_block(0u, 42u, a0, a1);
  tf_block(0u, 42u, b0, b1);
  uint32_t ku0 = a0, ku1 = b0;   // kc[0] -> u side
  uint32_t ki0 = a1, ki1 = b1;   // kc[1] -> i side

  hipMemsetAsync(hist, 0, (size_t)NENT * 16 * 4, stream);
  hipMemsetAsync(ttl, 0, (size_t)6 * BB * 4, stream);

  k_init<<<9375, 256, 0, stream>>>(ego, E, Esum, E16);
  k_hist_t<<<9375, 256, 0, stream>>>(adj_rows, hist);
  k_scan_t<<<1, 1024, 0, stream>>>(hist, tile_start, cursor, row_start);
  k_scatter_t<<<9375, 256, 0, stream>>>(adj_rows, adj_cols, adj_vals, cursor, sedge_r);
  k_sort_t<<<NTILE, 256, 0, stream>>>(sedge_r, tile_start, sedge, row_start);

  for (int l = 0; l < 2; ++l) {
    k_spmm<<<37500, 256, 0, stream>>>(E16, sedge, row_start, side);
    k_transform<<<TR_GRID, 256, 0, stream>>>(gc_w + l * 4096, gc_b + l * 64,
                                             bi_w + l * 4096, bi_b + l * 64,
                                             E, Esum, E16, side);
  }

  k_gather<<<4096, 128, 0, stream>>>(Esum, user_id, item_id, ue, ie);

  dim3 ge(4096, 3);
  k_encoder<<<ge, 256, 0, stream>>>(ue, uh_w, uh_b, ud_w1, ud_b1, ud_w2, ud_b2, recs_u);
  k_encoder<<<ge, 256, 0, stream>>>(ie, ih_w, ih_b, id_w1, id_b1, id_w2, id_b2, recs_i);

  k_attn<<<512, 256, 0, stream>>>(recs_u, q_w, q_b, k_w, k_b, v_w, v_b, att_u);
  k_attn<<<512, 256, 0, stream>>>(recs_i, q_w, q_b, k_w, k_b, v_w, v_b, att_i);

  k_noise<<<3072, 256, 0, stream>>>(att_u, att_i, ku0, ku1, ki0, ki1, n1, n2, posdot);

  dim3 gt(8, 16, 6);
  k_ttl<<<gt, 256, 0, stream>>>(n1, n2, ttl);
  k_clred<<<1, 1024, 0, stream>>>(ttl, posdot, outp);

  k_head<<<1024, 256, 0, stream>>>(att_u, att_i, skills, dg_w1, dg_b1, dg_w2, dg_b2,
                                   pr_w, pr_b, outp);
}

// Round 7
// 990.249 us; speedup vs baseline: 3.0432x; 1.0696x over previous
//
#include <hip/hip_runtime.h>
#include <stdint.h>
#include <math.h>

#define USER_N 100000
#define NODE_N 150000
#define DD 64
#define NNZE 2400000
#define BB 4096
#define NLV 3
#define LF 32
#define HALF_SZ 196608u  /* (3*4096*32)/2 */
#define NTILE 586        /* ceil(150000/256) */
#define NVX 8            /* virtual-XCD sub-buckets per tile */
#define NENT (NTILE * NVX)

typedef __attribute__((ext_vector_type(8))) short bf16x8;
typedef __attribute__((ext_vector_type(4))) float f32x4;

// ---------------- threefry2x32 (JAX original mode) ----------------
__host__ __device__ inline void tf_block(uint32_t k0, uint32_t k1, uint32_t& x0, uint32_t& x1) {
  uint32_t ks[3] = {k0, k1, k0 ^ k1 ^ 0x1BD11BDAu};
  x0 += ks[0]; x1 += ks[1];
  const int R0[4] = {13, 15, 26, 6};
  const int R1[4] = {17, 29, 16, 24};
#pragma unroll
  for (int i = 0; i < 5; ++i) {
    const int* R = (i & 1) ? R1 : R0;
#pragma unroll
    for (int j = 0; j < 4; ++j) {
      x0 += x1;
      x1 = (x1 << R[j]) | (x1 >> (32 - R[j]));
      x1 ^= x0;
    }
    x0 += ks[(i + 1) % 3];
    x1 += ks[(i + 2) % 3] + (uint32_t)(i + 1);
  }
}

__device__ inline float tf_uniform(uint32_t ka, uint32_t kb, uint32_t m) {
  uint32_t x0, x1;
  bool first = m < HALF_SZ;
  if (first) { x0 = m; x1 = m + HALF_SZ; } else { x0 = m - HALF_SZ; x1 = m; }
  tf_block(ka, kb, x0, x1);
  uint32_t bits = first ? x0 : x1;
  return __uint_as_float((bits >> 9) | 0x3f800000u) - 1.0f;
}

// bf16 round-to-nearest-even
__device__ inline unsigned short f2bf(float x) {
  uint32_t b = __float_as_uint(x);
  return (unsigned short)((b + 0x7FFFu + ((b >> 16) & 1u)) >> 16);
}

// ---------------- kernels ----------------
__global__ __launch_bounds__(256) void k_init(const float* __restrict__ ego,
                                              float* __restrict__ E, float* __restrict__ Esum,
                                              unsigned short* __restrict__ E16) {
  int i = blockIdx.x * 256 + threadIdx.x;  // float4 index
  float4 v = ((const float4*)ego)[i];
  ((float4*)E)[i] = v;
  ((float4*)Esum)[i] = v;
  ushort4 h;
  h.x = f2bf(v.x); h.y = f2bf(v.y); h.z = f2bf(v.z); h.w = f2bf(v.w);
  ((ushort4*)E16)[i] = h;
}

// per-(tile, virtual-XCD) histogram; counters padded to one per 64B line
__global__ __launch_bounds__(256) void k_hist_t(const int* __restrict__ rows,
                                                int* __restrict__ hist) {
  int e = blockIdx.x * 256 + threadIdx.x;
  int vx = blockIdx.x & (NVX - 1);
  if (e < NNZE) atomicAdd(&hist[((rows[e] >> 8) * NVX + vx) * 16], 1);
}

// single-block scan over 4688 (tile,vx) counts -> tile_start + per-entry cursors
__global__ __launch_bounds__(1024) void k_scan_t(const int* __restrict__ hist,
                                                 int* __restrict__ tile_start,
                                                 int* __restrict__ cursor,
                                                 int* __restrict__ row_start) {
  __shared__ int buf[1024];
  int t = threadIdx.x;
  int base = t * 5;
  int loc[5];
  int sum = 0;
#pragma unroll
  for (int j = 0; j < 5; ++j) {
    int idx = base + j;
    int v = (idx < NENT) ? hist[idx * 16] : 0;
    loc[j] = sum;
    sum += v;
  }
  buf[t] = sum;
  __syncthreads();
  for (int off = 1; off < 1024; off <<= 1) {
    int add = (t >= off) ? buf[t - off] : 0;
    __syncthreads();
    buf[t] += add;
    __syncthreads();
  }
  int tbase = (t > 0) ? buf[t - 1] : 0;
#pragma unroll
  for (int j = 0; j < 5; ++j) {
    int idx = base + j;
    if (idx < NENT) {
      int excl = tbase + loc[j];
      cursor[idx * 16] = excl;
      if ((idx & (NVX - 1)) == 0) tile_start[idx / NVX] = excl;
    }
  }
  if (t == 0) { tile_start[NTILE] = NNZE; row_start[NODE_N] = NNZE; }
}

// bucket edges by (256-row tile, virtual XCD): each sub-segment's write frontier
// is touched by ONE XCD's L2 -> full-line writebacks.
__global__ __launch_bounds__(256) void k_scatter_t(const int* __restrict__ rows,
                                                   const int* __restrict__ cols,
                                                   const float* __restrict__ vals,
                                                   int* __restrict__ cursor,
                                                   uint2* __restrict__ sedge) {
  int e = blockIdx.x * 256 + threadIdx.x;
  int vx = blockIdx.x & (NVX - 1);
  if (e < NNZE) {
    int r = rows[e];
    uint32_t rl = (uint32_t)(r & 255);
    int p = atomicAdd(&cursor[((r >> 8) * NVX + vx) * 16], 1);
    sedge[p] = make_uint2((uint32_t)cols[e] | (rl << 18), __float_as_uint(vals[e]));
  }
}

// per-tile 256-bin counting sort: bucketed records -> row-sorted CSR (+ row_start).
__global__ __launch_bounds__(256) void k_sort_t(const uint2* __restrict__ sedge_in,
                                                const int* __restrict__ tile_start,
                                                uint2* __restrict__ sedge_out,
                                                int* __restrict__ row_start) {
  __shared__ int hist[256], buf[256], curs[256];
  int t = threadIdx.x;
  int tile = blockIdx.x;
  int s = tile_start[tile], e = tile_start[tile + 1];
  hist[t] = 0;
  __syncthreads();
  for (int i = s + t; i < e; i += 256)
    atomicAdd(&hist[sedge_in[i].x >> 18], 1);
  __syncthreads();
  int v = hist[t];
  buf[t] = v;
  __syncthreads();
  for (int off = 1; off < 256; off <<= 1) {
    int add = (t >= off) ? buf[t - off] : 0;
    __syncthreads();
    buf[t] += add;
    __syncthreads();
  }
  int excl = buf[t] - v;
  curs[t] = excl;
  int row = tile * 256 + t;
  if (row < NODE_N) row_start[row] = s + excl;
  __syncthreads();
  for (int i = s + t; i < e; i += 256) {
    uint2 rec = sedge_in[i];
    int rl = rec.x >> 18;
    int p = atomicAdd(&curs[rl], 1);
    sedge_out[s + p] = make_uint2(rec.x & 0x3FFFFu, rec.y);
  }
}

// wave-per-row SpMM over sorted CSR, bf16 E rows (128B/row).
__global__ __launch_bounds__(256) void k_spmm(const unsigned short* __restrict__ E16,
                                              const uint2* __restrict__ sedge,
                                              const int* __restrict__ row_start,
                                              float* __restrict__ side) {
  const uint2* E2 = (const uint2*)E16;  // 16 uint2 per row
  int r = blockIdx.x * 4 + (threadIdx.x >> 6);
  int lane = threadIdx.x & 63;
  int g = lane >> 4;
  int q = lane & 15;
  int rs = row_start[r], re = row_start[r + 1];
  float4 acc = make_float4(0.f, 0.f, 0.f, 0.f);
  int e = rs;
#define BF_FMA(rec, a)                                                        \
  {                                                                           \
    float vv = __uint_as_float(rec.y);                                        \
    acc.x = fmaf(vv, __uint_as_float(a.x << 16), acc.x);                      \
    acc.y = fmaf(vv, __uint_as_float(a.x & 0xFFFF0000u), acc.y);              \
    acc.z = fmaf(vv, __uint_as_float(a.y << 16), acc.z);                      \
    acc.w = fmaf(vv, __uint_as_float(a.y & 0xFFFF0000u), acc.w);              \
  }
  for (; e + 16 <= re; e += 16) {
    uint2 e0 = sedge[e + g];
    uint2 e1 = sedge[e + 4 + g];
    uint2 e2 = sedge[e + 8 + g];
    uint2 e3 = sedge[e + 12 + g];
    uint2 a0 = E2[(size_t)e0.x * 16 + q];
    uint2 a1 = E2[(size_t)e1.x * 16 + q];
    uint2 a2 = E2[(size_t)e2.x * 16 + q];
    uint2 a3 = E2[(size_t)e3.x * 16 + q];
    BF_FMA(e0, a0) BF_FMA(e1, a1) BF_FMA(e2, a2) BF_FMA(e3, a3)
  }
  for (; e + 8 <= re; e += 8) {
    uint2 e0 = sedge[e + g];
    uint2 e1 = sedge[e + 4 + g];
    uint2 a0 = E2[(size_t)e0.x * 16 + q];
    uint2 a1 = E2[(size_t)e1.x * 16 + q];
    BF_FMA(e0, a0) BF_FMA(e1, a1)
  }
  for (; e + 4 <= re; e += 4) {
    uint2 e0 = sedge[e + g];
    uint2 a0 = E2[(size_t)e0.x * 16 + q];
    BF_FMA(e0, a0)
  }
  for (; e < re; ++e) {
    if (g == (e & 3)) {
      uint2 e0 = sedge[e];
      uint2 a0 = E2[(size_t)e0.x * 16 + q];
      BF_FMA(e0, a0)
    }
  }
#undef BF_FMA
#pragma unroll
  for (int off = 16; off <= 32; off <<= 1) {
    acc.x += __shfl_xor(acc.x, off, 64);
    acc.y += __shfl_xor(acc.y, off, 64);
    acc.z += __shfl_xor(acc.z, off, 64);
    acc.w += __shfl_xor(acc.w, off, 64);
  }
  if (g == 0) *(float4*)&side[(size_t)r * DD + q * 4] = acc;
}

// Transform: weights held in VGPR columns, row vectors broadcast from LDS via b128.
#define TR_ROWS 16
#define TR_GRID 1875   /* 9375 chunks / 5 per block */
__global__ __launch_bounds__(256) void k_transform(const float* __restrict__ gw,
                                                   const float* __restrict__ gb,
                                                   const float* __restrict__ bw,
                                                   const float* __restrict__ bb,
                                                   float* __restrict__ E, float* __restrict__ Esum,
                                                   unsigned short* __restrict__ E16,
                                                   const float* __restrict__ side) {
  __shared__ float ss[TR_ROWS][64];
  __shared__ float pp[TR_ROWS][64];
  int t = threadIdx.x;
  int lane = t & 63;
  int wv = t >> 6;
  float wgr[64], wbr[64];
#pragma unroll
  for (int k = 0; k < 64; ++k) {
    wgr[k] = gw[k * 64 + lane];
    wbr[k] = bw[k * 64 + lane];
  }
  float gbl = gb[lane], bbl = bb[lane];
  const int nchunks = NODE_N / TR_ROWS;  // 9375
  for (int chunk = blockIdx.x; chunk < nchunks; chunk += TR_GRID) {
    int r0 = chunk * TR_ROWS;
    {
      int row = t >> 4;
      int col = (t & 15) * 4;
      float4 sv = *(const float4*)&side[(size_t)(r0 + row) * 64 + col];
      float4 ev = *(const float4*)&E[(size_t)(r0 + row) * 64 + col];
      *(float4*)&ss[row][col] = sv;
      pp[row][col + 0] = sv.x * ev.x;
      pp[row][col + 1] = sv.y * ev.y;
      pp[row][col + 2] = sv.z * ev.z;
      pp[row][col + 3] = sv.w * ev.w;
    }
    __syncthreads();
#pragma unroll
    for (int rr = 0; rr < 4; ++rr) {
      int row = wv + rr * 4;
      float a10 = 0.f, a11 = 0.f, a12 = 0.f, a13 = 0.f;
      float a20 = 0.f, a21 = 0.f, a22 = 0.f, a23 = 0.f;
#pragma unroll
      for (int k = 0; k < 64; k += 4) {
        float4 s4 = *(const float4*)&ss[row][k];
        float4 p4 = *(const float4*)&pp[row][k];
        a10 = fmaf(s4.x, wgr[k + 0], a10);
        a11 = fmaf(s4.y, wgr[k + 1], a11);
        a12 = fmaf(s4.z, wgr[k + 2], a12);
        a13 = fmaf(s4.w, wgr[k + 3], a13);
        a20 = fmaf(p4.x, wbr[k + 0], a20);
        a21 = fmaf(p4.y, wbr[k + 1], a21);
        a22 = fmaf(p4.z, wbr[k + 2], a22);
        a23 = fmaf(p4.w, wbr[k + 3], a23);
      }
      float a1 = gbl + ((a10 + a11) + (a12 + a13));
      float a2 = bbl + ((a20 + a21) + (a22 + a23));
      a1 = (a1 > 0.f) ? a1 : 0.01f * a1;
      a2 = (a2 > 0.f) ? a2 : 0.01f * a2;
      float v = a1 + a2;
      float sq = v * v;
#pragma unroll
      for (int off = 32; off; off >>= 1) sq += __shfl_xor(sq, off, 64);
      v = v / fmaxf(sqrtf(sq), 1e-12f);
      size_t o = (size_t)(r0 + row) * 64 + lane;
      E[o] = v;
      E16[o] = f2bf(v);
      Esum[o] += v;
    }
    __syncthreads();
  }
}

__global__ __launch_bounds__(128) void k_gather(const float* __restrict__ Esum,
                                                const int* __restrict__ uid,
                                                const int* __restrict__ iid,
                                                float* __restrict__ ue, float* __restrict__ ie) {
  int b = blockIdx.x, t = threadIdx.x;
  if (t < 64) ue[(size_t)b * 64 + t] = Esum[(size_t)uid[b] * 64 + t];
  else {
    int d = t - 64;
    ie[(size_t)b * 64 + d] = Esum[(size_t)(USER_N + iid[b]) * 64 + d];
  }
}

__global__ __launch_bounds__(256) void k_encoder(const float* __restrict__ xin,
                                                 const float* __restrict__ hw, const float* __restrict__ hb,
                                                 const float* __restrict__ w1, const float* __restrict__ b1,
                                                 const float* __restrict__ w2, const float* __restrict__ b2,
                                                 float* __restrict__ recs) {
  __shared__ float sx[64], sreps[64], st[256];
  int b = blockIdx.x, l = blockIdx.y, t = threadIdx.x;
  if (t < 64) sx[t] = xin[(size_t)b * 64 + t];
  __syncthreads();
  if (t < 64) {
    const float* W = hw + l * 64 * 64;
    float a = hb[l * 64 + t];
#pragma unroll 8
    for (int k = 0; k < 64; ++k) a += sx[k] * W[k * 64 + t];
    sreps[t] = tanhf(a);
  }
  __syncthreads();
  {
    const float* W = w1 + l * 64 * 256;
    float a = b1[l * 256 + t];
#pragma unroll 8
    for (int k = 0; k < 64; ++k) a += sreps[k] * W[k * 256 + t];
    st[t] = tanhf(a);
  }
  __syncthreads();
  if (t < 32) {
    const float* W = w2 + l * 256 * 32;
    float a = b2[l * 32 + t];
#pragma unroll 8
    for (int k = 0; k < 256; ++k) a += st[k] * W[k * 32 + t];
    recs[((size_t)l * BB + b) * 32 + t] = a;
  }
}

__global__ __launch_bounds__(256) void k_attn(const float* __restrict__ recs,
                                              const float* __restrict__ qw, const float* __restrict__ qb,
                                              const float* __restrict__ kw, const float* __restrict__ kb,
                                              const float* __restrict__ vw, const float* __restrict__ vb,
                                              float* __restrict__ att) {
  int t = threadIdx.x;
  int b = blockIdx.x * 8 + (t >> 5);
  int d = t & 31;
  float x0 = recs[((size_t)0 * BB + b) * 32 + d];
  float x1 = recs[((size_t)1 * BB + b) * 32 + d];
  float x2 = recs[((size_t)2 * BB + b) * 32 + d];
  float q0 = qb[d], q1 = q0, q2 = q0;
  float c0 = kb[d], c1 = c0, c2 = c0;
  float v0 = vb[d], v1 = v0, v2 = v0;
#pragma unroll 4
  for (int kk = 0; kk < 32; ++kk) {
    float xa = __shfl(x0, kk, 32);
    float xb = __shfl(x1, kk, 32);
    float xc = __shfl(x2, kk, 32);
    float wq = qw[kk * 32 + d], wk = kw[kk * 32 + d], wv = vw[kk * 32 + d];
    q0 += xa * wq; q1 += xb * wq; q2 += xc * wq;
    c0 += xa * wk; c1 += xb * wk; c2 += xc * wk;
    v0 += xa * wv; v1 += xb * wv; v2 += xc * wv;
  }
  float qs[3] = {q0, q1, q2}, ks[3] = {c0, c1, c2}, vs[3] = {v0, v1, v2};
  float sc[3][3];
#pragma unroll
  for (int s = 0; s < 3; ++s)
#pragma unroll
    for (int u = 0; u < 3; ++u) {
      float p = qs[s] * ks[u];
#pragma unroll
      for (int off = 16; off; off >>= 1) p += __shfl_xor(p, off, 32);
      sc[s][u] = p * 0.17677669529663687f;  // 1/sqrt(32)
    }
#pragma unroll
  for (int s = 0; s < 3; ++s) {
    float m = fmaxf(sc[s][0], fmaxf(sc[s][1], sc[s][2]));
    float e0 = __expf(sc[s][0] - m), e1 = __expf(sc[s][1] - m), e2 = __expf(sc[s][2] - m);
    float inv = 1.f / (e0 + e1 + e2);
    att[(size_t)b * 96 + s * 32 + d] = (e0 * vs[0] + e1 * vs[1] + e2 * vs[2]) * inv;
  }
}

// noise: emits l2-normalized recs (n1) and perturbed recs (n2) directly as bf16
// for the MFMA ttl kernel; posdot stays fp32-exact.
__global__ __launch_bounds__(256) void k_noise(const float* __restrict__ att_u,
                                               const float* __restrict__ att_i,
                                               uint32_t ku0, uint32_t ku1, uint32_t ki0, uint32_t ki1,
                                               unsigned short* __restrict__ n1b,
                                               unsigned short* __restrict__ n2b,
                                               float* __restrict__ posdot) {
  int t = threadIdx.x;
  int g = blockIdx.x * 8 + (t >> 5);   // [0, 24576)
  int k = t & 31;
  int side = g / (NLV * BB);
  int rem = g - side * (NLV * BB);
  int l = rem >> 12;
  int b = rem & 4095;
  const float* att = side ? att_i : att_u;
  uint32_t ka = side ? ki0 : ku0;
  uint32_t kb = side ? ki1 : ku1;
  float r = att[(size_t)b * 96 + l * 32 + k];
  float ss = r * r;
#pragma unroll
  for (int off = 16; off; off >>= 1) ss += __shfl_xor(ss, off, 32);
  float v1 = r / fmaxf(sqrtf(ss), 1e-12f);
  uint32_t m = ((uint32_t)(l * BB + b)) * 32u + (uint32_t)k;
  float u = tf_uniform(ka, kb, m);
  float us = u * u;
#pragma unroll
  for (int off = 16; off; off >>= 1) us += __shfl_xor(us, off, 32);
  float un = u / fmaxf(sqrtf(us), 1e-12f);
  float sgn = (r > 0.f) ? 1.f : ((r < 0.f) ? -1.f : 0.f);
  float rn = r + sgn * un * 0.1f;
  float s2 = rn * rn;
#pragma unroll
  for (int off = 16; off; off >>= 1) s2 += __shfl_xor(s2, off, 32);
  float v2 = rn / fmaxf(sqrtf(s2), 1e-12f);
  float pd = v1 * v2;
#pragma unroll
  for (int off = 16; off; off >>= 1) pd += __shfl_xor(pd, off, 32);
  size_t o = (size_t)g * 32 + k;
  n1b[o] = f2bf(v1);
  n2b[o] = f2bf(v2);
  if (k == 0) posdot[g] = pd;
}

// ttl via MFMA: 6 slices of [4096x4096] = n1.n2^T with K=32 -> one
// mfma_f32_16x16x32_bf16 per 16x16 tile. Frag loads are direct 16B global
// reads (row = lane&15, k = quad*8..+7); C/D: col=lane&15, row=quad*4+reg.
// Block = 4 waves x 16-row i-tiles (64-row stripe); each wave sweeps all 256
// j-tiles, exp+accumulates 4 rows/lane, then 16-lane butterfly row-reduce.
__global__ __launch_bounds__(256) void k_ttl(const unsigned short* __restrict__ n1b,
                                             const unsigned short* __restrict__ n2b,
                                             float* __restrict__ ttl) {
  int t = threadIdx.x;
  int wv = t >> 6, lane = t & 63;
  int sl = blockIdx.x >> 6;            // 6 slices
  int istripe = blockIdx.x & 63;       // 64 stripes of 64 rows
  int i0 = istripe * 64 + wv * 16;
  const unsigned short* ab = n1b + (size_t)sl * BB * 32;
  const unsigned short* bb = n2b + (size_t)sl * BB * 32;
  int m = lane & 15, quad = lane >> 4;
  bf16x8 afrag = *(const bf16x8*)&ab[(size_t)(i0 + m) * 32 + quad * 8];
  const bf16x8* brow = (const bf16x8*)&bb[(size_t)m * 32 + quad * 8];  // stride 8 bf16x8 per 16 rows... indexed below
  float r0a = 0.f, r1a = 0.f, r2a = 0.f, r3a = 0.f;
  f32x4 z = {0.f, 0.f, 0.f, 0.f};
  for (int jt = 0; jt < 256; jt += 4) {
    // B-frag for j-tile jt+u: rows (jt+u)*16 + m, 8 bf16 at quad*8
    bf16x8 b0 = *(const bf16x8*)&bb[((size_t)((jt + 0) * 16 + m)) * 32 + quad * 8];
    bf16x8 b1 = *(const bf16x8*)&bb[((size_t)((jt + 1) * 16 + m)) * 32 + quad * 8];
    bf16x8 b2 = *(const bf16x8*)&bb[((size_t)((jt + 2) * 16 + m)) * 32 + quad * 8];
    bf16x8 b3 = *(const bf16x8*)&bb[((size_t)((jt + 3) * 16 + m)) * 32 + quad * 8];
    f32x4 s0 = __builtin_amdgcn_mfma_f32_16x16x32_bf16(afrag, b0, z, 0, 0, 0);
    f32x4 s1 = __builtin_amdgcn_mfma_f32_16x16x32_bf16(afrag, b1, z, 0, 0, 0);
    f32x4 s2 = __builtin_amdgcn_mfma_f32_16x16x32_bf16(afrag, b2, z, 0, 0, 0);
    f32x4 s3 = __builtin_amdgcn_mfma_f32_16x16x32_bf16(afrag, b3, z, 0, 0, 0);
    r0a += __expf(s0.x * 5.f) + __expf(s1.x * 5.f) + __expf(s2.x * 5.f) + __expf(s3.x * 5.f);
    r1a += __expf(s0.y * 5.f) + __expf(s1.y * 5.f) + __expf(s2.y * 5.f) + __expf(s3.y * 5.f);
    r2a += __expf(s0.z * 5.f) + __expf(s1.z * 5.f) + __expf(s2.z * 5.f) + __expf(s3.z * 5.f);
    r3a += __expf(s0.w * 5.f) + __expf(s1.w * 5.f) + __expf(s2.w * 5.f) + __expf(s3.w * 5.f);
  }
  (void)brow;
  // reduce across the 16 lanes of each quad (cols of the tile)
#pragma unroll
  for (int off = 1; off < 16; off <<= 1) {
    r0a += __shfl_xor(r0a, off, 64);
    r1a += __shfl_xor(r1a, off, 64);
    r2a += __shfl_xor(r2a, off, 64);
    r3a += __shfl_xor(r3a, off, 64);
  }
  if (m == 0) {
    int rbase = sl * BB + i0 + quad * 4;
    ttl[rbase + 0] = r0a;
    ttl[rbase + 1] = r1a;
    ttl[rbase + 2] = r2a;
    ttl[rbase + 3] = r3a;
  }
}

__global__ __launch_bounds__(1024) void k_clred(const float* __restrict__ ttl,
                                                const float* __restrict__ posdot,
                                                float* __restrict__ outp) {
  __shared__ float red[1024];
  int t = threadIdx.x;
  float a = 0.f;
  for (int idx = t; idx < 6 * BB; idx += 1024)
    a += logf(ttl[idx]) - posdot[idx] * 5.0f;
  red[t] = a;
  __syncthreads();
  for (int off = 512; off; off >>= 1) {
    if (t < off) red[t] += red[t + off];
    __syncthreads();
  }
  if (t == 0) outp[2 * BB] = red[0] * (1.f / 12288.f);  // (cl_u + cl_i)
}

__global__ __launch_bounds__(256) void k_head(const float* __restrict__ att_u,
                                              const float* __restrict__ att_i,
                                              const float* __restrict__ skills,
                                              const float* __restrict__ w1, const float* __restrict__ b1,
                                              const float* __restrict__ w2, const float* __restrict__ b2,
                                              const float* __restrict__ pw, const float* __restrict__ pb,
                                              float* __restrict__ outp) {
  __shared__ float diag[4][96], t1[4][64];
  int t = threadIdx.x;
  int w = t >> 6, lane = t & 63;
  int b = blockIdx.x * 4 + w;
  for (int j = lane; j < 96; j += 64) {
    float su = 1.f / (1.f + __expf(-att_u[(size_t)b * 96 + j]));
    float si = 1.f / (1.f + __expf(-att_i[(size_t)b * 96 + j]));
    diag[w][j] = (su - si) * skills[(size_t)b * 96 + j];
  }
  __syncthreads();
  float a = b1[lane];
#pragma unroll 8
  for (int j = 0; j < 96; ++j) a += diag[w][j] * w1[j * 64 + lane];
  t1[w][lane] = tanhf(a);
  __syncthreads();
  float h = b2[lane];
#pragma unroll 8
  for (int kk = 0; kk < 64; ++kk) h += t1[w][kk] * w2[kk * 64 + lane];
  float p0 = h * pw[lane * 2 + 0];
  float p1 = h * pw[lane * 2 + 1];
#pragma unroll
  for (int off = 32; off; off >>= 1) {
    p0 += __shfl_xor(p0, off, 64);
    p1 += __shfl_xor(p1, off, 64);
  }
  if (lane == 0) {
    float l0 = p0 + pb[0], l1 = p1 + pb[1];
    float m = fmaxf(l0, l1);
    float e0 = __expf(l0 - m), e1 = __expf(l1 - m);
    float inv = 1.f / (e0 + e1);
    outp[(size_t)b * 2 + 0] = e0 * inv;
    outp[(size_t)b * 2 + 1] = e1 * inv;
  }
}

// ---------------- launcher ----------------
extern "C" void kernel_launch(void* const* d_in, const int* in_sizes, int n_in,
                              void* d_out, int out_size, void* d_ws, size_t ws_size,
                              hipStream_t stream) {
  const float* ego    = (const float*)d_in[0];
  const float* gc_w   = (const float*)d_in[1];
  const float* gc_b   = (const float*)d_in[2];
  const float* bi_w   = (const float*)d_in[3];
  const float* bi_b   = (const float*)d_in[4];
  const float* uh_w   = (const float*)d_in[5];
  const float* uh_b   = (const float*)d_in[6];
  const float* ih_w   = (const float*)d_in[7];
  const float* ih_b   = (const float*)d_in[8];
  const float* ud_w1  = (const float*)d_in[9];
  const float* ud_b1  = (const float*)d_in[10];
  const float* ud_w2  = (const float*)d_in[11];
  const float* ud_b2  = (const float*)d_in[12];
  const float* id_w1  = (const float*)d_in[13];
  const float* id_b1  = (const float*)d_in[14];
  const float* id_w2  = (const float*)d_in[15];
  const float* id_b2  = (const float*)d_in[16];
  const float* q_w    = (const float*)d_in[17];
  const float* q_b    = (const float*)d_in[18];
  const float* k_w    = (const float*)d_in[19];
  const float* k_b    = (const float*)d_in[20];
  const float* v_w    = (const float*)d_in[21];
  const float* v_b    = (const float*)d_in[22];
  const float* dg_w1  = (const float*)d_in[23];
  const float* dg_b1  = (const float*)d_in[24];
  const float* dg_w2  = (const float*)d_in[25];
  const float* dg_b2  = (const float*)d_in[26];
  const float* pr_w   = (const float*)d_in[27];
  const float* pr_b   = (const float*)d_in[28];
  const float* adj_vals = (const float*)d_in[29];
  const float* skills = (const float*)d_in[30];
  const int* user_id  = (const int*)d_in[31];
  const int* item_id  = (const int*)d_in[32];
  const int* adj_rows = (const int*)d_in[33];
  const int* adj_cols = (const int*)d_in[34];
  float* outp = (float*)d_out;

  char* w = (char*)d_ws;
  auto alloc = [&](size_t bytes) -> char* {
    char* p = w;
    w += (bytes + 255) & ~(size_t)255;
    return p;
  };
  float* E      = (float*)alloc((size_t)NODE_N * DD * 4);
  float* Esum   = (float*)alloc((size_t)NODE_N * DD * 4);
  float* side   = (float*)alloc((size_t)NODE_N * DD * 4);
  unsigned short* E16 = (unsigned short*)alloc((size_t)NODE_N * DD * 2);
  uint2* sedge_r= (uint2*)alloc((size_t)NNZE * 8);   // tile-bucketed (dead after sort)
  uint2* sedge  = (uint2*)alloc((size_t)NNZE * 8);   // row-sorted CSR
  int*   hist   = (int*)  alloc((size_t)NENT * 16 * 4);
  int*   tile_start = (int*)alloc((size_t)(NTILE + 1) * 4);
  int*   cursor = (int*)  alloc((size_t)NENT * 16 * 4);
  int*   row_start = (int*)alloc((size_t)(NODE_N + 1) * 4);
  float* posdot = (float*)alloc((size_t)6 * BB * 4);
  float* ttl    = (float*)alloc((size_t)6 * BB * 4);

  // late-phase buffers aliased onto sedge_r (dead after k_sort_t)
  char* ap = (char*)sedge_r;
  auto alias = [&](size_t bytes) -> char* {
    char* p = ap;
    ap += (bytes + 255) & ~(size_t)255;
    return p;
  };
  float* ue     = (float*)alias((size_t)BB * 64 * 4);
  float* ie     = (float*)alias((size_t)BB * 64 * 4);
  float* recs_u = (float*)alias((size_t)NLV * BB * 32 * 4);
  float* recs_i = (float*)alias((size_t)NLV * BB * 32 * 4);
  float* att_u  = (float*)alias((size_t)BB * 96 * 4);
  float* att_i  = (float*)alias((size_t)BB * 96 * 4);
  unsigned short* n1b = (unsigned short*)alias((size_t)6 * BB * 32 * 2);
  unsigned short* n2b = (unsigned short*)alias((size_t)6 * BB * 32 * 2);

  // host-side: kc = jax.random.split(jax.random.key(42), 2)
  uint32_t a0 = 0, a1 = 2, b0 = 1, b1 = 3;
  tf_block(0u, 42u, a0, a1);
  tf_block(0u, 42u, b0, b1);
  uint32_t ku0 = a0, ku1 = b0;   // kc[0] -> u side
  uint32_t ki0 = a1, ki1 = b1;   // kc[1] -> i side

  hipMemsetAsync(hist, 0, (size_t)NENT * 16 * 4, stream);

  k_init<<<9375, 256, 0, stream>>>(ego, E, Esum, E16);
  k_hist_t<<<9375, 256, 0, stream>>>(adj_rows, hist);
  k_scan_t<<<1, 1024, 0, stream>>>(hist, tile_start, cursor, row_start);
  k_scatter_t<<<9375, 256, 0, stream>>>(adj_rows, adj_cols, adj_vals, cursor, sedge_r);
  k_sort_t<<<NTILE, 256, 0, stream>>>(sedge_r, tile_start, sedge, row_start);

  for (int l = 0; l < 2; ++l) {
    k_spmm<<<37500, 256, 0, stream>>>(E16, sedge, row_start, side);
    k_transform<<<TR_GRID, 256, 0, stream>>>(gc_w + l * 4096, gc_b + l * 64,
                                             bi_w + l * 4096, bi_b + l * 64,
                                             E, Esum, E16, side);
  }

  k_gather<<<4096, 128, 0, stream>>>(Esum, user_id, item_id, ue, ie);

  dim3 ge(4096, 3);
  k_encoder<<<ge, 256, 0, stream>>>(ue, uh_w, uh_b, ud_w1, ud_b1, ud_w2, ud_b2, recs_u);
  k_encoder<<<ge, 256, 0, stream>>>(ie, ih_w, ih_b, id_w1, id_b1, id_w2, id_b2, recs_i);

  k_attn<<<512, 256, 0, stream>>>(recs_u, q_w, q_b, k_w, k_b, v_w, v_b, att_u);
  k_attn<<<512, 256, 0, stream>>>(recs_i, q_w, q_b, k_w, k_b, v_w, v_b, att_i);

  k_noise<<<3072, 256, 0, stream>>>(att_u, att_i, ku0, ku1, ki0, ki1, n1b, n2b, posdot);

  k_ttl<<<384, 256, 0, stream>>>(n1b, n2b, ttl);
  k_clred<<<1, 1024, 0, stream>>>(ttl, posdot, outp);

  k_head<<<1024, 256, 0, stream>>>(att_u, att_i, skills, dg_w1, dg_b1, dg_w2, dg_b2,
                                   pr_w, pr_b, outp);
}

// Round 8
// 848.703 us; speedup vs baseline: 3.5508x; 1.1668x over previous
//
#include <hip/hip_runtime.h>
#include <stdint.h>
#include <math.h>

#define USER_N 100000
#define NODE_N 150000
#define DD 64
#define NNZE 2400000
#define BB 4096
#define NLV 3
#define LF 32
#define HALF_SZ 196608u  /* (3*4096*32)/2 */
#define NTILE 586        /* ceil(150000/256) */
#define NVX 8            /* virtual-XCD sub-buckets per tile */
#define NENT (NTILE * NVX)

typedef __attribute__((ext_vector_type(8))) short bf16x8;
typedef __attribute__((ext_vector_type(4))) float f32x4;

// ---------------- threefry2x32 (JAX original mode) ----------------
__host__ __device__ inline void tf_block(uint32_t k0, uint32_t k1, uint32_t& x0, uint32_t& x1) {
  uint32_t ks[3] = {k0, k1, k0 ^ k1 ^ 0x1BD11BDAu};
  x0 += ks[0]; x1 += ks[1];
  const int R0[4] = {13, 15, 26, 6};
  const int R1[4] = {17, 29, 16, 24};
#pragma unroll
  for (int i = 0; i < 5; ++i) {
    const int* R = (i & 1) ? R1 : R0;
#pragma unroll
    for (int j = 0; j < 4; ++j) {
      x0 += x1;
      x1 = (x1 << R[j]) | (x1 >> (32 - R[j]));
      x1 ^= x0;
    }
    x0 += ks[(i + 1) % 3];
    x1 += ks[(i + 2) % 3] + (uint32_t)(i + 1);
  }
}

__device__ inline float tf_uniform(uint32_t ka, uint32_t kb, uint32_t m) {
  uint32_t x0, x1;
  bool first = m < HALF_SZ;
  if (first) { x0 = m; x1 = m + HALF_SZ; } else { x0 = m - HALF_SZ; x1 = m; }
  tf_block(ka, kb, x0, x1);
  uint32_t bits = first ? x0 : x1;
  return __uint_as_float((bits >> 9) | 0x3f800000u) - 1.0f;
}

// bf16 round-to-nearest-even
__device__ inline unsigned short f2bf(float x) {
  uint32_t b = __float_as_uint(x);
  return (unsigned short)((b + 0x7FFFu + ((b >> 16) & 1u)) >> 16);
}

// ---------------- kernels ----------------
// init: only the bf16 mirror of ego is needed up front (E0 fp32 == ego input).
__global__ __launch_bounds__(256) void k_init(const float* __restrict__ ego,
                                              unsigned short* __restrict__ E16) {
  int i = blockIdx.x * 256 + threadIdx.x;  // float4 index
  float4 v = ((const float4*)ego)[i];
  ushort4 h;
  h.x = f2bf(v.x); h.y = f2bf(v.y); h.z = f2bf(v.z); h.w = f2bf(v.w);
  ((ushort4*)E16)[i] = h;
}

// per-(tile, virtual-XCD) histogram; counters padded to one per 64B line
__global__ __launch_bounds__(256) void k_hist_t(const int* __restrict__ rows,
                                                int* __restrict__ hist) {
  int e = blockIdx.x * 256 + threadIdx.x;
  int vx = blockIdx.x & (NVX - 1);
  if (e < NNZE) atomicAdd(&hist[((rows[e] >> 8) * NVX + vx) * 16], 1);
}

// single-block scan over 4688 (tile,vx) counts -> tile_start + per-entry cursors
__global__ __launch_bounds__(1024) void k_scan_t(const int* __restrict__ hist,
                                                 int* __restrict__ tile_start,
                                                 int* __restrict__ cursor,
                                                 int* __restrict__ row_start) {
  __shared__ int buf[1024];
  int t = threadIdx.x;
  int base = t * 5;
  int loc[5];
  int sum = 0;
#pragma unroll
  for (int j = 0; j < 5; ++j) {
    int idx = base + j;
    int v = (idx < NENT) ? hist[idx * 16] : 0;
    loc[j] = sum;
    sum += v;
  }
  buf[t] = sum;
  __syncthreads();
  for (int off = 1; off < 1024; off <<= 1) {
    int add = (t >= off) ? buf[t - off] : 0;
    __syncthreads();
    buf[t] += add;
    __syncthreads();
  }
  int tbase = (t > 0) ? buf[t - 1] : 0;
#pragma unroll
  for (int j = 0; j < 5; ++j) {
    int idx = base + j;
    if (idx < NENT) {
      int excl = tbase + loc[j];
      cursor[idx * 16] = excl;
      if ((idx & (NVX - 1)) == 0) tile_start[idx / NVX] = excl;
    }
  }
  if (t == 0) { tile_start[NTILE] = NNZE; row_start[NODE_N] = NNZE; }
}

// bucket edges by (256-row tile, virtual XCD): each sub-segment's write frontier
// is touched by ONE XCD's L2 -> full-line writebacks.
__global__ __launch_bounds__(256) void k_scatter_t(const int* __restrict__ rows,
                                                   const int* __restrict__ cols,
                                                   const float* __restrict__ vals,
                                                   int* __restrict__ cursor,
                                                   uint2* __restrict__ sedge) {
  int e = blockIdx.x * 256 + threadIdx.x;
  int vx = blockIdx.x & (NVX - 1);
  if (e < NNZE) {
    int r = rows[e];
    uint32_t rl = (uint32_t)(r & 255);
    int p = atomicAdd(&cursor[((r >> 8) * NVX + vx) * 16], 1);
    sedge[p] = make_uint2((uint32_t)cols[e] | (rl << 18), __float_as_uint(vals[e]));
  }
}

// per-tile 256-bin counting sort: bucketed records -> row-sorted CSR (+ row_start).
__global__ __launch_bounds__(256) void k_sort_t(const uint2* __restrict__ sedge_in,
                                                const int* __restrict__ tile_start,
                                                uint2* __restrict__ sedge_out,
                                                int* __restrict__ row_start) {
  __shared__ int hist[256], buf[256], curs[256];
  int t = threadIdx.x;
  int tile = blockIdx.x;
  int s = tile_start[tile], e = tile_start[tile + 1];
  hist[t] = 0;
  __syncthreads();
  for (int i = s + t; i < e; i += 256)
    atomicAdd(&hist[sedge_in[i].x >> 18], 1);
  __syncthreads();
  int v = hist[t];
  buf[t] = v;
  __syncthreads();
  for (int off = 1; off < 256; off <<= 1) {
    int add = (t >= off) ? buf[t - off] : 0;
    __syncthreads();
    buf[t] += add;
    __syncthreads();
  }
  int excl = buf[t] - v;
  curs[t] = excl;
  int row = tile * 256 + t;
  if (row < NODE_N) row_start[row] = s + excl;
  __syncthreads();
  for (int i = s + t; i < e; i += 256) {
    uint2 rec = sedge_in[i];
    int rl = rec.x >> 18;
    int p = atomicAdd(&curs[rl], 1);
    sedge_out[s + p] = make_uint2(rec.x & 0x3FFFFu, rec.y);
  }
}

// wave-per-row SpMM over sorted CSR, bf16 E gathers. Epilogue emits bf16
// side16 and p16 = bf16(Eprev * side) for the MFMA transform.
__global__ __launch_bounds__(256) void k_spmm(const unsigned short* __restrict__ E16,
                                              const uint2* __restrict__ sedge,
                                              const int* __restrict__ row_start,
                                              const float* __restrict__ Eprev,
                                              unsigned short* __restrict__ side16,
                                              unsigned short* __restrict__ p16) {
  const uint2* E2 = (const uint2*)E16;  // 16 uint2 per row
  int r = blockIdx.x * 4 + (threadIdx.x >> 6);
  int lane = threadIdx.x & 63;
  int g = lane >> 4;
  int q = lane & 15;
  int rs = row_start[r], re = row_start[r + 1];
  float4 acc = make_float4(0.f, 0.f, 0.f, 0.f);
  int e = rs;
#define BF_FMA(rec, a)                                                        \
  {                                                                           \
    float vv = __uint_as_float(rec.y);                                        \
    acc.x = fmaf(vv, __uint_as_float(a.x << 16), acc.x);                      \
    acc.y = fmaf(vv, __uint_as_float(a.x & 0xFFFF0000u), acc.y);              \
    acc.z = fmaf(vv, __uint_as_float(a.y << 16), acc.z);                      \
    acc.w = fmaf(vv, __uint_as_float(a.y & 0xFFFF0000u), acc.w);              \
  }
  for (; e + 16 <= re; e += 16) {
    uint2 e0 = sedge[e + g];
    uint2 e1 = sedge[e + 4 + g];
    uint2 e2 = sedge[e + 8 + g];
    uint2 e3 = sedge[e + 12 + g];
    uint2 a0 = E2[(size_t)e0.x * 16 + q];
    uint2 a1 = E2[(size_t)e1.x * 16 + q];
    uint2 a2 = E2[(size_t)e2.x * 16 + q];
    uint2 a3 = E2[(size_t)e3.x * 16 + q];
    BF_FMA(e0, a0) BF_FMA(e1, a1) BF_FMA(e2, a2) BF_FMA(e3, a3)
  }
  for (; e + 8 <= re; e += 8) {
    uint2 e0 = sedge[e + g];
    uint2 e1 = sedge[e + 4 + g];
    uint2 a0 = E2[(size_t)e0.x * 16 + q];
    uint2 a1 = E2[(size_t)e1.x * 16 + q];
    BF_FMA(e0, a0) BF_FMA(e1, a1)
  }
  for (; e + 4 <= re; e += 4) {
    uint2 e0 = sedge[e + g];
    uint2 a0 = E2[(size_t)e0.x * 16 + q];
    BF_FMA(e0, a0)
  }
  for (; e < re; ++e) {
    if (g == (e & 3)) {
      uint2 e0 = sedge[e];
      uint2 a0 = E2[(size_t)e0.x * 16 + q];
      BF_FMA(e0, a0)
    }
  }
#undef BF_FMA
#pragma unroll
  for (int off = 16; off <= 32; off <<= 1) {
    acc.x += __shfl_xor(acc.x, off, 64);
    acc.y += __shfl_xor(acc.y, off, 64);
    acc.z += __shfl_xor(acc.z, off, 64);
    acc.w += __shfl_xor(acc.w, off, 64);
  }
  if (g == 0) {
    float4 ev = *(const float4*)&Eprev[(size_t)r * DD + q * 4];
    ushort4 s16, pp;
    s16.x = f2bf(acc.x); s16.y = f2bf(acc.y); s16.z = f2bf(acc.z); s16.w = f2bf(acc.w);
    pp.x = f2bf(acc.x * ev.x); pp.y = f2bf(acc.y * ev.y);
    pp.z = f2bf(acc.z * ev.z); pp.w = f2bf(acc.w * ev.w);
    *(ushort4*)&side16[(size_t)r * DD + q * 4] = s16;
    *(ushort4*)&p16[(size_t)r * DD + q * 4] = pp;
  }
}

// MFMA transform: E_out = l2norm(leaky(side@gw+gb) + leaky((E.side)@bw+bb)).
// One wave per 16-row tile; A-frags = 16B bf16 row loads (m=lane&15, k=quad*8+j,
// layout verified by k_ttl); B-frags = weight columns W[k][c*16+n] (Wt rows),
// built once per wave from strided scalar loads. C/D: col=lane&15, row=quad*4+reg.
// No LDS at all (r7's k_transform was LDS-pipe-bound at 107us).
__global__ __launch_bounds__(256) void k_transform(const float* __restrict__ gw,
                                                   const float* __restrict__ gb,
                                                   const float* __restrict__ bw,
                                                   const float* __restrict__ bb,
                                                   const unsigned short* __restrict__ side16,
                                                   const unsigned short* __restrict__ p16,
                                                   float* __restrict__ Eout,
                                                   unsigned short* __restrict__ E16) {
  int t = threadIdx.x;
  int wv = t >> 6, lane = t & 63;
  int n = lane & 15, quad = lane >> 4;
  bf16x8 wg[4][2], wb[4][2];
  float gbl[4], bbl[4];
#pragma unroll
  for (int c = 0; c < 4; ++c) {
    gbl[c] = gb[c * 16 + n];
    bbl[c] = bb[c * 16 + n];
#pragma unroll
    for (int h = 0; h < 2; ++h) {
#pragma unroll
      for (int j = 0; j < 8; ++j) {
        int k = h * 32 + quad * 8 + j;
        wg[c][h][j] = (short)f2bf(gw[k * 64 + c * 16 + n]);
        wb[c][h][j] = (short)f2bf(bw[k * 64 + c * 16 + n]);
      }
    }
  }
  const f32x4 z = {0.f, 0.f, 0.f, 0.f};
  for (int tile = blockIdx.x * 4 + wv; tile < NODE_N / 16; tile += gridDim.x * 4) {
    int i0 = tile * 16;
    bf16x8 as0 = *(const bf16x8*)&side16[(size_t)(i0 + n) * DD + quad * 8];
    bf16x8 as1 = *(const bf16x8*)&side16[(size_t)(i0 + n) * DD + 32 + quad * 8];
    bf16x8 ap0 = *(const bf16x8*)&p16[(size_t)(i0 + n) * DD + quad * 8];
    bf16x8 ap1 = *(const bf16x8*)&p16[(size_t)(i0 + n) * DD + 32 + quad * 8];
    float v[4][4];
    float sq0 = 0.f, sq1 = 0.f, sq2 = 0.f, sq3 = 0.f;
#pragma unroll
    for (int c = 0; c < 4; ++c) {
      f32x4 ag = __builtin_amdgcn_mfma_f32_16x16x32_bf16(as0, wg[c][0], z, 0, 0, 0);
      ag = __builtin_amdgcn_mfma_f32_16x16x32_bf16(as1, wg[c][1], ag, 0, 0, 0);
      f32x4 ab = __builtin_amdgcn_mfma_f32_16x16x32_bf16(ap0, wb[c][0], z, 0, 0, 0);
      ab = __builtin_amdgcn_mfma_f32_16x16x32_bf16(ap1, wb[c][1], ab, 0, 0, 0);
#pragma unroll
      for (int r = 0; r < 4; ++r) {
        float a1 = ag[r] + gbl[c];
        a1 = (a1 > 0.f) ? a1 : 0.01f * a1;
        float a2 = ab[r] + bbl[c];
        a2 = (a2 > 0.f) ? a2 : 0.01f * a2;
        float vv = a1 + a2;
        v[c][r] = vv;
        if (r == 0) sq0 += vv * vv;
        else if (r == 1) sq1 += vv * vv;
        else if (r == 2) sq2 += vv * vv;
        else sq3 += vv * vv;
      }
    }
#pragma unroll
    for (int off = 1; off < 16; off <<= 1) {
      sq0 += __shfl_xor(sq0, off, 64);
      sq1 += __shfl_xor(sq1, off, 64);
      sq2 += __shfl_xor(sq2, off, 64);
      sq3 += __shfl_xor(sq3, off, 64);
    }
    float inv0 = 1.f / fmaxf(sqrtf(sq0), 1e-12f);
    float inv1 = 1.f / fmaxf(sqrtf(sq1), 1e-12f);
    float inv2 = 1.f / fmaxf(sqrtf(sq2), 1e-12f);
    float inv3 = 1.f / fmaxf(sqrtf(sq3), 1e-12f);
#pragma unroll
    for (int c = 0; c < 4; ++c) {
      float vn0 = v[c][0] * inv0;
      float vn1 = v[c][1] * inv1;
      float vn2 = v[c][2] * inv2;
      float vn3 = v[c][3] * inv3;
      size_t o0 = (size_t)(i0 + quad * 4 + 0) * DD + c * 16 + n;
      size_t o1 = o0 + DD, o2 = o1 + DD, o3 = o2 + DD;
      Eout[o0] = vn0; Eout[o1] = vn1; Eout[o2] = vn2; Eout[o3] = vn3;
      E16[o0] = f2bf(vn0); E16[o1] = f2bf(vn1); E16[o2] = f2bf(vn2); E16[o3] = f2bf(vn3);
    }
  }
}

// gather: Esum = ego + E1 + E2 on just the 8192 batch rows.
__global__ __launch_bounds__(128) void k_gather(const float* __restrict__ ego,
                                                const float* __restrict__ E1,
                                                const float* __restrict__ E2,
                                                const int* __restrict__ uid,
                                                const int* __restrict__ iid,
                                                float* __restrict__ ue, float* __restrict__ ie) {
  int b = blockIdx.x, t = threadIdx.x;
  if (t < 64) {
    size_t o = (size_t)uid[b] * 64 + t;
    ue[(size_t)b * 64 + t] = ego[o] + E1[o] + E2[o];
  } else {
    int d = t - 64;
    size_t o = (size_t)(USER_N + iid[b]) * 64 + d;
    ie[(size_t)b * 64 + d] = ego[o] + E1[o] + E2[o];
  }
}

__global__ __launch_bounds__(256) void k_encoder(const float* __restrict__ xin,
                                                 const float* __restrict__ hw, const float* __restrict__ hb,
                                                 const float* __restrict__ w1, const float* __restrict__ b1,
                                                 const float* __restrict__ w2, const float* __restrict__ b2,
                                                 float* __restrict__ recs) {
  __shared__ float sx[64], sreps[64], st[256];
  int b = blockIdx.x, l = blockIdx.y, t = threadIdx.x;
  if (t < 64) sx[t] = xin[(size_t)b * 64 + t];
  __syncthreads();
  if (t < 64) {
    const float* W = hw + l * 64 * 64;
    float a = hb[l * 64 + t];
#pragma unroll 8
    for (int k = 0; k < 64; ++k) a += sx[k] * W[k * 64 + t];
    sreps[t] = tanhf(a);
  }
  __syncthreads();
  {
    const float* W = w1 + l * 64 * 256;
    float a = b1[l * 256 + t];
#pragma unroll 8
    for (int k = 0; k < 64; ++k) a += sreps[k] * W[k * 256 + t];
    st[t] = tanhf(a);
  }
  __syncthreads();
  if (t < 32) {
    const float* W = w2 + l * 256 * 32;
    float a = b2[l * 32 + t];
#pragma unroll 8
    for (int k = 0; k < 256; ++k) a += st[k] * W[k * 32 + t];
    recs[((size_t)l * BB + b) * 32 + t] = a;
  }
}

__global__ __launch_bounds__(256) void k_attn(const float* __restrict__ recs,
                                              const float* __restrict__ qw, const float* __restrict__ qb,
                                              const float* __restrict__ kw, const float* __restrict__ kb,
                                              const float* __restrict__ vw, const float* __restrict__ vb,
                                              float* __restrict__ att) {
  int t = threadIdx.x;
  int b = blockIdx.x * 8 + (t >> 5);
  int d = t & 31;
  float x0 = recs[((size_t)0 * BB + b) * 32 + d];
  float x1 = recs[((size_t)1 * BB + b) * 32 + d];
  float x2 = recs[((size_t)2 * BB + b) * 32 + d];
  float q0 = qb[d], q1 = q0, q2 = q0;
  float c0 = kb[d], c1 = c0, c2 = c0;
  float v0 = vb[d], v1 = v0, v2 = v0;
#pragma unroll 4
  for (int kk = 0; kk < 32; ++kk) {
    float xa = __shfl(x0, kk, 32);
    float xb = __shfl(x1, kk, 32);
    float xc = __shfl(x2, kk, 32);
    float wq = qw[kk * 32 + d], wk = kw[kk * 32 + d], wv = vw[kk * 32 + d];
    q0 += xa * wq; q1 += xb * wq; q2 += xc * wq;
    c0 += xa * wk; c1 += xb * wk; c2 += xc * wk;
    v0 += xa * wv; v1 += xb * wv; v2 += xc * wv;
  }
  float qs[3] = {q0, q1, q2}, ks[3] = {c0, c1, c2}, vs[3] = {v0, v1, v2};
  float sc[3][3];
#pragma unroll
  for (int s = 0; s < 3; ++s)
#pragma unroll
    for (int u = 0; u < 3; ++u) {
      float p = qs[s] * ks[u];
#pragma unroll
      for (int off = 16; off; off >>= 1) p += __shfl_xor(p, off, 32);
      sc[s][u] = p * 0.17677669529663687f;  // 1/sqrt(32)
    }
#pragma unroll
  for (int s = 0; s < 3; ++s) {
    float m = fmaxf(sc[s][0], fmaxf(sc[s][1], sc[s][2]));
    float e0 = __expf(sc[s][0] - m), e1 = __expf(sc[s][1] - m), e2 = __expf(sc[s][2] - m);
    float inv = 1.f / (e0 + e1 + e2);
    att[(size_t)b * 96 + s * 32 + d] = (e0 * vs[0] + e1 * vs[1] + e2 * vs[2]) * inv;
  }
}

// noise: emits l2-normalized recs (n1) and perturbed recs (n2) directly as bf16
// for the MFMA ttl kernel; posdot stays fp32-exact.
__global__ __launch_bounds__(256) void k_noise(const float* __restrict__ att_u,
                                               const float* __restrict__ att_i,
                                               uint32_t ku0, uint32_t ku1, uint32_t ki0, uint32_t ki1,
                                               unsigned short* __restrict__ n1b,
                                               unsigned short* __restrict__ n2b,
                                               float* __restrict__ posdot) {
  int t = threadIdx.x;
  int g = blockIdx.x * 8 + (t >> 5);   // [0, 24576)
  int k = t & 31;
  int side = g / (NLV * BB);
  int rem = g - side * (NLV * BB);
  int l = rem >> 12;
  int b = rem & 4095;
  const float* att = side ? att_i : att_u;
  uint32_t ka = side ? ki0 : ku0;
  uint32_t kb = side ? ki1 : ku1;
  float r = att[(size_t)b * 96 + l * 32 + k];
  float ss = r * r;
#pragma unroll
  for (int off = 16; off; off >>= 1) ss += __shfl_xor(ss, off, 32);
  float v1 = r / fmaxf(sqrtf(ss), 1e-12f);
  uint32_t m = ((uint32_t)(l * BB + b)) * 32u + (uint32_t)k;
  float u = tf_uniform(ka, kb, m);
  float us = u * u;
#pragma unroll
  for (int off = 16; off; off >>= 1) us += __shfl_xor(us, off, 32);
  float un = u / fmaxf(sqrtf(us), 1e-12f);
  float sgn = (r > 0.f) ? 1.f : ((r < 0.f) ? -1.f : 0.f);
  float rn = r + sgn * un * 0.1f;
  float s2 = rn * rn;
#pragma unroll
  for (int off = 16; off; off >>= 1) s2 += __shfl_xor(s2, off, 32);
  float v2 = rn / fmaxf(sqrtf(s2), 1e-12f);
  float pd = v1 * v2;
#pragma unroll
  for (int off = 16; off; off >>= 1) pd += __shfl_xor(pd, off, 32);
  size_t o = (size_t)g * 32 + k;
  n1b[o] = f2bf(v1);
  n2b[o] = f2bf(v2);
  if (k == 0) posdot[g] = pd;
}

// ttl via MFMA (layout verified r7): 6 slices of [4096x4096] = n1.n2^T, K=32.
__global__ __launch_bounds__(256) void k_ttl(const unsigned short* __restrict__ n1b,
                                             const unsigned short* __restrict__ n2b,
                                             float* __restrict__ ttl) {
  int t = threadIdx.x;
  int wv = t >> 6, lane = t & 63;
  int sl = blockIdx.x >> 6;            // 6 slices
  int istripe = blockIdx.x & 63;       // 64 stripes of 64 rows
  int i0 = istripe * 64 + wv * 16;
  const unsigned short* ab = n1b + (size_t)sl * BB * 32;
  const unsigned short* bb = n2b + (size_t)sl * BB * 32;
  int m = lane & 15, quad = lane >> 4;
  bf16x8 afrag = *(const bf16x8*)&ab[(size_t)(i0 + m) * 32 + quad * 8];
  float r0a = 0.f, r1a = 0.f, r2a = 0.f, r3a = 0.f;
  f32x4 z = {0.f, 0.f, 0.f, 0.f};
  for (int jt = 0; jt < 256; jt += 4) {
    bf16x8 b0 = *(const bf16x8*)&bb[((size_t)((jt + 0) * 16 + m)) * 32 + quad * 8];
    bf16x8 b1 = *(const bf16x8*)&bb[((size_t)((jt + 1) * 16 + m)) * 32 + quad * 8];
    bf16x8 b2 = *(const bf16x8*)&bb[((size_t)((jt + 2) * 16 + m)) * 32 + quad * 8];
    bf16x8 b3 = *(const bf16x8*)&bb[((size_t)((jt + 3) * 16 + m)) * 32 + quad * 8];
    f32x4 s0 = __builtin_amdgcn_mfma_f32_16x16x32_bf16(afrag, b0, z, 0, 0, 0);
    f32x4 s1 = __builtin_amdgcn_mfma_f32_16x16x32_bf16(afrag, b1, z, 0, 0, 0);
    f32x4 s2 = __builtin_amdgcn_mfma_f32_16x16x32_bf16(afrag, b2, z, 0, 0, 0);
    f32x4 s3 = __builtin_amdgcn_mfma_f32_16x16x32_bf16(afrag, b3, z, 0, 0, 0);
    r0a += __expf(s0.x * 5.f) + __expf(s1.x * 5.f) + __expf(s2.x * 5.f) + __expf(s3.x * 5.f);
    r1a += __expf(s0.y * 5.f) + __expf(s1.y * 5.f) + __expf(s2.y * 5.f) + __expf(s3.y * 5.f);
    r2a += __expf(s0.z * 5.f) + __expf(s1.z * 5.f) + __expf(s2.z * 5.f) + __expf(s3.z * 5.f);
    r3a += __expf(s0.w * 5.f) + __expf(s1.w * 5.f) + __expf(s2.w * 5.f) + __expf(s3.w * 5.f);
  }
#pragma unroll
  for (int off = 1; off < 16; off <<= 1) {
    r0a += __shfl_xor(r0a, off, 64);
    r1a += __shfl_xor(r1a, off, 64);
    r2a += __shfl_xor(r2a, off, 64);
    r3a += __shfl_xor(r3a, off, 64);
  }
  if (m == 0) {
    int rbase = sl * BB + i0 + quad * 4;
    ttl[rbase + 0] = r0a;
    ttl[rbase + 1] = r1a;
    ttl[rbase + 2] = r2a;
    ttl[rbase + 3] = r3a;
  }
}

__global__ __launch_bounds__(1024) void k_clred(const float* __restrict__ ttl,
                                                const float* __restrict__ posdot,
                                                float* __restrict__ outp) {
  __shared__ float red[1024];
  int t = threadIdx.x;
  float a = 0.f;
  for (int idx = t; idx < 6 * BB; idx += 1024)
    a += logf(ttl[idx]) - posdot[idx] * 5.0f;
  red[t] = a;
  __syncthreads();
  for (int off = 512; off; off >>= 1) {
    if (t < off) red[t] += red[t + off];
    __syncthreads();
  }
  if (t == 0) outp[2 * BB] = red[0] * (1.f / 12288.f);  // (cl_u + cl_i)
}

__global__ __launch_bounds__(256) void k_head(const float* __restrict__ att_u,
                                              const float* __restrict__ att_i,
                                              const float* __restrict__ skills,
                                              const float* __restrict__ w1, const float* __restrict__ b1,
                                              const float* __restrict__ w2, const float* __restrict__ b2,
                                              const float* __restrict__ pw, const float* __restrict__ pb,
                                              float* __restrict__ outp) {
  __shared__ float diag[4][96], t1[4][64];
  int t = threadIdx.x;
  int w = t >> 6, lane = t & 63;
  int b = blockIdx.x * 4 + w;
  for (int j = lane; j < 96; j += 64) {
    float su = 1.f / (1.f + __expf(-att_u[(size_t)b * 96 + j]));
    float si = 1.f / (1.f + __expf(-att_i[(size_t)b * 96 + j]));
    diag[w][j] = (su - si) * skills[(size_t)b * 96 + j];
  }
  __syncthreads();
  float a = b1[lane];
#pragma unroll 8
  for (int j = 0; j < 96; ++j) a += diag[w][j] * w1[j * 64 + lane];
  t1[w][lane] = tanhf(a);
  __syncthreads();
  float h = b2[lane];
#pragma unroll 8
  for (int kk = 0; kk < 64; ++kk) h += t1[w][kk] * w2[kk * 64 + lane];
  float p0 = h * pw[lane * 2 + 0];
  float p1 = h * pw[lane * 2 + 1];
#pragma unroll
  for (int off = 32; off; off >>= 1) {
    p0 += __shfl_xor(p0, off, 64);
    p1 += __shfl_xor(p1, off, 64);
  }
  if (lane == 0) {
    float l0 = p0 + pb[0], l1 = p1 + pb[1];
    float m = fmaxf(l0, l1);
    float e0 = __expf(l0 - m), e1 = __expf(l1 - m);
    float inv = 1.f / (e0 + e1);
    outp[(size_t)b * 2 + 0] = e0 * inv;
    outp[(size_t)b * 2 + 1] = e1 * inv;
  }
}

// ---------------- launcher ----------------
extern "C" void kernel_launch(void* const* d_in, const int* in_sizes, int n_in,
                              void* d_out, int out_size, void* d_ws, size_t ws_size,
                              hipStream_t stream) {
  const float* ego    = (const float*)d_in[0];
  const float* gc_w   = (const float*)d_in[1];
  const float* gc_b   = (const float*)d_in[2];
  const float* bi_w   = (const float*)d_in[3];
  const float* bi_b   = (const float*)d_in[4];
  const float* uh_w   = (const float*)d_in[5];
  const float* uh_b   = (const float*)d_in[6];
  const float* ih_w   = (const float*)d_in[7];
  const float* ih_b   = (const float*)d_in[8];
  const float* ud_w1  = (const float*)d_in[9];
  const float* ud_b1  = (const float*)d_in[10];
  const float* ud_w2  = (const float*)d_in[11];
  const float* ud_b2  = (const float*)d_in[12];
  const float* id_w1  = (const float*)d_in[13];
  const float* id_b1  = (const float*)d_in[14];
  const float* id_w2  = (const float*)d_in[15];
  const float* id_b2  = (const float*)d_in[16];
  const float* q_w    = (const float*)d_in[17];
  const float* q_b    = (const float*)d_in[18];
  const float* k_w    = (const float*)d_in[19];
  const float* k_b    = (const float*)d_in[20];
  const float* v_w    = (const float*)d_in[21];
  const float* v_b    = (const float*)d_in[22];
  const float* dg_w1  = (const float*)d_in[23];
  const float* dg_b1  = (const float*)d_in[24];
  const float* dg_w2  = (const float*)d_in[25];
  const float* dg_b2  = (const float*)d_in[26];
  const float* pr_w   = (const float*)d_in[27];
  const float* pr_b   = (const float*)d_in[28];
  const float* adj_vals = (const float*)d_in[29];
  const float* skills = (const float*)d_in[30];
  const int* user_id  = (const int*)d_in[31];
  const int* item_id  = (const int*)d_in[32];
  const int* adj_rows = (const int*)d_in[33];
  const int* adj_cols = (const int*)d_in[34];
  float* outp = (float*)d_out;

  char* w = (char*)d_ws;
  auto alloc = [&](size_t bytes) -> char* {
    char* p = w;
    w += (bytes + 255) & ~(size_t)255;
    return p;
  };
  float* E1     = (float*)alloc((size_t)NODE_N * DD * 4);
  float* E2     = (float*)alloc((size_t)NODE_N * DD * 4);
  unsigned short* E16    = (unsigned short*)alloc((size_t)NODE_N * DD * 2);
  unsigned short* side16 = (unsigned short*)alloc((size_t)NODE_N * DD * 2);
  unsigned short* p16    = (unsigned short*)alloc((size_t)NODE_N * DD * 2);
  uint2* sedge_r= (uint2*)alloc((size_t)NNZE * 8);   // tile-bucketed (dead after sort)
  uint2* sedge  = (uint2*)alloc((size_t)NNZE * 8);   // row-sorted CSR
  int*   hist   = (int*)  alloc((size_t)NENT * 16 * 4);
  int*   tile_start = (int*)alloc((size_t)(NTILE + 1) * 4);
  int*   cursor = (int*)  alloc((size_t)NENT * 16 * 4);
  int*   row_start = (int*)alloc((size_t)(NODE_N + 1) * 4);
  float* posdot = (float*)alloc((size_t)6 * BB * 4);
  float* ttl    = (float*)alloc((size_t)6 * BB * 4);

  // late-phase buffers aliased onto sedge_r (dead after k_sort_t)
  char* ap = (char*)sedge_r;
  auto alias = [&](size_t bytes) -> char* {
    char* p = ap;
    ap += (bytes + 255) & ~(size_t)255;
    return p;
  };
  float* ue     = (float*)alias((size_t)BB * 64 * 4);
  float* ie     = (float*)alias((size_t)BB * 64 * 4);
  float* recs_u = (float*)alias((size_t)NLV * BB * 32 * 4);
  float* recs_i = (float*)alias((size_t)NLV * BB * 32 * 4);
  float* att_u  = (float*)alias((size_t)BB * 96 * 4);
  float* att_i  = (float*)alias((size_t)BB * 96 * 4);
  unsigned short* n1b = (unsigned short*)alias((size_t)6 * BB * 32 * 2);
  unsigned short* n2b = (unsigned short*)alias((size_t)6 * BB * 32 * 2);

  // host-side: kc = jax.random.split(jax.random.key(42), 2)
  uint32_t a0 = 0, a1 = 2, b0 = 1, b1 = 3;
  tf_block(0u, 42u, a0, a1);
  tf_block(0u, 42u, b0, b1);
  uint32_t ku0 = a0, ku1 = b0;   // kc[0] -> u side
  uint32_t ki0 = a1, ki1 = b1;   // kc[1] -> i side

  hipMemsetAsync(hist, 0, (size_t)NENT * 16 * 4, stream);

  k_init<<<9375, 256, 0, stream>>>(ego, E16);
  k_hist_t<<<9375, 256, 0, stream>>>(adj_rows, hist);
  k_scan_t<<<1, 1024, 0, stream>>>(hist, tile_start, cursor, row_start);
  k_scatter_t<<<9375, 256, 0, stream>>>(adj_rows, adj_cols, adj_vals, cursor, sedge_r);
  k_sort_t<<<NTILE, 256, 0, stream>>>(sedge_r, tile_start, sedge, row_start);

  const float* Eprev = ego;
  float* Ebufs[2] = {E1, E2};
  for (int l = 0; l < 2; ++l) {
    k_spmm<<<37500, 256, 0, stream>>>(E16, sedge, row_start, Eprev, side16, p16);
    k_transform<<<1172, 256, 0, stream>>>(gc_w + l * 4096, gc_b + l * 64,
                                          bi_w + l * 4096, bi_b + l * 64,
                                          side16, p16, Ebufs[l], E16);
    Eprev = Ebufs[l];
  }

  k_gather<<<4096, 128, 0, stream>>>(ego, E1, E2, user_id, item_id, ue, ie);

  dim3 ge(4096, 3);
  k_encoder<<<ge, 256, 0, stream>>>(ue, uh_w, uh_b, ud_w1, ud_b1, ud_w2, ud_b2, recs_u);
  k_encoder<<<ge, 256, 0, stream>>>(ie, ih_w, ih_b, id_w1, id_b1, id_w2, id_b2, recs_i);

  k_attn<<<512, 256, 0, stream>>>(recs_u, q_w, q_b, k_w, k_b, v_w, v_b, att_u);
  k_attn<<<512, 256, 0, stream>>>(recs_i, q_w, q_b, k_w, k_b, v_w, v_b, att_i);

  k_noise<<<3072, 256, 0, stream>>>(att_u, att_i, ku0, ku1, ki0, ki1, n1b, n2b, posdot);

  k_ttl<<<384, 256, 0, stream>>>(n1b, n2b, ttl);
  k_clred<<<1, 1024, 0, stream>>>(ttl, posdot, outp);

  k_head<<<1024, 256, 0, stream>>>(att_u, att_i, skills, dg_w1, dg_b1, dg_w2, dg_b2,
                                   pr_w, pr_b, outp);
}

// Round 9
// 750.919 us; speedup vs baseline: 4.0131x; 1.1302x over previous
//
#include <hip/hip_runtime.h>
#include <stdint.h>
#include <math.h>

#define USER_N 100000
#define NODE_N 150000
#define DD 64
#define NNZE 2400000
#define BB 4096
#define NLV 3
#define LF 32
#define HALF_SZ 196608u  /* (3*4096*32)/2 */
#define NTILE 586        /* ceil(150000/256) */
#define NSUB 8           /* per-tile sub-segments, one per physical XCD */
#define SCAP 768         /* capacity per (tile,xcd) segment; mean 512, +12 sigma */

typedef __attribute__((ext_vector_type(8))) short bf16x8;
typedef __attribute__((ext_vector_type(4))) float f32x4;

// HW_REG_XCC_ID: id=20, offset=0, width=32 -> imm = 20 | (31<<11)
#define XCC_ID_IMM 63508

// ---------------- threefry2x32 (JAX original mode) ----------------
__host__ __device__ inline void tf_block(uint32_t k0, uint32_t k1, uint32_t& x0, uint32_t& x1) {
  uint32_t ks[3] = {k0, k1, k0 ^ k1 ^ 0x1BD11BDAu};
  x0 += ks[0]; x1 += ks[1];
  const int R0[4] = {13, 15, 26, 6};
  const int R1[4] = {17, 29, 16, 24};
#pragma unroll
  for (int i = 0; i < 5; ++i) {
    const int* R = (i & 1) ? R1 : R0;
#pragma unroll
    for (int j = 0; j < 4; ++j) {
      x0 += x1;
      x1 = (x1 << R[j]) | (x1 >> (32 - R[j]));
      x1 ^= x0;
    }
    x0 += ks[(i + 1) % 3];
    x1 += ks[(i + 2) % 3] + (uint32_t)(i + 1);
  }
}

__device__ inline float tf_uniform(uint32_t ka, uint32_t kb, uint32_t m) {
  uint32_t x0, x1;
  bool first = m < HALF_SZ;
  if (first) { x0 = m; x1 = m + HALF_SZ; } else { x0 = m - HALF_SZ; x1 = m; }
  tf_block(ka, kb, x0, x1);
  uint32_t bits = first ? x0 : x1;
  return __uint_as_float((bits >> 9) | 0x3f800000u) - 1.0f;
}

// bf16 round-to-nearest-even
__device__ inline unsigned short f2bf(float x) {
  uint32_t b = __float_as_uint(x);
  return (unsigned short)((b + 0x7FFFu + ((b >> 16) & 1u)) >> 16);
}

// ---------------- kernels ----------------
__global__ __launch_bounds__(256) void k_init(const float* __restrict__ ego,
                                              unsigned short* __restrict__ E16) {
  int i = blockIdx.x * 256 + threadIdx.x;  // float4 index
  float4 v = ((const float4*)ego)[i];
  ushort4 h;
  h.x = f2bf(v.x); h.y = f2bf(v.y); h.z = f2bf(v.z); h.w = f2bf(v.w);
  ((ushort4*)E16)[i] = h;
}

// bucket edges into fixed-capacity (tile, physical-XCD) segments. Each segment
// is written by blocks on ONE XCD (vx = real XCC_ID, not a dispatch guess) ->
// frontier lines fully populated before a single writeback. Fallback to the
// next sub-segment on overflow keeps correctness independent of the mapping.
__global__ __launch_bounds__(256) void k_scatter_t(const int* __restrict__ rows,
                                                   const int* __restrict__ cols,
                                                   const float* __restrict__ vals,
                                                   int* __restrict__ cursor,
                                                   uint2* __restrict__ sedge_r) {
  int e = blockIdx.x * 256 + threadIdx.x;
  if (e >= NNZE) return;
  unsigned vx = __builtin_amdgcn_s_getreg(XCC_ID_IMM) & (NSUB - 1);
  int r = rows[e];
  int tile = r >> 8;
  uint2 rec = make_uint2((uint32_t)cols[e] | ((uint32_t)(r & 255) << 18),
                         __float_as_uint(vals[e]));
#pragma unroll 1
  for (int att = 0; att < NSUB; ++att) {
    int s = (int)((vx + att) & (NSUB - 1));
    int seg = tile * NSUB + s;
    int p = atomicAdd(&cursor[seg * 16], 1);
    if (p < SCAP) {
      sedge_r[(size_t)seg * SCAP + p] = rec;
      return;
    }
  }
}

// tiny scan over 586 tile totals (from cursors) -> out_base for sorted CSR
__global__ __launch_bounds__(1024) void k_scan586(const int* __restrict__ cursor,
                                                  int* __restrict__ out_base,
                                                  int* __restrict__ row_start) {
  __shared__ int buf[1024];
  int t = threadIdx.x;
  int tot = 0;
  if (t < NTILE) {
#pragma unroll
    for (int x = 0; x < NSUB; ++x) {
      int c = cursor[(t * NSUB + x) * 16];
      tot += (c < SCAP) ? c : SCAP;
    }
  }
  buf[t] = tot;
  __syncthreads();
  for (int off = 1; off < 1024; off <<= 1) {
    int add = (t >= off) ? buf[t - off] : 0;
    __syncthreads();
    buf[t] += add;
    __syncthreads();
  }
  if (t < NTILE) out_base[t] = buf[t] - tot;  // exclusive
  if (t == 0) row_start[NODE_N] = NNZE;
}

// per-tile 256-bin counting sort: drains the 8 sub-segments -> row-sorted CSR.
__global__ __launch_bounds__(256) void k_sort_t(const uint2* __restrict__ sedge_r,
                                                const int* __restrict__ cursor,
                                                const int* __restrict__ out_base,
                                                uint2* __restrict__ sedge,
                                                int* __restrict__ row_start) {
  __shared__ int hist[256], buf[256], curs[256];
  int t = threadIdx.x;
  int tile = blockIdx.x;
  int obase = out_base[tile];
  hist[t] = 0;
  __syncthreads();
#pragma unroll 1
  for (int x = 0; x < NSUB; ++x) {
    int seg = tile * NSUB + x;
    int cnt = cursor[seg * 16];
    if (cnt > SCAP) cnt = SCAP;
    const uint2* sp = sedge_r + (size_t)seg * SCAP;
    for (int i = t; i < cnt; i += 256)
      atomicAdd(&hist[sp[i].x >> 18], 1);
  }
  __syncthreads();
  int v = hist[t];
  buf[t] = v;
  __syncthreads();
  for (int off = 1; off < 256; off <<= 1) {
    int add = (t >= off) ? buf[t - off] : 0;
    __syncthreads();
    buf[t] += add;
    __syncthreads();
  }
  int excl = buf[t] - v;
  curs[t] = excl;
  int row = tile * 256 + t;
  if (row < NODE_N) row_start[row] = obase + excl;
  __syncthreads();
#pragma unroll 1
  for (int x = 0; x < NSUB; ++x) {
    int seg = tile * NSUB + x;
    int cnt = cursor[seg * 16];
    if (cnt > SCAP) cnt = SCAP;
    const uint2* sp = sedge_r + (size_t)seg * SCAP;
    for (int i = t; i < cnt; i += 256) {
      uint2 rec = sp[i];
      int rl = rec.x >> 18;
      int p = atomicAdd(&curs[rl], 1);
      sedge[obase + p] = make_uint2(rec.x & 0x3FFFFu, rec.y);
    }
  }
}

// wave-per-row SpMM over sorted CSR, bf16 E gathers. Epilogue emits bf16
// side16 and p16 = bf16(Eprev * side) for the MFMA transform.
__global__ __launch_bounds__(256) void k_spmm(const unsigned short* __restrict__ E16,
                                              const uint2* __restrict__ sedge,
                                              const int* __restrict__ row_start,
                                              const float* __restrict__ Eprev,
                                              unsigned short* __restrict__ side16,
                                              unsigned short* __restrict__ p16) {
  const uint2* E2 = (const uint2*)E16;  // 16 uint2 per row
  int r = blockIdx.x * 4 + (threadIdx.x >> 6);
  int lane = threadIdx.x & 63;
  int g = lane >> 4;
  int q = lane & 15;
  int rs = row_start[r], re = row_start[r + 1];
  float4 acc = make_float4(0.f, 0.f, 0.f, 0.f);
  int e = rs;
#define BF_FMA(rec, a)                                                        \
  {                                                                           \
    float vv = __uint_as_float(rec.y);                                        \
    acc.x = fmaf(vv, __uint_as_float(a.x << 16), acc.x);                      \
    acc.y = fmaf(vv, __uint_as_float(a.x & 0xFFFF0000u), acc.y);              \
    acc.z = fmaf(vv, __uint_as_float(a.y << 16), acc.z);                      \
    acc.w = fmaf(vv, __uint_as_float(a.y & 0xFFFF0000u), acc.w);              \
  }
  for (; e + 16 <= re; e += 16) {
    uint2 e0 = sedge[e + g];
    uint2 e1 = sedge[e + 4 + g];
    uint2 e2 = sedge[e + 8 + g];
    uint2 e3 = sedge[e + 12 + g];
    uint2 a0 = E2[(size_t)e0.x * 16 + q];
    uint2 a1 = E2[(size_t)e1.x * 16 + q];
    uint2 a2 = E2[(size_t)e2.x * 16 + q];
    uint2 a3 = E2[(size_t)e3.x * 16 + q];
    BF_FMA(e0, a0) BF_FMA(e1, a1) BF_FMA(e2, a2) BF_FMA(e3, a3)
  }
  for (; e + 8 <= re; e += 8) {
    uint2 e0 = sedge[e + g];
    uint2 e1 = sedge[e + 4 + g];
    uint2 a0 = E2[(size_t)e0.x * 16 + q];
    uint2 a1 = E2[(size_t)e1.x * 16 + q];
    BF_FMA(e0, a0) BF_FMA(e1, a1)
  }
  for (; e + 4 <= re; e += 4) {
    uint2 e0 = sedge[e + g];
    uint2 a0 = E2[(size_t)e0.x * 16 + q];
    BF_FMA(e0, a0)
  }
  for (; e < re; ++e) {
    if (g == (e & 3)) {
      uint2 e0 = sedge[e];
      uint2 a0 = E2[(size_t)e0.x * 16 + q];
      BF_FMA(e0, a0)
    }
  }
#undef BF_FMA
#pragma unroll
  for (int off = 16; off <= 32; off <<= 1) {
    acc.x += __shfl_xor(acc.x, off, 64);
    acc.y += __shfl_xor(acc.y, off, 64);
    acc.z += __shfl_xor(acc.z, off, 64);
    acc.w += __shfl_xor(acc.w, off, 64);
  }
  if (g == 0) {
    float4 ev = *(const float4*)&Eprev[(size_t)r * DD + q * 4];
    ushort4 s16, pp;
    s16.x = f2bf(acc.x); s16.y = f2bf(acc.y); s16.z = f2bf(acc.z); s16.w = f2bf(acc.w);
    pp.x = f2bf(acc.x * ev.x); pp.y = f2bf(acc.y * ev.y);
    pp.z = f2bf(acc.z * ev.z); pp.w = f2bf(acc.w * ev.w);
    *(ushort4*)&side16[(size_t)r * DD + q * 4] = s16;
    *(ushort4*)&p16[(size_t)r * DD + q * 4] = pp;
  }
}

// MFMA transform (layouts verified r7/r8): E_out = l2norm(leaky(side@gw+gb)
// + leaky((E.side)@bw+bb)). No LDS.
__global__ __launch_bounds__(256) void k_transform(const float* __restrict__ gw,
                                                   const float* __restrict__ gb,
                                                   const float* __restrict__ bw,
                                                   const float* __restrict__ bb,
                                                   const unsigned short* __restrict__ side16,
                                                   const unsigned short* __restrict__ p16,
                                                   float* __restrict__ Eout,
                                                   unsigned short* __restrict__ E16) {
  int t = threadIdx.x;
  int wv = t >> 6, lane = t & 63;
  int n = lane & 15, quad = lane >> 4;
  bf16x8 wg[4][2], wb[4][2];
  float gbl[4], bbl[4];
#pragma unroll
  for (int c = 0; c < 4; ++c) {
    gbl[c] = gb[c * 16 + n];
    bbl[c] = bb[c * 16 + n];
#pragma unroll
    for (int h = 0; h < 2; ++h) {
#pragma unroll
      for (int j = 0; j < 8; ++j) {
        int k = h * 32 + quad * 8 + j;
        wg[c][h][j] = (short)f2bf(gw[k * 64 + c * 16 + n]);
        wb[c][h][j] = (short)f2bf(bw[k * 64 + c * 16 + n]);
      }
    }
  }
  const f32x4 z = {0.f, 0.f, 0.f, 0.f};
  for (int tile = blockIdx.x * 4 + wv; tile < NODE_N / 16; tile += gridDim.x * 4) {
    int i0 = tile * 16;
    bf16x8 as0 = *(const bf16x8*)&side16[(size_t)(i0 + n) * DD + quad * 8];
    bf16x8 as1 = *(const bf16x8*)&side16[(size_t)(i0 + n) * DD + 32 + quad * 8];
    bf16x8 ap0 = *(const bf16x8*)&p16[(size_t)(i0 + n) * DD + quad * 8];
    bf16x8 ap1 = *(const bf16x8*)&p16[(size_t)(i0 + n) * DD + 32 + quad * 8];
    float v[4][4];
    float sq0 = 0.f, sq1 = 0.f, sq2 = 0.f, sq3 = 0.f;
#pragma unroll
    for (int c = 0; c < 4; ++c) {
      f32x4 ag = __builtin_amdgcn_mfma_f32_16x16x32_bf16(as0, wg[c][0], z, 0, 0, 0);
      ag = __builtin_amdgcn_mfma_f32_16x16x32_bf16(as1, wg[c][1], ag, 0, 0, 0);
      f32x4 ab = __builtin_amdgcn_mfma_f32_16x16x32_bf16(ap0, wb[c][0], z, 0, 0, 0);
      ab = __builtin_amdgcn_mfma_f32_16x16x32_bf16(ap1, wb[c][1], ab, 0, 0, 0);
#pragma unroll
      for (int r = 0; r < 4; ++r) {
        float a1 = ag[r] + gbl[c];
        a1 = (a1 > 0.f) ? a1 : 0.01f * a1;
        float a2 = ab[r] + bbl[c];
        a2 = (a2 > 0.f) ? a2 : 0.01f * a2;
        float vv = a1 + a2;
        v[c][r] = vv;
        if (r == 0) sq0 += vv * vv;
        else if (r == 1) sq1 += vv * vv;
        else if (r == 2) sq2 += vv * vv;
        else sq3 += vv * vv;
      }
    }
#pragma unroll
    for (int off = 1; off < 16; off <<= 1) {
      sq0 += __shfl_xor(sq0, off, 64);
      sq1 += __shfl_xor(sq1, off, 64);
      sq2 += __shfl_xor(sq2, off, 64);
      sq3 += __shfl_xor(sq3, off, 64);
    }
    float inv0 = 1.f / fmaxf(sqrtf(sq0), 1e-12f);
    float inv1 = 1.f / fmaxf(sqrtf(sq1), 1e-12f);
    float inv2 = 1.f / fmaxf(sqrtf(sq2), 1e-12f);
    float inv3 = 1.f / fmaxf(sqrtf(sq3), 1e-12f);
#pragma unroll
    for (int c = 0; c < 4; ++c) {
      float vn0 = v[c][0] * inv0;
      float vn1 = v[c][1] * inv1;
      float vn2 = v[c][2] * inv2;
      float vn3 = v[c][3] * inv3;
      size_t o0 = (size_t)(i0 + quad * 4 + 0) * DD + c * 16 + n;
      size_t o1 = o0 + DD, o2 = o1 + DD, o3 = o2 + DD;
      Eout[o0] = vn0; Eout[o1] = vn1; Eout[o2] = vn2; Eout[o3] = vn3;
      E16[o0] = f2bf(vn0); E16[o1] = f2bf(vn1); E16[o2] = f2bf(vn2); E16[o3] = f2bf(vn3);
    }
  }
}

// gather: Esum = ego + E1 + E2 on just the 8192 batch rows.
__global__ __launch_bounds__(128) void k_gather(const float* __restrict__ ego,
                                                const float* __restrict__ E1,
                                                const float* __restrict__ E2,
                                                const int* __restrict__ uid,
                                                const int* __restrict__ iid,
                                                float* __restrict__ ue, float* __restrict__ ie) {
  int b = blockIdx.x, t = threadIdx.x;
  if (t < 64) {
    size_t o = (size_t)uid[b] * 64 + t;
    ue[(size_t)b * 64 + t] = ego[o] + E1[o] + E2[o];
  } else {
    int d = t - 64;
    size_t o = (size_t)(USER_N + iid[b]) * 64 + d;
    ie[(size_t)b * 64 + d] = ego[o] + E1[o] + E2[o];
  }
}

__global__ __launch_bounds__(256) void k_encoder(const float* __restrict__ xin,
                                                 const float* __restrict__ hw, const float* __restrict__ hb,
                                                 const float* __restrict__ w1, const float* __restrict__ b1,
                                                 const float* __restrict__ w2, const float* __restrict__ b2,
                                                 float* __restrict__ recs) {
  __shared__ float sx[64], sreps[64], st[256];
  int b = blockIdx.x, l = blockIdx.y, t = threadIdx.x;
  if (t < 64) sx[t] = xin[(size_t)b * 64 + t];
  __syncthreads();
  if (t < 64) {
    const float* W = hw + l * 64 * 64;
    float a = hb[l * 64 + t];
#pragma unroll 8
    for (int k = 0; k < 64; ++k) a += sx[k] * W[k * 64 + t];
    sreps[t] = tanhf(a);
  }
  __syncthreads();
  {
    const float* W = w1 + l * 64 * 256;
    float a = b1[l * 256 + t];
#pragma unroll 8
    for (int k = 0; k < 64; ++k) a += sreps[k] * W[k * 256 + t];
    st[t] = tanhf(a);
  }
  __syncthreads();
  if (t < 32) {
    const float* W = w2 + l * 256 * 32;
    float a = b2[l * 32 + t];
#pragma unroll 8
    for (int k = 0; k < 256; ++k) a += st[k] * W[k * 32 + t];
    recs[((size_t)l * BB + b) * 32 + t] = a;
  }
}

__global__ __launch_bounds__(256) void k_attn(const float* __restrict__ recs,
                                              const float* __restrict__ qw, const float* __restrict__ qb,
                                              const float* __restrict__ kw, const float* __restrict__ kb,
                                              const float* __restrict__ vw, const float* __restrict__ vb,
                                              float* __restrict__ att) {
  int t = threadIdx.x;
  int b = blockIdx.x * 8 + (t >> 5);
  int d = t & 31;
  float x0 = recs[((size_t)0 * BB + b) * 32 + d];
  float x1 = recs[((size_t)1 * BB + b) * 32 + d];
  float x2 = recs[((size_t)2 * BB + b) * 32 + d];
  float q0 = qb[d], q1 = q0, q2 = q0;
  float c0 = kb[d], c1 = c0, c2 = c0;
  float v0 = vb[d], v1 = v0, v2 = v0;
#pragma unroll 4
  for (int kk = 0; kk < 32; ++kk) {
    float xa = __shfl(x0, kk, 32);
    float xb = __shfl(x1, kk, 32);
    float xc = __shfl(x2, kk, 32);
    float wq = qw[kk * 32 + d], wk = kw[kk * 32 + d], wv = vw[kk * 32 + d];
    q0 += xa * wq; q1 += xb * wq; q2 += xc * wq;
    c0 += xa * wk; c1 += xb * wk; c2 += xc * wk;
    v0 += xa * wv; v1 += xb * wv; v2 += xc * wv;
  }
  float qs[3] = {q0, q1, q2}, ks[3] = {c0, c1, c2}, vs[3] = {v0, v1, v2};
  float sc[3][3];
#pragma unroll
  for (int s = 0; s < 3; ++s)
#pragma unroll
    for (int u = 0; u < 3; ++u) {
      float p = qs[s] * ks[u];
#pragma unroll
      for (int off = 16; off; off >>= 1) p += __shfl_xor(p, off, 32);
      sc[s][u] = p * 0.17677669529663687f;  // 1/sqrt(32)
    }
#pragma unroll
  for (int s = 0; s < 3; ++s) {
    float m = fmaxf(sc[s][0], fmaxf(sc[s][1], sc[s][2]));
    float e0 = __expf(sc[s][0] - m), e1 = __expf(sc[s][1] - m), e2 = __expf(sc[s][2] - m);
    float inv = 1.f / (e0 + e1 + e2);
    att[(size_t)b * 96 + s * 32 + d] = (e0 * vs[0] + e1 * vs[1] + e2 * vs[2]) * inv;
  }
}

// noise: emits l2-normalized recs (n1) and perturbed recs (n2) directly as bf16
// for the MFMA ttl kernel; posdot stays fp32-exact.
__global__ __launch_bounds__(256) void k_noise(const float* __restrict__ att_u,
                                               const float* __restrict__ att_i,
                                               uint32_t ku0, uint32_t ku1, uint32_t ki0, uint32_t ki1,
                                               unsigned short* __restrict__ n1b,
                                               unsigned short* __restrict__ n2b,
                                               float* __restrict__ posdot) {
  int t = threadIdx.x;
  int g = blockIdx.x * 8 + (t >> 5);   // [0, 24576)
  int k = t & 31;
  int side = g / (NLV * BB);
  int rem = g - side * (NLV * BB);
  int l = rem >> 12;
  int b = rem & 4095;
  const float* att = side ? att_i : att_u;
  uint32_t ka = side ? ki0 : ku0;
  uint32_t kb = side ? ki1 : ku1;
  float r = att[(size_t)b * 96 + l * 32 + k];
  float ss = r * r;
#pragma unroll
  for (int off = 16; off; off >>= 1) ss += __shfl_xor(ss, off, 32);
  float v1 = r / fmaxf(sqrtf(ss), 1e-12f);
  uint32_t m = ((uint32_t)(l * BB + b)) * 32u + (uint32_t)k;
  float u = tf_uniform(ka, kb, m);
  float us = u * u;
#pragma unroll
  for (int off = 16; off; off >>= 1) us += __shfl_xor(us, off, 32);
  float un = u / fmaxf(sqrtf(us), 1e-12f);
  float sgn = (r > 0.f) ? 1.f : ((r < 0.f) ? -1.f : 0.f);
  float rn = r + sgn * un * 0.1f;
  float s2 = rn * rn;
#pragma unroll
  for (int off = 16; off; off >>= 1) s2 += __shfl_xor(s2, off, 32);
  float v2 = rn / fmaxf(sqrtf(s2), 1e-12f);
  float pd = v1 * v2;
#pragma unroll
  for (int off = 16; off; off >>= 1) pd += __shfl_xor(pd, off, 32);
  size_t o = (size_t)g * 32 + k;
  n1b[o] = f2bf(v1);
  n2b[o] = f2bf(v2);
  if (k == 0) posdot[g] = pd;
}

// ttl via MFMA (layout verified r7): 6 slices of [4096x4096] = n1.n2^T, K=32.
__global__ __launch_bounds__(256) void k_ttl(const unsigned short* __restrict__ n1b,
                                             const unsigned short* __restrict__ n2b,
                                             float* __restrict__ ttl) {
  int t = threadIdx.x;
  int wv = t >> 6, lane = t & 63;
  int sl = blockIdx.x >> 6;            // 6 slices
  int istripe = blockIdx.x & 63;       // 64 stripes of 64 rows
  int i0 = istripe * 64 + wv * 16;
  const unsigned short* ab = n1b + (size_t)sl * BB * 32;
  const unsigned short* bb = n2b + (size_t)sl * BB * 32;
  int m = lane & 15, quad = lane >> 4;
  bf16x8 afrag = *(const bf16x8*)&ab[(size_t)(i0 + m) * 32 + quad * 8];
  float r0a = 0.f, r1a = 0.f, r2a = 0.f, r3a = 0.f;
  f32x4 z = {0.f, 0.f, 0.f, 0.f};
  for (int jt = 0; jt < 256; jt += 4) {
    bf16x8 b0 = *(const bf16x8*)&bb[((size_t)((jt + 0) * 16 + m)) * 32 + quad * 8];
    bf16x8 b1 = *(const bf16x8*)&bb[((size_t)((jt + 1) * 16 + m)) * 32 + quad * 8];
    bf16x8 b2 = *(const bf16x8*)&bb[((size_t)((jt + 2) * 16 + m)) * 32 + quad * 8];
    bf16x8 b3 = *(const bf16x8*)&bb[((size_t)((jt + 3) * 16 + m)) * 32 + quad * 8];
    f32x4 s0 = __builtin_amdgcn_mfma_f32_16x16x32_bf16(afrag, b0, z, 0, 0, 0);
    f32x4 s1 = __builtin_amdgcn_mfma_f32_16x16x32_bf16(afrag, b1, z, 0, 0, 0);
    f32x4 s2 = __builtin_amdgcn_mfma_f32_16x16x32_bf16(afrag, b2, z, 0, 0, 0);
    f32x4 s3 = __builtin_amdgcn_mfma_f32_16x16x32_bf16(afrag, b3, z, 0, 0, 0);
    r0a += __expf(s0.x * 5.f) + __expf(s1.x * 5.f) + __expf(s2.x * 5.f) + __expf(s3.x * 5.f);
    r1a += __expf(s0.y * 5.f) + __expf(s1.y * 5.f) + __expf(s2.y * 5.f) + __expf(s3.y * 5.f);
    r2a += __expf(s0.z * 5.f) + __expf(s1.z * 5.f) + __expf(s2.z * 5.f) + __expf(s3.z * 5.f);
    r3a += __expf(s0.w * 5.f) + __expf(s1.w * 5.f) + __expf(s2.w * 5.f) + __expf(s3.w * 5.f);
  }
#pragma unroll
  for (int off = 1; off < 16; off <<= 1) {
    r0a += __shfl_xor(r0a, off, 64);
    r1a += __shfl_xor(r1a, off, 64);
    r2a += __shfl_xor(r2a, off, 64);
    r3a += __shfl_xor(r3a, off, 64);
  }
  if (m == 0) {
    int rbase = sl * BB + i0 + quad * 4;
    ttl[rbase + 0] = r0a;
    ttl[rbase + 1] = r1a;
    ttl[rbase + 2] = r2a;
    ttl[rbase + 3] = r3a;
  }
}

__global__ __launch_bounds__(1024) void k_clred(const float* __restrict__ ttl,
                                                const float* __restrict__ posdot,
                                                float* __restrict__ outp) {
  __shared__ float red[1024];
  int t = threadIdx.x;
  float a = 0.f;
  for (int idx = t; idx < 6 * BB; idx += 1024)
    a += logf(ttl[idx]) - posdot[idx] * 5.0f;
  red[t] = a;
  __syncthreads();
  for (int off = 512; off; off >>= 1) {
    if (t < off) red[t] += red[t + off];
    __syncthreads();
  }
  if (t == 0) outp[2 * BB] = red[0] * (1.f / 12288.f);  // (cl_u + cl_i)
}

__global__ __launch_bounds__(256) void k_head(const float* __restrict__ att_u,
                                              const float* __restrict__ att_i,
                                              const float* __restrict__ skills,
                                              const float* __restrict__ w1, const float* __restrict__ b1,
                                              const float* __restrict__ w2, const float* __restrict__ b2,
                                              const float* __restrict__ pw, const float* __restrict__ pb,
                                              float* __restrict__ outp) {
  __shared__ float diag[4][96], t1[4][64];
  int t = threadIdx.x;
  int w = t >> 6, lane = t & 63;
  int b = blockIdx.x * 4 + w;
  for (int j = lane; j < 96; j += 64) {
    float su = 1.f / (1.f + __expf(-att_u[(size_t)b * 96 + j]));
    float si = 1.f / (1.f + __expf(-att_i[(size_t)b * 96 + j]));
    diag[w][j] = (su - si) * skills[(size_t)b * 96 + j];
  }
  __syncthreads();
  float a = b1[lane];
#pragma unroll 8
  for (int j = 0; j < 96; ++j) a += diag[w][j] * w1[j * 64 + lane];
  t1[w][lane] = tanhf(a);
  __syncthreads();
  float h = b2[lane];
#pragma unroll 8
  for (int kk = 0; kk < 64; ++kk) h += t1[w][kk] * w2[kk * 64 + lane];
  float p0 = h * pw[lane * 2 + 0];
  float p1 = h * pw[lane * 2 + 1];
#pragma unroll
  for (int off = 32; off; off >>= 1) {
    p0 += __shfl_xor(p0, off, 64);
    p1 += __shfl_xor(p1, off, 64);
  }
  if (lane == 0) {
    float l0 = p0 + pb[0], l1 = p1 + pb[1];
    float m = fmaxf(l0, l1);
    float e0 = __expf(l0 - m), e1 = __expf(l1 - m);
    float inv = 1.f / (e0 + e1);
    outp[(size_t)b * 2 + 0] = e0 * inv;
    outp[(size_t)b * 2 + 1] = e1 * inv;
  }
}

// ---------------- launcher ----------------
extern "C" void kernel_launch(void* const* d_in, const int* in_sizes, int n_in,
                              void* d_out, int out_size, void* d_ws, size_t ws_size,
                              hipStream_t stream) {
  const float* ego    = (const float*)d_in[0];
  const float* gc_w   = (const float*)d_in[1];
  const float* gc_b   = (const float*)d_in[2];
  const float* bi_w   = (const float*)d_in[3];
  const float* bi_b   = (const float*)d_in[4];
  const float* uh_w   = (const float*)d_in[5];
  const float* uh_b   = (const float*)d_in[6];
  const float* ih_w   = (const float*)d_in[7];
  const float* ih_b   = (const float*)d_in[8];
  const float* ud_w1  = (const float*)d_in[9];
  const float* ud_b1  = (const float*)d_in[10];
  const float* ud_w2  = (const float*)d_in[11];
  const float* ud_b2  = (const float*)d_in[12];
  const float* id_w1  = (const float*)d_in[13];
  const float* id_b1  = (const float*)d_in[14];
  const float* id_w2  = (const float*)d_in[15];
  const float* id_b2  = (const float*)d_in[16];
  const float* q_w    = (const float*)d_in[17];
  const float* q_b    = (const float*)d_in[18];
  const float* k_w    = (const float*)d_in[19];
  const float* k_b    = (const float*)d_in[20];
  const float* v_w    = (const float*)d_in[21];
  const float* v_b    = (const float*)d_in[22];
  const float* dg_w1  = (const float*)d_in[23];
  const float* dg_b1  = (const float*)d_in[24];
  const float* dg_w2  = (const float*)d_in[25];
  const float* dg_b2  = (const float*)d_in[26];
  const float* pr_w   = (const float*)d_in[27];
  const float* pr_b   = (const float*)d_in[28];
  const float* adj_vals = (const float*)d_in[29];
  const float* skills = (const float*)d_in[30];
  const int* user_id  = (const int*)d_in[31];
  const int* item_id  = (const int*)d_in[32];
  const int* adj_rows = (const int*)d_in[33];
  const int* adj_cols = (const int*)d_in[34];
  float* outp = (float*)d_out;

  char* w = (char*)d_ws;
  auto alloc = [&](size_t bytes) -> char* {
    char* p = w;
    w += (bytes + 255) & ~(size_t)255;
    return p;
  };
  float* E1     = (float*)alloc((size_t)NODE_N * DD * 4);
  float* E2     = (float*)alloc((size_t)NODE_N * DD * 4);
  unsigned short* E16    = (unsigned short*)alloc((size_t)NODE_N * DD * 2);
  unsigned short* side16 = (unsigned short*)alloc((size_t)NODE_N * DD * 2);
  unsigned short* p16    = (unsigned short*)alloc((size_t)NODE_N * DD * 2);
  uint2* sedge_r= (uint2*)alloc((size_t)NTILE * NSUB * SCAP * 8);  // 28.8MB, dead after sort
  uint2* sedge  = (uint2*)alloc((size_t)NNZE * 8);   // row-sorted CSR
  int*   cursor = (int*)  alloc((size_t)NTILE * NSUB * 16 * 4);
  int*   out_base = (int*)alloc((size_t)(NTILE + 1) * 4);
  int*   row_start = (int*)alloc((size_t)(NODE_N + 1) * 4);
  float* posdot = (float*)alloc((size_t)6 * BB * 4);
  float* ttl    = (float*)alloc((size_t)6 * BB * 4);

  // late-phase buffers aliased onto sedge_r (dead after k_sort_t)
  char* ap = (char*)sedge_r;
  auto alias = [&](size_t bytes) -> char* {
    char* p = ap;
    ap += (bytes + 255) & ~(size_t)255;
    return p;
  };
  float* ue     = (float*)alias((size_t)BB * 64 * 4);
  float* ie     = (float*)alias((size_t)BB * 64 * 4);
  float* recs_u = (float*)alias((size_t)NLV * BB * 32 * 4);
  float* recs_i = (float*)alias((size_t)NLV * BB * 32 * 4);
  float* att_u  = (float*)alias((size_t)BB * 96 * 4);
  float* att_i  = (float*)alias((size_t)BB * 96 * 4);
  unsigned short* n1b = (unsigned short*)alias((size_t)6 * BB * 32 * 2);
  unsigned short* n2b = (unsigned short*)alias((size_t)6 * BB * 32 * 2);

  // host-side: kc = jax.random.split(jax.random.key(42), 2)
  uint32_t a0 = 0, a1 = 2, b0 = 1, b1 = 3;
  tf_block(0u, 42u, a0, a1);
  tf_block(0u, 42u, b0, b1);
  uint32_t ku0 = a0, ku1 = b0;   // kc[0] -> u side
  uint32_t ki0 = a1, ki1 = b1;   // kc[1] -> i side

  hipMemsetAsync(cursor, 0, (size_t)NTILE * NSUB * 16 * 4, stream);

  k_init<<<9375, 256, 0, stream>>>(ego, E16);
  k_scatter_t<<<9375, 256, 0, stream>>>(adj_rows, adj_cols, adj_vals, cursor, sedge_r);
  k_scan586<<<1, 1024, 0, stream>>>(cursor, out_base, row_start);
  k_sort_t<<<NTILE, 256, 0, stream>>>(sedge_r, cursor, out_base, sedge, row_start);

  const float* Eprev = ego;
  float* Ebufs[2] = {E1, E2};
  for (int l = 0; l < 2; ++l) {
    k_spmm<<<37500, 256, 0, stream>>>(E16, sedge, row_start, Eprev, side16, p16);
    k_transform<<<1172, 256, 0, stream>>>(gc_w + l * 4096, gc_b + l * 64,
                                          bi_w + l * 4096, bi_b + l * 64,
                                          side16, p16, Ebufs[l], E16);
    Eprev = Ebufs[l];
  }

  k_gather<<<4096, 128, 0, stream>>>(ego, E1, E2, user_id, item_id, ue, ie);

  dim3 ge(4096, 3);
  k_encoder<<<ge, 256, 0, stream>>>(ue, uh_w, uh_b, ud_w1, ud_b1, ud_w2, ud_b2, recs_u);
  k_encoder<<<ge, 256, 0, stream>>>(ie, ih_w, ih_b, id_w1, id_b1, id_w2, id_b2, recs_i);

  k_attn<<<512, 256, 0, stream>>>(recs_u, q_w, q_b, k_w, k_b, v_w, v_b, att_u);
  k_attn<<<512, 256, 0, stream>>>(recs_i, q_w, q_b, k_w, k_b, v_w, v_b, att_i);

  k_noise<<<3072, 256, 0, stream>>>(att_u, att_i, ku0, ku1, ki0, ki1, n1b, n2b, posdot);

  k_ttl<<<384, 256, 0, stream>>>(n1b, n2b, ttl);
  k_clred<<<1, 1024, 0, stream>>>(ttl, posdot, outp);

  k_head<<<1024, 256, 0, stream>>>(att_u, att_i, skills, dg_w1, dg_b1, dg_w2, dg_b2,
                                   pr_w, pr_b, outp);
}

// Round 10
// 702.578 us; speedup vs baseline: 4.2893x; 1.0688x over previous
//
#include <hip/hip_runtime.h>
#include <stdint.h>
#include <math.h>

#define USER_N 100000
#define NODE_N 150000
#define DD 64
#define NNZE 2400000
#define BB 4096
#define NLV 3
#define LF 32
#define HALF_SZ 196608u  /* (3*4096*32)/2 */
#define NTILE 586        /* ceil(150000/256) */
#define NSUB 8           /* per-tile sub-segments, one per physical XCD */
#define SCAP 1024        /* capacity per (tile,xcd) segment; mean 512 */
#define EPB 4096         /* edges per scatter block */

typedef __attribute__((ext_vector_type(8))) short bf16x8;
typedef __attribute__((ext_vector_type(4))) float f32x4;

// HW_REG_XCC_ID: id=20, offset=0, width=32 -> imm = 20 | (31<<11)
#define XCC_ID_IMM 63508

// ---------------- threefry2x32 (JAX original mode) ----------------
__host__ __device__ inline void tf_block(uint32_t k0, uint32_t k1, uint32_t& x0, uint32_t& x1) {
  uint32_t ks[3] = {k0, k1, k0 ^ k1 ^ 0x1BD11BDAu};
  x0 += ks[0]; x1 += ks[1];
  const int R0[4] = {13, 15, 26, 6};
  const int R1[4] = {17, 29, 16, 24};
#pragma unroll
  for (int i = 0; i < 5; ++i) {
    const int* R = (i & 1) ? R1 : R0;
#pragma unroll
    for (int j = 0; j < 4; ++j) {
      x0 += x1;
      x1 = (x1 << R[j]) | (x1 >> (32 - R[j]));
      x1 ^= x0;
    }
    x0 += ks[(i + 1) % 3];
    x1 += ks[(i + 2) % 3] + (uint32_t)(i + 1);
  }
}

__device__ inline float tf_uniform(uint32_t ka, uint32_t kb, uint32_t m) {
  uint32_t x0, x1;
  bool first = m < HALF_SZ;
  if (first) { x0 = m; x1 = m + HALF_SZ; } else { x0 = m - HALF_SZ; x1 = m; }
  tf_block(ka, kb, x0, x1);
  uint32_t bits = first ? x0 : x1;
  return __uint_as_float((bits >> 9) | 0x3f800000u) - 1.0f;
}

// bf16 round-to-nearest-even
__device__ inline unsigned short f2bf(float x) {
  uint32_t b = __float_as_uint(x);
  return (unsigned short)((b + 0x7FFFu + ((b >> 16) & 1u)) >> 16);
}

// ---------------- kernels ----------------
__global__ __launch_bounds__(256) void k_init(const float* __restrict__ ego,
                                              unsigned short* __restrict__ E16) {
  int i = blockIdx.x * 256 + threadIdx.x;  // float4 index
  float4 v = ((const float4*)ego)[i];
  ushort4 h;
  h.x = f2bf(v.x); h.y = f2bf(v.y); h.z = f2bf(v.z); h.w = f2bf(v.w);
  ((ushort4*)E16)[i] = h;
}

// Block-aggregated scatter: LDS histogram over 586 tiles -> ONE global atomic
// per (tile, block) reserving a contiguous range in this XCD's segment ->
// records placed via LDS sub-cursors. Cuts global atomics 2.4M -> ~340K
// (r9's 96MB WRITE_SIZE was dominated by per-record atomic RMW traffic).
// Overflow past SCAP falls back to per-record atomics on neighbor segments.
__global__ __launch_bounds__(256) void k_scatter_t(const int* __restrict__ rows,
                                                   const int* __restrict__ cols,
                                                   const float* __restrict__ vals,
                                                   int* __restrict__ cursor,
                                                   uint2* __restrict__ sedge_r) {
  __shared__ int cnt[NTILE];
  __shared__ int curs[NTILE];
  int t = threadIdx.x;
  for (int i = t; i < NTILE; i += 256) cnt[i] = 0;
  __syncthreads();
  int r[16];
  int ebase = blockIdx.x * EPB;
#pragma unroll
  for (int j = 0; j < 16; ++j) {
    int e = ebase + j * 256 + t;
    r[j] = (e < NNZE) ? rows[e] : -1;
    if (r[j] >= 0) atomicAdd(&cnt[r[j] >> 8], 1);
  }
  __syncthreads();
  unsigned myx = __builtin_amdgcn_s_getreg(XCC_ID_IMM) & (NSUB - 1);
  for (int i = t; i < NTILE; i += 256) {
    int c = cnt[i];
    curs[i] = c ? atomicAdd(&cursor[(i * NSUB + (int)myx) * 16], c) : 0;
  }
  __syncthreads();
#pragma unroll
  for (int j = 0; j < 16; ++j) {
    if (r[j] < 0) continue;
    int e = ebase + j * 256 + t;
    int tile = r[j] >> 8;
    uint2 rec = make_uint2((uint32_t)cols[e] | ((uint32_t)(r[j] & 255) << 18),
                           __float_as_uint(vals[e]));
    int p = atomicAdd(&curs[tile], 1);
    if (p < SCAP) {
      sedge_r[(size_t)(tile * NSUB + (int)myx) * SCAP + p] = rec;
    } else {
#pragma unroll 1
      for (int att = 1; att < NSUB; ++att) {
        int seg = tile * NSUB + (int)((myx + att) & (NSUB - 1));
        int p2 = atomicAdd(&cursor[seg * 16], 1);
        if (p2 < SCAP) { sedge_r[(size_t)seg * SCAP + p2] = rec; break; }
      }
    }
  }
}

// tiny scan over 586 tile totals (from cursors) -> out_base for sorted CSR
__global__ __launch_bounds__(1024) void k_scan586(const int* __restrict__ cursor,
                                                  int* __restrict__ out_base,
                                                  int* __restrict__ row_start) {
  __shared__ int buf[1024];
  int t = threadIdx.x;
  int tot = 0;
  if (t < NTILE) {
#pragma unroll
    for (int x = 0; x < NSUB; ++x) {
      int c = cursor[(t * NSUB + x) * 16];
      tot += (c < SCAP) ? c : SCAP;
    }
  }
  buf[t] = tot;
  __syncthreads();
  for (int off = 1; off < 1024; off <<= 1) {
    int add = (t >= off) ? buf[t - off] : 0;
    __syncthreads();
    buf[t] += add;
    __syncthreads();
  }
  if (t < NTILE) out_base[t] = buf[t] - tot;  // exclusive
  if (t == 0) row_start[NODE_N] = NNZE;
}

// per-tile 256-bin counting sort: drains the 8 sub-segments -> row-sorted CSR.
__global__ __launch_bounds__(256) void k_sort_t(const uint2* __restrict__ sedge_r,
                                                const int* __restrict__ cursor,
                                                const int* __restrict__ out_base,
                                                uint2* __restrict__ sedge,
                                                int* __restrict__ row_start) {
  __shared__ int hist[256], buf[256], curs[256];
  int t = threadIdx.x;
  int tile = blockIdx.x;
  int obase = out_base[tile];
  hist[t] = 0;
  __syncthreads();
#pragma unroll 1
  for (int x = 0; x < NSUB; ++x) {
    int seg = tile * NSUB + x;
    int cnt = cursor[seg * 16];
    if (cnt > SCAP) cnt = SCAP;
    const uint2* sp = sedge_r + (size_t)seg * SCAP;
    for (int i = t; i < cnt; i += 256)
      atomicAdd(&hist[sp[i].x >> 18], 1);
  }
  __syncthreads();
  int v = hist[t];
  buf[t] = v;
  __syncthreads();
  for (int off = 1; off < 256; off <<= 1) {
    int add = (t >= off) ? buf[t - off] : 0;
    __syncthreads();
    buf[t] += add;
    __syncthreads();
  }
  int excl = buf[t] - v;
  curs[t] = excl;
  int row = tile * 256 + t;
  if (row < NODE_N) row_start[row] = obase + excl;
  __syncthreads();
#pragma unroll 1
  for (int x = 0; x < NSUB; ++x) {
    int seg = tile * NSUB + x;
    int cnt = cursor[seg * 16];
    if (cnt > SCAP) cnt = SCAP;
    const uint2* sp = sedge_r + (size_t)seg * SCAP;
    for (int i = t; i < cnt; i += 256) {
      uint2 rec = sp[i];
      int rl = rec.x >> 18;
      int p = atomicAdd(&curs[rl], 1);
      sedge[obase + p] = make_uint2(rec.x & 0x3FFFFu, rec.y);
    }
  }
}

// wave-per-row SpMM over sorted CSR, bf16 E gathers. Epilogue emits bf16
// side16 and p16 = bf16(Eprev * side) for the MFMA transform.
__global__ __launch_bounds__(256) void k_spmm(const unsigned short* __restrict__ E16,
                                              const uint2* __restrict__ sedge,
                                              const int* __restrict__ row_start,
                                              const float* __restrict__ Eprev,
                                              unsigned short* __restrict__ side16,
                                              unsigned short* __restrict__ p16) {
  const uint2* E2 = (const uint2*)E16;  // 16 uint2 per row
  int r = blockIdx.x * 4 + (threadIdx.x >> 6);
  int lane = threadIdx.x & 63;
  int g = lane >> 4;
  int q = lane & 15;
  int rs = row_start[r], re = row_start[r + 1];
  float4 acc = make_float4(0.f, 0.f, 0.f, 0.f);
  int e = rs;
#define BF_FMA(rec, a)                                                        \
  {                                                                           \
    float vv = __uint_as_float(rec.y);                                        \
    acc.x = fmaf(vv, __uint_as_float(a.x << 16), acc.x);                      \
    acc.y = fmaf(vv, __uint_as_float(a.x & 0xFFFF0000u), acc.y);              \
    acc.z = fmaf(vv, __uint_as_float(a.y << 16), acc.z);                      \
    acc.w = fmaf(vv, __uint_as_float(a.y & 0xFFFF0000u), acc.w);              \
  }
  for (; e + 16 <= re; e += 16) {
    uint2 e0 = sedge[e + g];
    uint2 e1 = sedge[e + 4 + g];
    uint2 e2 = sedge[e + 8 + g];
    uint2 e3 = sedge[e + 12 + g];
    uint2 a0 = E2[(size_t)e0.x * 16 + q];
    uint2 a1 = E2[(size_t)e1.x * 16 + q];
    uint2 a2 = E2[(size_t)e2.x * 16 + q];
    uint2 a3 = E2[(size_t)e3.x * 16 + q];
    BF_FMA(e0, a0) BF_FMA(e1, a1) BF_FMA(e2, a2) BF_FMA(e3, a3)
  }
  for (; e + 8 <= re; e += 8) {
    uint2 e0 = sedge[e + g];
    uint2 e1 = sedge[e + 4 + g];
    uint2 a0 = E2[(size_t)e0.x * 16 + q];
    uint2 a1 = E2[(size_t)e1.x * 16 + q];
    BF_FMA(e0, a0) BF_FMA(e1, a1)
  }
  for (; e + 4 <= re; e += 4) {
    uint2 e0 = sedge[e + g];
    uint2 a0 = E2[(size_t)e0.x * 16 + q];
    BF_FMA(e0, a0)
  }
  for (; e < re; ++e) {
    if (g == (e & 3)) {
      uint2 e0 = sedge[e];
      uint2 a0 = E2[(size_t)e0.x * 16 + q];
      BF_FMA(e0, a0)
    }
  }
#undef BF_FMA
#pragma unroll
  for (int off = 16; off <= 32; off <<= 1) {
    acc.x += __shfl_xor(acc.x, off, 64);
    acc.y += __shfl_xor(acc.y, off, 64);
    acc.z += __shfl_xor(acc.z, off, 64);
    acc.w += __shfl_xor(acc.w, off, 64);
  }
  if (g == 0) {
    float4 ev = *(const float4*)&Eprev[(size_t)r * DD + q * 4];
    ushort4 s16, pp;
    s16.x = f2bf(acc.x); s16.y = f2bf(acc.y); s16.z = f2bf(acc.z); s16.w = f2bf(acc.w);
    pp.x = f2bf(acc.x * ev.x); pp.y = f2bf(acc.y * ev.y);
    pp.z = f2bf(acc.z * ev.z); pp.w = f2bf(acc.w * ev.w);
    *(ushort4*)&side16[(size_t)r * DD + q * 4] = s16;
    *(ushort4*)&p16[(size_t)r * DD + q * 4] = pp;
  }
}

// MFMA transform (layouts verified r7/r8): E_out = l2norm(leaky(side@gw+gb)
// + leaky((E.side)@bw+bb)). No LDS.
__global__ __launch_bounds__(256) void k_transform(const float* __restrict__ gw,
                                                   const float* __restrict__ gb,
                                                   const float* __restrict__ bw,
                                                   const float* __restrict__ bb,
                                                   const unsigned short* __restrict__ side16,
                                                   const unsigned short* __restrict__ p16,
                                                   float* __restrict__ Eout,
                                                   unsigned short* __restrict__ E16) {
  int t = threadIdx.x;
  int wv = t >> 6, lane = t & 63;
  int n = lane & 15, quad = lane >> 4;
  bf16x8 wg[4][2], wb[4][2];
  float gbl[4], bbl[4];
#pragma unroll
  for (int c = 0; c < 4; ++c) {
    gbl[c] = gb[c * 16 + n];
    bbl[c] = bb[c * 16 + n];
#pragma unroll
    for (int h = 0; h < 2; ++h) {
#pragma unroll
      for (int j = 0; j < 8; ++j) {
        int k = h * 32 + quad * 8 + j;
        wg[c][h][j] = (short)f2bf(gw[k * 64 + c * 16 + n]);
        wb[c][h][j] = (short)f2bf(bw[k * 64 + c * 16 + n]);
      }
    }
  }
  const f32x4 z = {0.f, 0.f, 0.f, 0.f};
  for (int tile = blockIdx.x * 4 + wv; tile < NODE_N / 16; tile += gridDim.x * 4) {
    int i0 = tile * 16;
    bf16x8 as0 = *(const bf16x8*)&side16[(size_t)(i0 + n) * DD + quad * 8];
    bf16x8 as1 = *(const bf16x8*)&side16[(size_t)(i0 + n) * DD + 32 + quad * 8];
    bf16x8 ap0 = *(const bf16x8*)&p16[(size_t)(i0 + n) * DD + quad * 8];
    bf16x8 ap1 = *(const bf16x8*)&p16[(size_t)(i0 + n) * DD + 32 + quad * 8];
    float v[4][4];
    float sq0 = 0.f, sq1 = 0.f, sq2 = 0.f, sq3 = 0.f;
#pragma unroll
    for (int c = 0; c < 4; ++c) {
      f32x4 ag = __builtin_amdgcn_mfma_f32_16x16x32_bf16(as0, wg[c][0], z, 0, 0, 0);
      ag = __builtin_amdgcn_mfma_f32_16x16x32_bf16(as1, wg[c][1], ag, 0, 0, 0);
      f32x4 ab = __builtin_amdgcn_mfma_f32_16x16x32_bf16(ap0, wb[c][0], z, 0, 0, 0);
      ab = __builtin_amdgcn_mfma_f32_16x16x32_bf16(ap1, wb[c][1], ab, 0, 0, 0);
#pragma unroll
      for (int r = 0; r < 4; ++r) {
        float a1 = ag[r] + gbl[c];
        a1 = (a1 > 0.f) ? a1 : 0.01f * a1;
        float a2 = ab[r] + bbl[c];
        a2 = (a2 > 0.f) ? a2 : 0.01f * a2;
        float vv = a1 + a2;
        v[c][r] = vv;
        if (r == 0) sq0 += vv * vv;
        else if (r == 1) sq1 += vv * vv;
        else if (r == 2) sq2 += vv * vv;
        else sq3 += vv * vv;
      }
    }
#pragma unroll
    for (int off = 1; off < 16; off <<= 1) {
      sq0 += __shfl_xor(sq0, off, 64);
      sq1 += __shfl_xor(sq1, off, 64);
      sq2 += __shfl_xor(sq2, off, 64);
      sq3 += __shfl_xor(sq3, off, 64);
    }
    float inv0 = 1.f / fmaxf(sqrtf(sq0), 1e-12f);
    float inv1 = 1.f / fmaxf(sqrtf(sq1), 1e-12f);
    float inv2 = 1.f / fmaxf(sqrtf(sq2), 1e-12f);
    float inv3 = 1.f / fmaxf(sqrtf(sq3), 1e-12f);
#pragma unroll
    for (int c = 0; c < 4; ++c) {
      float vn0 = v[c][0] * inv0;
      float vn1 = v[c][1] * inv1;
      float vn2 = v[c][2] * inv2;
      float vn3 = v[c][3] * inv3;
      size_t o0 = (size_t)(i0 + quad * 4 + 0) * DD + c * 16 + n;
      size_t o1 = o0 + DD, o2 = o1 + DD, o3 = o2 + DD;
      Eout[o0] = vn0; Eout[o1] = vn1; Eout[o2] = vn2; Eout[o3] = vn3;
      E16[o0] = f2bf(vn0); E16[o1] = f2bf(vn1); E16[o2] = f2bf(vn2); E16[o3] = f2bf(vn3);
    }
  }
}

// gather: Esum = ego + E1 + E2 on just the 8192 batch rows.
__global__ __launch_bounds__(128) void k_gather(const float* __restrict__ ego,
                                                const float* __restrict__ E1,
                                                const float* __restrict__ E2,
                                                const int* __restrict__ uid,
                                                const int* __restrict__ iid,
                                                float* __restrict__ ue, float* __restrict__ ie) {
  int b = blockIdx.x, t = threadIdx.x;
  if (t < 64) {
    size_t o = (size_t)uid[b] * 64 + t;
    ue[(size_t)b * 64 + t] = ego[o] + E1[o] + E2[o];
  } else {
    int d = t - 64;
    size_t o = (size_t)(USER_N + iid[b]) * 64 + d;
    ie[(size_t)b * 64 + d] = ego[o] + E1[o] + E2[o];
  }
}

__global__ __launch_bounds__(256) void k_encoder(const float* __restrict__ xin,
                                                 const float* __restrict__ hw, const float* __restrict__ hb,
                                                 const float* __restrict__ w1, const float* __restrict__ b1,
                                                 const float* __restrict__ w2, const float* __restrict__ b2,
                                                 float* __restrict__ recs) {
  __shared__ float sx[64], sreps[64], st[256];
  int b = blockIdx.x, l = blockIdx.y, t = threadIdx.x;
  if (t < 64) sx[t] = xin[(size_t)b * 64 + t];
  __syncthreads();
  if (t < 64) {
    const float* W = hw + l * 64 * 64;
    float a = hb[l * 64 + t];
#pragma unroll 8
    for (int k = 0; k < 64; ++k) a += sx[k] * W[k * 64 + t];
    sreps[t] = tanhf(a);
  }
  __syncthreads();
  {
    const float* W = w1 + l * 64 * 256;
    float a = b1[l * 256 + t];
#pragma unroll 8
    for (int k = 0; k < 64; ++k) a += sreps[k] * W[k * 256 + t];
    st[t] = tanhf(a);
  }
  __syncthreads();
  if (t < 32) {
    const float* W = w2 + l * 256 * 32;
    float a = b2[l * 32 + t];
#pragma unroll 8
    for (int k = 0; k < 256; ++k) a += st[k] * W[k * 32 + t];
    recs[((size_t)l * BB + b) * 32 + t] = a;
  }
}

__global__ __launch_bounds__(256) void k_attn(const float* __restrict__ recs,
                                              const float* __restrict__ qw, const float* __restrict__ qb,
                                              const float* __restrict__ kw, const float* __restrict__ kb,
                                              const float* __restrict__ vw, const float* __restrict__ vb,
                                              float* __restrict__ att) {
  int t = threadIdx.x;
  int b = blockIdx.x * 8 + (t >> 5);
  int d = t & 31;
  float x0 = recs[((size_t)0 * BB + b) * 32 + d];
  float x1 = recs[((size_t)1 * BB + b) * 32 + d];
  float x2 = recs[((size_t)2 * BB + b) * 32 + d];
  float q0 = qb[d], q1 = q0, q2 = q0;
  float c0 = kb[d], c1 = c0, c2 = c0;
  float v0 = vb[d], v1 = v0, v2 = v0;
#pragma unroll 4
  for (int kk = 0; kk < 32; ++kk) {
    float xa = __shfl(x0, kk, 32);
    float xb = __shfl(x1, kk, 32);
    float xc = __shfl(x2, kk, 32);
    float wq = qw[kk * 32 + d], wk = kw[kk * 32 + d], wv = vw[kk * 32 + d];
    q0 += xa * wq; q1 += xb * wq; q2 += xc * wq;
    c0 += xa * wk; c1 += xb * wk; c2 += xc * wk;
    v0 += xa * wv; v1 += xb * wv; v2 += xc * wv;
  }
  float qs[3] = {q0, q1, q2}, ks[3] = {c0, c1, c2}, vs[3] = {v0, v1, v2};
  float sc[3][3];
#pragma unroll
  for (int s = 0; s < 3; ++s)
#pragma unroll
    for (int u = 0; u < 3; ++u) {
      float p = qs[s] * ks[u];
#pragma unroll
      for (int off = 16; off; off >>= 1) p += __shfl_xor(p, off, 32);
      sc[s][u] = p * 0.17677669529663687f;  // 1/sqrt(32)
    }
#pragma unroll
  for (int s = 0; s < 3; ++s) {
    float m = fmaxf(sc[s][0], fmaxf(sc[s][1], sc[s][2]));
    float e0 = __expf(sc[s][0] - m), e1 = __expf(sc[s][1] - m), e2 = __expf(sc[s][2] - m);
    float inv = 1.f / (e0 + e1 + e2);
    att[(size_t)b * 96 + s * 32 + d] = (e0 * vs[0] + e1 * vs[1] + e2 * vs[2]) * inv;
  }
}

// noise: emits l2-normalized recs (n1) and perturbed recs (n2) directly as bf16
// for the MFMA ttl kernel; posdot stays fp32-exact.
__global__ __launch_bounds__(256) void k_noise(const float* __restrict__ att_u,
                                               const float* __restrict__ att_i,
                                               uint32_t ku0, uint32_t ku1, uint32_t ki0, uint32_t ki1,
                                               unsigned short* __restrict__ n1b,
                                               unsigned short* __restrict__ n2b,
                                               float* __restrict__ posdot) {
  int t = threadIdx.x;
  int g = blockIdx.x * 8 + (t >> 5);   // [0, 24576)
  int k = t & 31;
  int side = g / (NLV * BB);
  int rem = g - side * (NLV * BB);
  int l = rem >> 12;
  int b = rem & 4095;
  const float* att = side ? att_i : att_u;
  uint32_t ka = side ? ki0 : ku0;
  uint32_t kb = side ? ki1 : ku1;
  float r = att[(size_t)b * 96 + l * 32 + k];
  float ss = r * r;
#pragma unroll
  for (int off = 16; off; off >>= 1) ss += __shfl_xor(ss, off, 32);
  float v1 = r / fmaxf(sqrtf(ss), 1e-12f);
  uint32_t m = ((uint32_t)(l * BB + b)) * 32u + (uint32_t)k;
  float u = tf_uniform(ka, kb, m);
  float us = u * u;
#pragma unroll
  for (int off = 16; off; off >>= 1) us += __shfl_xor(us, off, 32);
  float un = u / fmaxf(sqrtf(us), 1e-12f);
  float sgn = (r > 0.f) ? 1.f : ((r < 0.f) ? -1.f : 0.f);
  float rn = r + sgn * un * 0.1f;
  float s2 = rn * rn;
#pragma unroll
  for (int off = 16; off; off >>= 1) s2 += __shfl_xor(s2, off, 32);
  float v2 = rn / fmaxf(sqrtf(s2), 1e-12f);
  float pd = v1 * v2;
#pragma unroll
  for (int off = 16; off; off >>= 1) pd += __shfl_xor(pd, off, 32);
  size_t o = (size_t)g * 32 + k;
  n1b[o] = f2bf(v1);
  n2b[o] = f2bf(v2);
  if (k == 0) posdot[g] = pd;
}

// ttl via MFMA (layout verified r7): 6 slices of [4096x4096] = n1.n2^T, K=32.
__global__ __launch_bounds__(256) void k_ttl(const unsigned short* __restrict__ n1b,
                                             const unsigned short* __restrict__ n2b,
                                             float* __restrict__ ttl) {
  int t = threadIdx.x;
  int wv = t >> 6, lane = t & 63;
  int sl = blockIdx.x >> 6;            // 6 slices
  int istripe = blockIdx.x & 63;       // 64 stripes of 64 rows
  int i0 = istripe * 64 + wv * 16;
  const unsigned short* ab = n1b + (size_t)sl * BB * 32;
  const unsigned short* bb = n2b + (size_t)sl * BB * 32;
  int m = lane & 15, quad = lane >> 4;
  bf16x8 afrag = *(const bf16x8*)&ab[(size_t)(i0 + m) * 32 + quad * 8];
  float r0a = 0.f, r1a = 0.f, r2a = 0.f, r3a = 0.f;
  f32x4 z = {0.f, 0.f, 0.f, 0.f};
  for (int jt = 0; jt < 256; jt += 4) {
    bf16x8 b0 = *(const bf16x8*)&bb[((size_t)((jt + 0) * 16 + m)) * 32 + quad * 8];
    bf16x8 b1 = *(const bf16x8*)&bb[((size_t)((jt + 1) * 16 + m)) * 32 + quad * 8];
    bf16x8 b2 = *(const bf16x8*)&bb[((size_t)((jt + 2) * 16 + m)) * 32 + quad * 8];
    bf16x8 b3 = *(const bf16x8*)&bb[((size_t)((jt + 3) * 16 + m)) * 32 + quad * 8];
    f32x4 s0 = __builtin_amdgcn_mfma_f32_16x16x32_bf16(afrag, b0, z, 0, 0, 0);
    f32x4 s1 = __builtin_amdgcn_mfma_f32_16x16x32_bf16(afrag, b1, z, 0, 0, 0);
    f32x4 s2 = __builtin_amdgcn_mfma_f32_16x16x32_bf16(afrag, b2, z, 0, 0, 0);
    f32x4 s3 = __builtin_amdgcn_mfma_f32_16x16x32_bf16(afrag, b3, z, 0, 0, 0);
    r0a += __expf(s0.x * 5.f) + __expf(s1.x * 5.f) + __expf(s2.x * 5.f) + __expf(s3.x * 5.f);
    r1a += __expf(s0.y * 5.f) + __expf(s1.y * 5.f) + __expf(s2.y * 5.f) + __expf(s3.y * 5.f);
    r2a += __expf(s0.z * 5.f) + __expf(s1.z * 5.f) + __expf(s2.z * 5.f) + __expf(s3.z * 5.f);
    r3a += __expf(s0.w * 5.f) + __expf(s1.w * 5.f) + __expf(s2.w * 5.f) + __expf(s3.w * 5.f);
  }
#pragma unroll
  for (int off = 1; off < 16; off <<= 1) {
    r0a += __shfl_xor(r0a, off, 64);
    r1a += __shfl_xor(r1a, off, 64);
    r2a += __shfl_xor(r2a, off, 64);
    r3a += __shfl_xor(r3a, off, 64);
  }
  if (m == 0) {
    int rbase = sl * BB + i0 + quad * 4;
    ttl[rbase + 0] = r0a;
    ttl[rbase + 1] = r1a;
    ttl[rbase + 2] = r2a;
    ttl[rbase + 3] = r3a;
  }
}

__global__ __launch_bounds__(1024) void k_clred(const float* __restrict__ ttl,
                                                const float* __restrict__ posdot,
                                                float* __restrict__ outp) {
  __shared__ float red[1024];
  int t = threadIdx.x;
  float a = 0.f;
  for (int idx = t; idx < 6 * BB; idx += 1024)
    a += logf(ttl[idx]) - posdot[idx] * 5.0f;
  red[t] = a;
  __syncthreads();
  for (int off = 512; off; off >>= 1) {
    if (t < off) red[t] += red[t + off];
    __syncthreads();
  }
  if (t == 0) outp[2 * BB] = red[0] * (1.f / 12288.f);  // (cl_u + cl_i)
}

__global__ __launch_bounds__(256) void k_head(const float* __restrict__ att_u,
                                              const float* __restrict__ att_i,
                                              const float* __restrict__ skills,
                                              const float* __restrict__ w1, const float* __restrict__ b1,
                                              const float* __restrict__ w2, const float* __restrict__ b2,
                                              const float* __restrict__ pw, const float* __restrict__ pb,
                                              float* __restrict__ outp) {
  __shared__ float diag[4][96], t1[4][64];
  int t = threadIdx.x;
  int w = t >> 6, lane = t & 63;
  int b = blockIdx.x * 4 + w;
  for (int j = lane; j < 96; j += 64) {
    float su = 1.f / (1.f + __expf(-att_u[(size_t)b * 96 + j]));
    float si = 1.f / (1.f + __expf(-att_i[(size_t)b * 96 + j]));
    diag[w][j] = (su - si) * skills[(size_t)b * 96 + j];
  }
  __syncthreads();
  float a = b1[lane];
#pragma unroll 8
  for (int j = 0; j < 96; ++j) a += diag[w][j] * w1[j * 64 + lane];
  t1[w][lane] = tanhf(a);
  __syncthreads();
  float h = b2[lane];
#pragma unroll 8
  for (int kk = 0; kk < 64; ++kk) h += t1[w][kk] * w2[kk * 64 + lane];
  float p0 = h * pw[lane * 2 + 0];
  float p1 = h * pw[lane * 2 + 1];
#pragma unroll
  for (int off = 32; off; off >>= 1) {
    p0 += __shfl_xor(p0, off, 64);
    p1 += __shfl_xor(p1, off, 64);
  }
  if (lane == 0) {
    float l0 = p0 + pb[0], l1 = p1 + pb[1];
    float m = fmaxf(l0, l1);
    float e0 = __expf(l0 - m), e1 = __expf(l1 - m);
    float inv = 1.f / (e0 + e1);
    outp[(size_t)b * 2 + 0] = e0 * inv;
    outp[(size_t)b * 2 + 1] = e1 * inv;
  }
}

// ---------------- launcher ----------------
extern "C" void kernel_launch(void* const* d_in, const int* in_sizes, int n_in,
                              void* d_out, int out_size, void* d_ws, size_t ws_size,
                              hipStream_t stream) {
  const float* ego    = (const float*)d_in[0];
  const float* gc_w   = (const float*)d_in[1];
  const float* gc_b   = (const float*)d_in[2];
  const float* bi_w   = (const float*)d_in[3];
  const float* bi_b   = (const float*)d_in[4];
  const float* uh_w   = (const float*)d_in[5];
  const float* uh_b   = (const float*)d_in[6];
  const float* ih_w   = (const float*)d_in[7];
  const float* ih_b   = (const float*)d_in[8];
  const float* ud_w1  = (const float*)d_in[9];
  const float* ud_b1  = (const float*)d_in[10];
  const float* ud_w2  = (const float*)d_in[11];
  const float* ud_b2  = (const float*)d_in[12];
  const float* id_w1  = (const float*)d_in[13];
  const float* id_b1  = (const float*)d_in[14];
  const float* id_w2  = (const float*)d_in[15];
  const float* id_b2  = (const float*)d_in[16];
  const float* q_w    = (const float*)d_in[17];
  const float* q_b    = (const float*)d_in[18];
  const float* k_w    = (const float*)d_in[19];
  const float* k_b    = (const float*)d_in[20];
  const float* v_w    = (const float*)d_in[21];
  const float* v_b    = (const float*)d_in[22];
  const float* dg_w1  = (const float*)d_in[23];
  const float* dg_b1  = (const float*)d_in[24];
  const float* dg_w2  = (const float*)d_in[25];
  const float* dg_b2  = (const float*)d_in[26];
  const float* pr_w   = (const float*)d_in[27];
  const float* pr_b   = (const float*)d_in[28];
  const float* adj_vals = (const float*)d_in[29];
  const float* skills = (const float*)d_in[30];
  const int* user_id  = (const int*)d_in[31];
  const int* item_id  = (const int*)d_in[32];
  const int* adj_rows = (const int*)d_in[33];
  const int* adj_cols = (const int*)d_in[34];
  float* outp = (float*)d_out;

  char* w = (char*)d_ws;
  auto alloc = [&](size_t bytes) -> char* {
    char* p = w;
    w += (bytes + 255) & ~(size_t)255;
    return p;
  };
  float* E1     = (float*)alloc((size_t)NODE_N * DD * 4);
  float* E2     = (float*)alloc((size_t)NODE_N * DD * 4);
  unsigned short* E16    = (unsigned short*)alloc((size_t)NODE_N * DD * 2);
  unsigned short* side16 = (unsigned short*)alloc((size_t)NODE_N * DD * 2);
  unsigned short* p16    = (unsigned short*)alloc((size_t)NODE_N * DD * 2);
  uint2* sedge_r= (uint2*)alloc((size_t)NTILE * NSUB * SCAP * 8);  // 38.4MB, dead after sort
  uint2* sedge  = (uint2*)alloc((size_t)NNZE * 8);   // row-sorted CSR
  int*   cursor = (int*)  alloc((size_t)NTILE * NSUB * 16 * 4);
  int*   out_base = (int*)alloc((size_t)(NTILE + 1) * 4);
  int*   row_start = (int*)alloc((size_t)(NODE_N + 1) * 4);
  float* posdot = (float*)alloc((size_t)6 * BB * 4);
  float* ttl    = (float*)alloc((size_t)6 * BB * 4);

  // late-phase buffers aliased onto sedge_r (dead after k_sort_t)
  char* ap = (char*)sedge_r;
  auto alias = [&](size_t bytes) -> char* {
    char* p = ap;
    ap += (bytes + 255) & ~(size_t)255;
    return p;
  };
  float* ue     = (float*)alias((size_t)BB * 64 * 4);
  float* ie     = (float*)alias((size_t)BB * 64 * 4);
  float* recs_u = (float*)alias((size_t)NLV * BB * 32 * 4);
  float* recs_i = (float*)alias((size_t)NLV * BB * 32 * 4);
  float* att_u  = (float*)alias((size_t)BB * 96 * 4);
  float* att_i  = (float*)alias((size_t)BB * 96 * 4);
  unsigned short* n1b = (unsigned short*)alias((size_t)6 * BB * 32 * 2);
  unsigned short* n2b = (unsigned short*)alias((size_t)6 * BB * 32 * 2);

  // host-side: kc = jax.random.split(jax.random.key(42), 2)
  uint32_t a0 = 0, a1 = 2, b0 = 1, b1 = 3;
  tf_block(0u, 42u, a0, a1);
  tf_block(0u, 42u, b0, b1);
  uint32_t ku0 = a0, ku1 = b0;   // kc[0] -> u side
  uint32_t ki0 = a1, ki1 = b1;   // kc[1] -> i side

  hipMemsetAsync(cursor, 0, (size_t)NTILE * NSUB * 16 * 4, stream);

  k_init<<<9375, 256, 0, stream>>>(ego, E16);
  k_scatter_t<<<(NNZE + EPB - 1) / EPB, 256, 0, stream>>>(adj_rows, adj_cols, adj_vals,
                                                          cursor, sedge_r);
  k_scan586<<<1, 1024, 0, stream>>>(cursor, out_base, row_start);
  k_sort_t<<<NTILE, 256, 0, stream>>>(sedge_r, cursor, out_base, sedge, row_start);

  const float* Eprev = ego;
  float* Ebufs[2] = {E1, E2};
  for (int l = 0; l < 2; ++l) {
    k_spmm<<<37500, 256, 0, stream>>>(E16, sedge, row_start, Eprev, side16, p16);
    k_transform<<<1172, 256, 0, stream>>>(gc_w + l * 4096, gc_b + l * 64,
                                          bi_w + l * 4096, bi_b + l * 64,
                                          side16, p16, Ebufs[l], E16);
    Eprev = Ebufs[l];
  }

  k_gather<<<4096, 128, 0, stream>>>(ego, E1, E2, user_id, item_id, ue, ie);

  dim3 ge(4096, 3);
  k_encoder<<<ge, 256, 0, stream>>>(ue, uh_w, uh_b, ud_w1, ud_b1, ud_w2, ud_b2, recs_u);
  k_encoder<<<ge, 256, 0, stream>>>(ie, ih_w, ih_b, id_w1, id_b1, id_w2, id_b2, recs_i);

  k_attn<<<512, 256, 0, stream>>>(recs_u, q_w, q_b, k_w, k_b, v_w, v_b, att_u);
  k_attn<<<512, 256, 0, stream>>>(recs_i, q_w, q_b, k_w, k_b, v_w, v_b, att_i);

  k_noise<<<3072, 256, 0, stream>>>(att_u, att_i, ku0, ku1, ki0, ki1, n1b, n2b, posdot);

  k_ttl<<<384, 256, 0, stream>>>(n1b, n2b, ttl);
  k_clred<<<1, 1024, 0, stream>>>(ttl, posdot, outp);

  k_head<<<1024, 256, 0, stream>>>(att_u, att_i, skills, dg_w1, dg_b1, dg_w2, dg_b2,
                                   pr_w, pr_b, outp);
}

// Round 12
// 691.878 us; speedup vs baseline: 4.3556x; 1.0155x over previous
//
#include <hip/hip_runtime.h>
#include <stdint.h>
#include <math.h>

#define USER_N 100000
#define NODE_N 150000
#define DD 64
#define NNZE 2400000
#define BB 4096
#define NLV 3
#define LF 32
#define HALF_SZ 196608u  /* (3*4096*32)/2 */
#define NTILE 586        /* ceil(150000/256) */
#define NSUB 8           /* per-tile sub-segments, one per physical XCD */
#define SCAP 1024        /* capacity per (tile,xcd) segment; mean 512 */
#define EPB 4096         /* edges per scatter block */

typedef __attribute__((ext_vector_type(8))) short bf16x8;
typedef __attribute__((ext_vector_type(4))) float f32x4;
typedef __attribute__((ext_vector_type(2))) float f32x2;

// HW_REG_XCC_ID: id=20, offset=0, width=32 -> imm = 20 | (31<<11)
#define XCC_ID_IMM 63508

// ---------------- threefry2x32 (JAX original mode) ----------------
__host__ __device__ inline void tf_block(uint32_t k0, uint32_t k1, uint32_t& x0, uint32_t& x1) {
  uint32_t ks[3] = {k0, k1, k0 ^ k1 ^ 0x1BD11BDAu};
  x0 += ks[0]; x1 += ks[1];
  const int R0[4] = {13, 15, 26, 6};
  const int R1[4] = {17, 29, 16, 24};
#pragma unroll
  for (int i = 0; i < 5; ++i) {
    const int* R = (i & 1) ? R1 : R0;
#pragma unroll
    for (int j = 0; j < 4; ++j) {
      x0 += x1;
      x1 = (x1 << R[j]) | (x1 >> (32 - R[j]));
      x1 ^= x0;
    }
    x0 += ks[(i + 1) % 3];
    x1 += ks[(i + 2) % 3] + (uint32_t)(i + 1);
  }
}

__device__ inline float tf_uniform(uint32_t ka, uint32_t kb, uint32_t m) {
  uint32_t x0, x1;
  bool first = m < HALF_SZ;
  if (first) { x0 = m; x1 = m + HALF_SZ; } else { x0 = m - HALF_SZ; x1 = m; }
  tf_block(ka, kb, x0, x1);
  uint32_t bits = first ? x0 : x1;
  return __uint_as_float((bits >> 9) | 0x3f800000u) - 1.0f;
}

// bf16 round-to-nearest-even
__device__ inline unsigned short f2bf(float x) {
  uint32_t b = __float_as_uint(x);
  return (unsigned short)((b + 0x7FFFu + ((b >> 16) & 1u)) >> 16);
}

// fp8 e4m3 (HW cvt, OCP on gfx950): one byte from a float
__device__ inline unsigned char f2fp8(float x) {
  return (unsigned char)(__builtin_amdgcn_cvt_pk_fp8_f32(x, x, 0, false) & 0xFF);
}

// decode 4 packed e4m3 bytes -> 4 floats, then acc += v * row4
__device__ inline void fp8_fma(float4& acc, uint2 rec, uint32_t wrd) {
  float vv = __uint_as_float(rec.y);
  f32x2 lo = __builtin_amdgcn_cvt_pk_f32_fp8((int)wrd, false);
  f32x2 hi = __builtin_amdgcn_cvt_pk_f32_fp8((int)wrd, true);
  acc.x = fmaf(vv, lo.x, acc.x);
  acc.y = fmaf(vv, lo.y, acc.y);
  acc.z = fmaf(vv, hi.x, acc.z);
  acc.w = fmaf(vv, hi.y, acc.w);
}

// ---------------- kernels ----------------
// init: fp8 mirror of ego for the spmm gathers (4 dims -> 1 uint per thread)
__global__ __launch_bounds__(256) void k_init(const float* __restrict__ ego,
                                              uint32_t* __restrict__ E8) {
  int i = blockIdx.x * 256 + threadIdx.x;  // float4 index
  float4 v = ((const float4*)ego)[i];
  int w01 = __builtin_amdgcn_cvt_pk_fp8_f32(v.x, v.y, 0, false);
  int w = __builtin_amdgcn_cvt_pk_fp8_f32(v.z, v.w, w01, true);
  E8[i] = (uint32_t)w;
}

// Block-aggregated scatter (r10): LDS histogram over 586 tiles -> ONE global
// atomic per (tile, block) reserving a contiguous range in this XCD's segment.
__global__ __launch_bounds__(256) void k_scatter_t(const int* __restrict__ rows,
                                                   const int* __restrict__ cols,
                                                   const float* __restrict__ vals,
                                                   int* __restrict__ cursor,
                                                   uint2* __restrict__ sedge_r) {
  __shared__ int cnt[NTILE];
  __shared__ int curs[NTILE];
  int t = threadIdx.x;
  for (int i = t; i < NTILE; i += 256) cnt[i] = 0;
  __syncthreads();
  int r[16];
  int ebase = blockIdx.x * EPB;
#pragma unroll
  for (int j = 0; j < 16; ++j) {
    int e = ebase + j * 256 + t;
    r[j] = (e < NNZE) ? rows[e] : -1;
    if (r[j] >= 0) atomicAdd(&cnt[r[j] >> 8], 1);
  }
  __syncthreads();
  unsigned myx = __builtin_amdgcn_s_getreg(XCC_ID_IMM) & (NSUB - 1);
  for (int i = t; i < NTILE; i += 256) {
    int c = cnt[i];
    curs[i] = c ? atomicAdd(&cursor[(i * NSUB + (int)myx) * 16], c) : 0;
  }
  __syncthreads();
#pragma unroll
  for (int j = 0; j < 16; ++j) {
    if (r[j] < 0) continue;
    int e = ebase + j * 256 + t;
    int tile = r[j] >> 8;
    uint2 rec = make_uint2((uint32_t)cols[e] | ((uint32_t)(r[j] & 255) << 18),
                           __float_as_uint(vals[e]));
    int p = atomicAdd(&curs[tile], 1);
    if (p < SCAP) {
      sedge_r[(size_t)(tile * NSUB + (int)myx) * SCAP + p] = rec;
    } else {
#pragma unroll 1
      for (int att = 1; att < NSUB; ++att) {
        int seg = tile * NSUB + (int)((myx + att) & (NSUB - 1));
        int p2 = atomicAdd(&cursor[seg * 16], 1);
        if (p2 < SCAP) { sedge_r[(size_t)seg * SCAP + p2] = rec; break; }
      }
    }
  }
}

// tiny scan over 586 tile totals (from cursors) -> out_base for sorted CSR
__global__ __launch_bounds__(1024) void k_scan586(const int* __restrict__ cursor,
                                                  int* __restrict__ out_base,
                                                  int* __restrict__ row_start) {
  __shared__ int buf[1024];
  int t = threadIdx.x;
  int tot = 0;
  if (t < NTILE) {
#pragma unroll
    for (int x = 0; x < NSUB; ++x) {
      int c = cursor[(t * NSUB + x) * 16];
      tot += (c < SCAP) ? c : SCAP;
    }
  }
  buf[t] = tot;
  __syncthreads();
  for (int off = 1; off < 1024; off <<= 1) {
    int add = (t >= off) ? buf[t - off] : 0;
    __syncthreads();
    buf[t] += add;
    __syncthreads();
  }
  if (t < NTILE) out_base[t] = buf[t] - tot;  // exclusive
  if (t == 0) row_start[NODE_N] = NNZE;
}

// per-tile 256-bin counting sort: drains the 8 sub-segments -> row-sorted CSR.
__global__ __launch_bounds__(256) void k_sort_t(const uint2* __restrict__ sedge_r,
                                                const int* __restrict__ cursor,
                                                const int* __restrict__ out_base,
                                                uint2* __restrict__ sedge,
                                                int* __restrict__ row_start) {
  __shared__ int hist[256], buf[256], curs[256];
  int t = threadIdx.x;
  int tile = blockIdx.x;
  int obase = out_base[tile];
  hist[t] = 0;
  __syncthreads();
#pragma unroll 1
  for (int x = 0; x < NSUB; ++x) {
    int seg = tile * NSUB + x;
    int cnt = cursor[seg * 16];
    if (cnt > SCAP) cnt = SCAP;
    const uint2* sp = sedge_r + (size_t)seg * SCAP;
    for (int i = t; i < cnt; i += 256)
      atomicAdd(&hist[sp[i].x >> 18], 1);
  }
  __syncthreads();
  int v = hist[t];
  buf[t] = v;
  __syncthreads();
  for (int off = 1; off < 256; off <<= 1) {
    int add = (t >= off) ? buf[t - off] : 0;
    __syncthreads();
    buf[t] += add;
    __syncthreads();
  }
  int excl = buf[t] - v;
  curs[t] = excl;
  int row = tile * 256 + t;
  if (row < NODE_N) row_start[row] = obase + excl;
  __syncthreads();
#pragma unroll 1
  for (int x = 0; x < NSUB; ++x) {
    int seg = tile * NSUB + x;
    int cnt = cursor[seg * 16];
    if (cnt > SCAP) cnt = SCAP;
    const uint2* sp = sedge_r + (size_t)seg * SCAP;
    for (int i = t; i < cnt; i += 256) {
      uint2 rec = sp[i];
      int rl = rec.x >> 18;
      int p = atomicAdd(&curs[rl], 1);
      sedge[obase + p] = make_uint2(rec.x & 0x3FFFFu, rec.y);
    }
  }
}

// wave-per-row SpMM over sorted CSR, fp8 E gathers (64B/row — half of r10's
// bf16; the 160MB FETCH was gather fills at a ~2.4TB/s random-access ceiling).
// Epilogue reads its OWN fp8 row (64B) instead of Eprev fp32 (256B, -38.4MB).
__global__ __launch_bounds__(256) void k_spmm(const uint32_t* __restrict__ E8,
                                              const uint2* __restrict__ sedge,
                                              const int* __restrict__ row_start,
                                              unsigned short* __restrict__ side16,
                                              unsigned short* __restrict__ p16) {
  int r = blockIdx.x * 4 + (threadIdx.x >> 6);
  int lane = threadIdx.x & 63;
  int g = lane >> 4;
  int q = lane & 15;
  int rs = row_start[r], re = row_start[r + 1];
  float4 acc = make_float4(0.f, 0.f, 0.f, 0.f);
  int e = rs;
  for (; e + 16 <= re; e += 16) {
    uint2 e0 = sedge[e + g];
    uint2 e1 = sedge[e + 4 + g];
    uint2 e2 = sedge[e + 8 + g];
    uint2 e3 = sedge[e + 12 + g];
    uint32_t a0 = E8[(size_t)e0.x * 16 + q];
    uint32_t a1 = E8[(size_t)e1.x * 16 + q];
    uint32_t a2 = E8[(size_t)e2.x * 16 + q];
    uint32_t a3 = E8[(size_t)e3.x * 16 + q];
    fp8_fma(acc, e0, a0);
    fp8_fma(acc, e1, a1);
    fp8_fma(acc, e2, a2);
    fp8_fma(acc, e3, a3);
  }
  for (; e + 8 <= re; e += 8) {
    uint2 e0 = sedge[e + g];
    uint2 e1 = sedge[e + 4 + g];
    uint32_t a0 = E8[(size_t)e0.x * 16 + q];
    uint32_t a1 = E8[(size_t)e1.x * 16 + q];
    fp8_fma(acc, e0, a0);
    fp8_fma(acc, e1, a1);
  }
  for (; e + 4 <= re; e += 4) {
    uint2 e0 = sedge[e + g];
    uint32_t a0 = E8[(size_t)e0.x * 16 + q];
    fp8_fma(acc, e0, a0);
  }
  for (; e < re; ++e) {
    if (g == (e & 3)) {
      uint2 e0 = sedge[e];
      uint32_t a0 = E8[(size_t)e0.x * 16 + q];
      fp8_fma(acc, e0, a0);
    }
  }
#pragma unroll
  for (int off = 16; off <= 32; off <<= 1) {
    acc.x += __shfl_xor(acc.x, off, 64);
    acc.y += __shfl_xor(acc.y, off, 64);
    acc.z += __shfl_xor(acc.z, off, 64);
    acc.w += __shfl_xor(acc.w, off, 64);
  }
  if (g == 0) {
    uint32_t ew = E8[(size_t)r * 16 + q];
    f32x2 elo = __builtin_amdgcn_cvt_pk_f32_fp8((int)ew, false);
    f32x2 ehi = __builtin_amdgcn_cvt_pk_f32_fp8((int)ew, true);
    ushort4 s16, pp;
    s16.x = f2bf(acc.x); s16.y = f2bf(acc.y); s16.z = f2bf(acc.z); s16.w = f2bf(acc.w);
    pp.x = f2bf(acc.x * elo.x); pp.y = f2bf(acc.y * elo.y);
    pp.z = f2bf(acc.z * ehi.x); pp.w = f2bf(acc.w * ehi.y);
    *(ushort4*)&side16[(size_t)r * DD + q * 4] = s16;
    *(ushort4*)&p16[(size_t)r * DD + q * 4] = pp;
  }
}

// MFMA transform (layouts verified r7/r8): E_out = l2norm(leaky(side@gw+gb)
// + leaky((E.side)@bw+bb)). Writes fp32 Eout (for gather-sum) + fp8 E8 mirror.
__global__ __launch_bounds__(256) void k_transform(const float* __restrict__ gw,
                                                   const float* __restrict__ gb,
                                                   const float* __restrict__ bw,
                                                   const float* __restrict__ bb,
                                                   const unsigned short* __restrict__ side16,
                                                   const unsigned short* __restrict__ p16,
                                                   float* __restrict__ Eout,
                                                   unsigned char* __restrict__ E8b) {
  int t = threadIdx.x;
  int wv = t >> 6, lane = t & 63;
  int n = lane & 15, quad = lane >> 4;
  bf16x8 wg[4][2], wb[4][2];
  float gbl[4], bbl[4];
#pragma unroll
  for (int c = 0; c < 4; ++c) {
    gbl[c] = gb[c * 16 + n];
    bbl[c] = bb[c * 16 + n];
#pragma unroll
    for (int h = 0; h < 2; ++h) {
#pragma unroll
      for (int j = 0; j < 8; ++j) {
        int k = h * 32 + quad * 8 + j;
        wg[c][h][j] = (short)f2bf(gw[k * 64 + c * 16 + n]);
        wb[c][h][j] = (short)f2bf(bw[k * 64 + c * 16 + n]);
      }
    }
  }
  const f32x4 z = {0.f, 0.f, 0.f, 0.f};
  for (int tile = blockIdx.x * 4 + wv; tile < NODE_N / 16; tile += gridDim.x * 4) {
    int i0 = tile * 16;
    bf16x8 as0 = *(const bf16x8*)&side16[(size_t)(i0 + n) * DD + quad * 8];
    bf16x8 as1 = *(const bf16x8*)&side16[(size_t)(i0 + n) * DD + 32 + quad * 8];
    bf16x8 ap0 = *(const bf16x8*)&p16[(size_t)(i0 + n) * DD + quad * 8];
    bf16x8 ap1 = *(const bf16x8*)&p16[(size_t)(i0 + n) * DD + 32 + quad * 8];
    float v[4][4];
    float sq0 = 0.f, sq1 = 0.f, sq2 = 0.f, sq3 = 0.f;
#pragma unroll
    for (int c = 0; c < 4; ++c) {
      f32x4 ag = __builtin_amdgcn_mfma_f32_16x16x32_bf16(as0, wg[c][0], z, 0, 0, 0);
      ag = __builtin_amdgcn_mfma_f32_16x16x32_bf16(as1, wg[c][1], ag, 0, 0, 0);
      f32x4 ab = __builtin_amdgcn_mfma_f32_16x16x32_bf16(ap0, wb[c][0], z, 0, 0, 0);
      ab = __builtin_amdgcn_mfma_f32_16x16x32_bf16(ap1, wb[c][1], ab, 0, 0, 0);
#pragma unroll
      for (int r = 0; r < 4; ++r) {
        float a1 = ag[r] + gbl[c];
        a1 = (a1 > 0.f) ? a1 : 0.01f * a1;
        float a2 = ab[r] + bbl[c];
        a2 = (a2 > 0.f) ? a2 : 0.01f * a2;
        float vv = a1 + a2;
        v[c][r] = vv;
        if (r == 0) sq0 += vv * vv;
        else if (r == 1) sq1 += vv * vv;
        else if (r == 2) sq2 += vv * vv;
        else sq3 += vv * vv;
      }
    }
#pragma unroll
    for (int off = 1; off < 16; off <<= 1) {
      sq0 += __shfl_xor(sq0, off, 64);
      sq1 += __shfl_xor(sq1, off, 64);
      sq2 += __shfl_xor(sq2, off, 64);
      sq3 += __shfl_xor(sq3, off, 64);
    }
    float inv0 = 1.f / fmaxf(sqrtf(sq0), 1e-12f);
    float inv1 = 1.f / fmaxf(sqrtf(sq1), 1e-12f);
    float inv2 = 1.f / fmaxf(sqrtf(sq2), 1e-12f);
    float inv3 = 1.f / fmaxf(sqrtf(sq3), 1e-12f);
#pragma unroll
    for (int c = 0; c < 4; ++c) {
      float vn0 = v[c][0] * inv0;
      float vn1 = v[c][1] * inv1;
      float vn2 = v[c][2] * inv2;
      float vn3 = v[c][3] * inv3;
      size_t o0 = (size_t)(i0 + quad * 4 + 0) * DD + c * 16 + n;
      size_t o1 = o0 + DD, o2 = o1 + DD, o3 = o2 + DD;
      Eout[o0] = vn0; Eout[o1] = vn1; Eout[o2] = vn2; Eout[o3] = vn3;
      E8b[o0] = f2fp8(vn0); E8b[o1] = f2fp8(vn1);
      E8b[o2] = f2fp8(vn2); E8b[o3] = f2fp8(vn3);
    }
  }
}

// gather: Esum = ego + E1 + E2 on just the 8192 batch rows.
__global__ __launch_bounds__(128) void k_gather(const float* __restrict__ ego,
                                                const float* __restrict__ E1,
                                                const float* __restrict__ E2,
                                                const int* __restrict__ uid,
                                                const int* __restrict__ iid,
                                                float* __restrict__ ue, float* __restrict__ ie) {
  int b = blockIdx.x, t = threadIdx.x;
  if (t < 64) {
    size_t o = (size_t)uid[b] * 64 + t;
    ue[(size_t)b * 64 + t] = ego[o] + E1[o] + E2[o];
  } else {
    int d = t - 64;
    size_t o = (size_t)(USER_N + iid[b]) * 64 + d;
    ie[(size_t)b * 64 + d] = ego[o] + E1[o] + E2[o];
  }
}

__global__ __launch_bounds__(256) void k_encoder(const float* __restrict__ xin,
                                                 const float* __restrict__ hw, const float* __restrict__ hb,
                                                 const float* __restrict__ w1, const float* __restrict__ b1,
                                                 const float* __restrict__ w2, const float* __restrict__ b2,
                                                 float* __restrict__ recs) {
  __shared__ float sx[64], sreps[64], st[256];
  int b = blockIdx.x, l = blockIdx.y, t = threadIdx.x;
  if (t < 64) sx[t] = xin[(size_t)b * 64 + t];
  __syncthreads();
  if (t < 64) {
    const float* W = hw + l * 64 * 64;
    float a = hb[l * 64 + t];
#pragma unroll 8
    for (int k = 0; k < 64; ++k) a += sx[k] * W[k * 64 + t];
    sreps[t] = tanhf(a);
  }
  __syncthreads();
  {
    const float* W = w1 + l * 64 * 256;
    float a = b1[l * 256 + t];
#pragma unroll 8
    for (int k = 0; k < 64; ++k) a += sreps[k] * W[k * 256 + t];
    st[t] = tanhf(a);
  }
  __syncthreads();
  if (t < 32) {
    const float* W = w2 + l * 256 * 32;
    float a = b2[l * 32 + t];
#pragma unroll 8
    for (int k = 0; k < 256; ++k) a += st[k] * W[k * 32 + t];
    recs[((size_t)l * BB + b) * 32 + t] = a;
  }
}

__global__ __launch_bounds__(256) void k_attn(const float* __restrict__ recs,
                                              const float* __restrict__ qw, const float* __restrict__ qb,
                                              const float* __restrict__ kw, const float* __restrict__ kb,
                                              const float* __restrict__ vw, const float* __restrict__ vb,
                                              float* __restrict__ att) {
  int t = threadIdx.x;
  int b = blockIdx.x * 8 + (t >> 5);
  int d = t & 31;
  float x0 = recs[((size_t)0 * BB + b) * 32 + d];
  float x1 = recs[((size_t)1 * BB + b) * 32 + d];
  float x2 = recs[((size_t)2 * BB + b) * 32 + d];
  float q0 = qb[d], q1 = q0, q2 = q0;
  float c0 = kb[d], c1 = c0, c2 = c0;
  float v0 = vb[d], v1 = v0, v2 = v0;
#pragma unroll 4
  for (int kk = 0; kk < 32; ++kk) {
    float xa = __shfl(x0, kk, 32);
    float xb = __shfl(x1, kk, 32);
    float xc = __shfl(x2, kk, 32);
    float wq = qw[kk * 32 + d], wk = kw[kk * 32 + d], wv = vw[kk * 32 + d];
    q0 += xa * wq; q1 += xb * wq; q2 += xc * wq;
    c0 += xa * wk; c1 += xb * wk; c2 += xc * wk;
    v0 += xa * wv; v1 += xb * wv; v2 += xc * wv;
  }
  float qs[3] = {q0, q1, q2}, ks[3] = {c0, c1, c2}, vs[3] = {v0, v1, v2};
  float sc[3][3];
#pragma unroll
  for (int s = 0; s < 3; ++s)
#pragma unroll
    for (int u = 0; u < 3; ++u) {
      float p = qs[s] * ks[u];
#pragma unroll
      for (int off = 16; off; off >>= 1) p += __shfl_xor(p, off, 32);
      sc[s][u] = p * 0.17677669529663687f;  // 1/sqrt(32)
    }
#pragma unroll
  for (int s = 0; s < 3; ++s) {
    float m = fmaxf(sc[s][0], fmaxf(sc[s][1], sc[s][2]));
    float e0 = __expf(sc[s][0] - m), e1 = __expf(sc[s][1] - m), e2 = __expf(sc[s][2] - m);
    float inv = 1.f / (e0 + e1 + e2);
    att[(size_t)b * 96 + s * 32 + d] = (e0 * vs[0] + e1 * vs[1] + e2 * vs[2]) * inv;
  }
}

// noise: emits l2-normalized recs (n1) and perturbed recs (n2) directly as bf16
// for the MFMA ttl kernel; posdot stays fp32-exact.
__global__ __launch_bounds__(256) void k_noise(const float* __restrict__ att_u,
                                               const float* __restrict__ att_i,
                                               uint32_t ku0, uint32_t ku1, uint32_t ki0, uint32_t ki1,
                                               unsigned short* __restrict__ n1b,
                                               unsigned short* __restrict__ n2b,
                                               float* __restrict__ posdot) {
  int t = threadIdx.x;
  int g = blockIdx.x * 8 + (t >> 5);   // [0, 24576)
  int k = t & 31;
  int side = g / (NLV * BB);
  int rem = g - side * (NLV * BB);
  int l = rem >> 12;
  int b = rem & 4095;
  const float* att = side ? att_i : att_u;
  uint32_t ka = side ? ki0 : ku0;
  uint32_t kb = side ? ki1 : ku1;
  float r = att[(size_t)b * 96 + l * 32 + k];
  float ss = r * r;
#pragma unroll
  for (int off = 16; off; off >>= 1) ss += __shfl_xor(ss, off, 32);
  float v1 = r / fmaxf(sqrtf(ss), 1e-12f);
  uint32_t m = ((uint32_t)(l * BB + b)) * 32u + (uint32_t)k;
  float u = tf_uniform(ka, kb, m);
  float us = u * u;
#pragma unroll
  for (int off = 16; off; off >>= 1) us += __shfl_xor(us, off, 32);
  float un = u / fmaxf(sqrtf(us), 1e-12f);
  float sgn = (r > 0.f) ? 1.f : ((r < 0.f) ? -1.f : 0.f);
  float rn = r + sgn * un * 0.1f;
  float s2 = rn * rn;
#pragma unroll
  for (int off = 16; off; off >>= 1) s2 += __shfl_xor(s2, off, 32);
  float v2 = rn / fmaxf(sqrtf(s2), 1e-12f);
  float pd = v1 * v2;
#pragma unroll
  for (int off = 16; off; off >>= 1) pd += __shfl_xor(pd, off, 32);
  size_t o = (size_t)g * 32 + k;
  n1b[o] = f2bf(v1);
  n2b[o] = f2bf(v2);
  if (k == 0) posdot[g] = pd;
}

// ttl via MFMA (layout verified r7): 6 slices of [4096x4096] = n1.n2^T, K=32.
__global__ __launch_bounds__(256) void k_ttl(const unsigned short* __restrict__ n1b,
                                             const unsigned short* __restrict__ n2b,
                                             float* __restrict__ ttl) {
  int t = threadIdx.x;
  int wv = t >> 6, lane = t & 63;
  int sl = blockIdx.x >> 6;            // 6 slices
  int istripe = blockIdx.x & 63;       // 64 stripes of 64 rows
  int i0 = istripe * 64 + wv * 16;
  const unsigned short* ab = n1b + (size_t)sl * BB * 32;
  const unsigned short* bb = n2b + (size_t)sl * BB * 32;
  int m = lane & 15, quad = lane >> 4;
  bf16x8 afrag = *(const bf16x8*)&ab[(size_t)(i0 + m) * 32 + quad * 8];
  float r0a = 0.f, r1a = 0.f, r2a = 0.f, r3a = 0.f;
  f32x4 z = {0.f, 0.f, 0.f, 0.f};
  for (int jt = 0; jt < 256; jt += 4) {
    bf16x8 b0 = *(const bf16x8*)&bb[((size_t)((jt + 0) * 16 + m)) * 32 + quad * 8];
    bf16x8 b1 = *(const bf16x8*)&bb[((size_t)((jt + 1) * 16 + m)) * 32 + quad * 8];
    bf16x8 b2 = *(const bf16x8*)&bb[((size_t)((jt + 2) * 16 + m)) * 32 + quad * 8];
    bf16x8 b3 = *(const bf16x8*)&bb[((size_t)((jt + 3) * 16 + m)) * 32 + quad * 8];
    f32x4 s0 = __builtin_amdgcn_mfma_f32_16x16x32_bf16(afrag, b0, z, 0, 0, 0);
    f32x4 s1 = __builtin_amdgcn_mfma_f32_16x16x32_bf16(afrag, b1, z, 0, 0, 0);
    f32x4 s2 = __builtin_amdgcn_mfma_f32_16x16x32_bf16(afrag, b2, z, 0, 0, 0);
    f32x4 s3 = __builtin_amdgcn_mfma_f32_16x16x32_bf16(afrag, b3, z, 0, 0, 0);
    r0a += __expf(s0.x * 5.f) + __expf(s1.x * 5.f) + __expf(s2.x * 5.f) + __expf(s3.x * 5.f);
    r1a += __expf(s0.y * 5.f) + __expf(s1.y * 5.f) + __expf(s2.y * 5.f) + __expf(s3.y * 5.f);
    r2a += __expf(s0.z * 5.f) + __expf(s1.z * 5.f) + __expf(s2.z * 5.f) + __expf(s3.z * 5.f);
    r3a += __expf(s0.w * 5.f) + __expf(s1.w * 5.f) + __expf(s2.w * 5.f) + __expf(s3.w * 5.f);
  }
#pragma unroll
  for (int off = 1; off < 16; off <<= 1) {
    r0a += __shfl_xor(r0a, off, 64);
    r1a += __shfl_xor(r1a, off, 64);
    r2a += __shfl_xor(r2a, off, 64);
    r3a += __shfl_xor(r3a, off, 64);
  }
  if (m == 0) {
    int rbase = sl * BB + i0 + quad * 4;
    ttl[rbase + 0] = r0a;
    ttl[rbase + 1] = r1a;
    ttl[rbase + 2] = r2a;
    ttl[rbase + 3] = r3a;
  }
}

__global__ __launch_bounds__(1024) void k_clred(const float* __restrict__ ttl,
                                                const float* __restrict__ posdot,
                                                float* __restrict__ outp) {
  __shared__ float red[1024];
  int t = threadIdx.x;
  float a = 0.f;
  for (int idx = t; idx < 6 * BB; idx += 1024)
    a += logf(ttl[idx]) - posdot[idx] * 5.0f;
  red[t] = a;
  __syncthreads();
  for (int off = 512; off; off >>= 1) {
    if (t < off) red[t] += red[t + off];
    __syncthreads();
  }
  if (t == 0) outp[2 * BB] = red[0] * (1.f / 12288.f);  // (cl_u + cl_i)
}

__global__ __launch_bounds__(256) void k_head(const float* __restrict__ att_u,
                                              const float* __restrict__ att_i,
                                              const float* __restrict__ skills,
                                              const float* __restrict__ w1, const float* __restrict__ b1,
                                              const float* __restrict__ w2, const float* __restrict__ b2,
                                              const float* __restrict__ pw, const float* __restrict__ pb,
                                              float* __restrict__ outp) {
  __shared__ float diag[4][96], t1[4][64];
  int t = threadIdx.x;
  int w = t >> 6, lane = t & 63;
  int b = blockIdx.x * 4 + w;
  for (int j = lane; j < 96; j += 64) {
    float su = 1.f / (1.f + __expf(-att_u[(size_t)b * 96 + j]));
    float si = 1.f / (1.f + __expf(-att_i[(size_t)b * 96 + j]));
    diag[w][j] = (su - si) * skills[(size_t)b * 96 + j];
  }
  __syncthreads();
  float a = b1[lane];
#pragma unroll 8
  for (int j = 0; j < 96; ++j) a += diag[w][j] * w1[j * 64 + lane];
  t1[w][lane] = tanhf(a);
  __syncthreads();
  float h = b2[lane];
#pragma unroll 8
  for (int kk = 0; kk < 64; ++kk) h += t1[w][kk] * w2[kk * 64 + lane];
  float p0 = h * pw[lane * 2 + 0];
  float p1 = h * pw[lane * 2 + 1];
#pragma unroll
  for (int off = 32; off; off >>= 1) {
    p0 += __shfl_xor(p0, off, 64);
    p1 += __shfl_xor(p1, off, 64);
  }
  if (lane == 0) {
    float l0 = p0 + pb[0], l1 = p1 + pb[1];
    float m = fmaxf(l0, l1);
    float e0 = __expf(l0 - m), e1 = __expf(l1 - m);
    float inv = 1.f / (e0 + e1);
    outp[(size_t)b * 2 + 0] = e0 * inv;
    outp[(size_t)b * 2 + 1] = e1 * inv;
  }
}

// ---------------- launcher ----------------
extern "C" void kernel_launch(void* const* d_in, const int* in_sizes, int n_in,
                              void* d_out, int out_size, void* d_ws, size_t ws_size,
                              hipStream_t stream) {
  const float* ego    = (const float*)d_in[0];
  const float* gc_w   = (const float*)d_in[1];
  const float* gc_b   = (const float*)d_in[2];
  const float* bi_w   = (const float*)d_in[3];
  const float* bi_b   = (const float*)d_in[4];
  const float* uh_w   = (const float*)d_in[5];
  const float* uh_b   = (const float*)d_in[6];
  const float* ih_w   = (const float*)d_in[7];
  const float* ih_b   = (const float*)d_in[8];
  const float* ud_w1  = (const float*)d_in[9];
  const float* ud_b1  = (const float*)d_in[10];
  const float* ud_w2  = (const float*)d_in[11];
  const float* ud_b2  = (const float*)d_in[12];
  const float* id_w1  = (const float*)d_in[13];
  const float* id_b1  = (const float*)d_in[14];
  const float* id_w2  = (const float*)d_in[15];
  const float* id_b2  = (const float*)d_in[16];
  const float* q_w    = (const float*)d_in[17];
  const float* q_b    = (const float*)d_in[18];
  const float* k_w    = (const float*)d_in[19];
  const float* k_b    = (const float*)d_in[20];
  const float* v_w    = (const float*)d_in[21];
  const float* v_b    = (const float*)d_in[22];
  const float* dg_w1  = (const float*)d_in[23];
  const float* dg_b1  = (const float*)d_in[24];
  const float* dg_w2  = (const float*)d_in[25];
  const float* dg_b2  = (const float*)d_in[26];
  const float* pr_w   = (const float*)d_in[27];
  const float* pr_b   = (const float*)d_in[28];
  const float* adj_vals = (const float*)d_in[29];
  const float* skills = (const float*)d_in[30];
  const int* user_id  = (const int*)d_in[31];
  const int* item_id  = (const int*)d_in[32];
  const int* adj_rows = (const int*)d_in[33];
  const int* adj_cols = (const int*)d_in[34];
  float* outp = (float*)d_out;

  char* w = (char*)d_ws;
  auto alloc = [&](size_t bytes) -> char* {
    char* p = w;
    w += (bytes + 255) & ~(size_t)255;
    return p;
  };
  float* E1     = (float*)alloc((size_t)NODE_N * DD * 4);
  float* E2     = (float*)alloc((size_t)NODE_N * DD * 4);
  uint32_t* E8  = (uint32_t*)alloc((size_t)NODE_N * DD);   // fp8 mirror, 9.6MB
  unsigned short* side16 = (unsigned short*)alloc((size_t)NODE_N * DD * 2);
  unsigned short* p16    = (unsigned short*)alloc((size_t)NODE_N * DD * 2);
  uint2* sedge_r= (uint2*)alloc((size_t)NTILE * NSUB * SCAP * 8);  // dead after sort
  uint2* sedge  = (uint2*)alloc((size_t)NNZE * 8);   // row-sorted CSR
  int*   cursor = (int*)  alloc((size_t)NTILE * NSUB * 16 * 4);
  int*   out_base = (int*)alloc((size_t)(NTILE + 1) * 4);
  int*   row_start = (int*)alloc((size_t)(NODE_N + 1) * 4);
  float* posdot = (float*)alloc((size_t)6 * BB * 4);
  float* ttl    = (float*)alloc((size_t)6 * BB * 4);

  // late-phase buffers aliased onto sedge_r (dead after k_sort_t)
  char* ap = (char*)sedge_r;
  auto alias = [&](size_t bytes) -> char* {
    char* p = ap;
    ap += (bytes + 255) & ~(size_t)255;
    return p;
  };
  float* ue     = (float*)alias((size_t)BB * 64 * 4);
  float* ie     = (float*)alias((size_t)BB * 64 * 4);
  float* recs_u = (float*)alias((size_t)NLV * BB * 32 * 4);
  float* recs_i = (float*)alias((size_t)NLV * BB * 32 * 4);
  float* att_u  = (float*)alias((size_t)BB * 96 * 4);
  float* att_i  = (float*)alias((size_t)BB * 96 * 4);
  unsigned short* n1b = (unsigned short*)alias((size_t)6 * BB * 32 * 2);
  unsigned short* n2b = (unsigned short*)alias((size_t)6 * BB * 32 * 2);

  // host-side: kc = jax.random.split(jax.random.key(42), 2)
  uint32_t a0 = 0, a1 = 2, b0 = 1, b1 = 3;
  tf_block(0u, 42u, a0, a1);
  tf_block(0u, 42u, b0, b1);
  uint32_t ku0 = a0, ku1 = b0;   // kc[0] -> u side
  uint32_t ki0 = a1, ki1 = b1;   // kc[1] -> i side

  (void)hipMemsetAsync(cursor, 0, (size_t)NTILE * NSUB * 16 * 4, stream);

  k_init<<<9375, 256, 0, stream>>>(ego, E8);
  k_scatter_t<<<(NNZE + EPB - 1) / EPB, 256, 0, stream>>>(adj_rows, adj_cols, adj_vals,
                                                          cursor, sedge_r);
  k_scan586<<<1, 1024, 0, stream>>>(cursor, out_base, row_start);
  k_sort_t<<<NTILE, 256, 0, stream>>>(sedge_r, cursor, out_base, sedge, row_start);

  float* Ebufs[2] = {E1, E2};
  for (int l = 0; l < 2; ++l) {
    k_spmm<<<37500, 256, 0, stream>>>(E8, sedge, row_start, side16, p16);
    k_transform<<<1172, 256, 0, stream>>>(gc_w + l * 4096, gc_b + l * 64,
                                          bi_w + l * 4096, bi_b + l * 64,
                                          side16, p16, Ebufs[l], (unsigned char*)E8);
  }

  k_gather<<<4096, 128, 0, stream>>>(ego, E1, E2, user_id, item_id, ue, ie);

  dim3 ge(4096, 3);
  k_encoder<<<ge, 256, 0, stream>>>(ue, uh_w, uh_b, ud_w1, ud_b1, ud_w2, ud_b2, recs_u);
  k_encoder<<<ge, 256, 0, stream>>>(ie, ih_w, ih_b, id_w1, id_b1, id_w2, id_b2, recs_i);

  k_attn<<<512, 256, 0, stream>>>(recs_u, q_w, q_b, k_w, k_b, v_w, v_b, att_u);
  k_attn<<<512, 256, 0, stream>>>(recs_i, q_w, q_b, k_w, k_b, v_w, v_b, att_i);

  k_noise<<<3072, 256, 0, stream>>>(att_u, att_i, ku0, ku1, ki0, ki1, n1b, n2b, posdot);

  k_ttl<<<384, 256, 0, stream>>>(n1b, n2b, ttl);
  k_clred<<<1, 1024, 0, stream>>>(ttl, posdot, outp);

  k_head<<<1024, 256, 0, stream>>>(att_u, att_i, skills, dg_w1, dg_b1, dg_w2, dg_b2,
                                   pr_w, pr_b, outp);
}